// Round 1
// baseline (4324.116 us; speedup 1.0000x reference)
//
#include <hip/hip_runtime.h>
#include <math.h>

// ---------------------------------------------------------------------------
// SACNet forward, fp32 baseline.
// B=512, IN=200, P=19, CF=64, TF=32, K=48, D=32, NC=16
// ---------------------------------------------------------------------------

// workspace offsets (in floats)
#define OFF_W0T   0u           // 200*9*64 = 115200
#define OFF_W1T   115200u      // 64*9*64  = 36864
#define OFF_W2T   152064u      // 36864
#define OFF_WEFF1 188928u      // 256*64*289 = 4734976
#define OFF_WEFF2 4923904u     // 256*64*169 = 2768896
#define OFF_WEFF3 7692800u     // 256*64*49  = 802816
#define OFF_C1    8495616u     // 512*64*289 = 9469952 (TMP aliases this while building weff)
#define OFF_C2    17965568u    // 512*64*169 = 5537792
#define OFF_XX1   23503360u    // 512*64*49  = 1605632
#define OFF_ALPHA 25108992u    // 512*1568
#define OFF_BETA  25911808u
#define OFF_GAM   26714624u
#define OFF_CTX   27517440u    // 512*2401 = 1229312 (H1P aliases this at dense phase: 7*512*256=917504)
#define OFF_CTX2  28746752u    // 512*1568
#define OFF_XX2   29549568u    // 512*3136
#define OFF_Z     31155200u    // 512*49*32
#define OFF_A     31958016u    // 512*49*48
#define OFF_E     33162240u    // 512*48*32
#define OFF_BNS   33948672u    // 96
#define OFF_XX3   33948768u    // 512*3136
#define OFF_H1    35554400u    // 512*256
#define OFF_H2    35685472u    // 512*128
// total = 35751008 floats = 143.0 MB

// --------------------------- weight transpose ------------------------------
// w [64][inC][3][3] -> wt [inC*3*3][64]  (wt[((ic*3+ky)*3+kx)*64 + c])
__global__ __launch_bounds__(256) void sac_twt(const float* __restrict__ w,
                                               float* __restrict__ wt, int inC) {
    int idx = blockIdx.x * 256 + threadIdx.x;
    int total = 64 * inC * 9;
    if (idx >= total) return;
    int c = idx & 63;
    int q = idx >> 6;
    int kx = q % 3, ky = (q / 3) % 3, ic = q / 9;
    wt[idx] = w[((c * inC + ic) * 3 + ky) * 3 + kx];
}

// --------------------- fold bilinear upsample into w_d1 --------------------
// pass A: contract x-axis 19 -> S.  tmp[o][c][j][xp]
__global__ __launch_bounds__(256) void sac_upA(const float* __restrict__ w_d1,
                                               float* __restrict__ tmp, int S, int co) {
    int idx = blockIdx.x * 256 + threadIdx.x;
    int total = 256 * 64 * 19 * S;
    if (idx >= total) return;
    int xp = idx % S;
    int j  = (idx / S) % 19;
    int c  = (idx / (S * 19)) % 64;
    int o  = idx / (S * 19 * 64);
    const float* wrow = w_d1 + (size_t)o * 69312 + (size_t)(co + c) * 361 + j * 19;
    float ratio = (float)(S - 1) / 18.0f;
    float s = 0.f;
    for (int i = 0; i < 19; ++i) {
        float xs = i * ratio;
        int x0 = (int)floorf(xs);
        float wx = xs - (float)x0;
        int x1 = x0 + 1; if (x1 > S - 1) x1 = S - 1;
        float cf = (xp == x0 ? 1.f - wx : 0.f) + (xp == x1 ? wx : 0.f);
        s += cf * wrow[i];
    }
    tmp[idx] = s;
}
// pass B: contract y-axis 19 -> S.  weff[o][c][yp][xp]
__global__ __launch_bounds__(256) void sac_upB(const float* __restrict__ tmp,
                                               float* __restrict__ weff, int S) {
    int idx = blockIdx.x * 256 + threadIdx.x;
    int total = 256 * 64 * S * S;
    if (idx >= total) return;
    int xp = idx % S;
    int yp = (idx / S) % S;
    int c  = (idx / (S * S)) % 64;
    int o  = idx / (S * S * 64);
    const float* tp = tmp + (((size_t)o * 64 + c) * 19) * S + xp;
    float ratio = (float)(S - 1) / 18.0f;
    float s = 0.f;
    for (int j = 0; j < 19; ++j) {
        float ys = j * ratio;
        int y0 = (int)floorf(ys);
        float wy = ys - (float)y0;
        int y1 = y0 + 1; if (y1 > S - 1) y1 = S - 1;
        float cf = (yp == y0 ? 1.f - wy : 0.f) + (yp == y1 ? wy : 0.f);
        s += cf * tp[j * S];
    }
    weff[idx] = s;
}

// ------------------------------- conv0 -------------------------------------
// x (512,200,19,19) -> c1 (512,64,17,17), 3x3 dil1 + bias + relu
__global__ __launch_bounds__(256) void sac_conv0(const float* __restrict__ x,
                                                 const float* __restrict__ w0t,
                                                 const float* __restrict__ b0,
                                                 float* __restrict__ c1) {
    int blk = blockIdx.x;
    int b = blk / 17, oy = blk % 17;
    __shared__ float xs[200 * 57 + 8];
    __shared__ float wsh[4 * 9 * 64];
    int tid = threadIdx.x;
    const float* xb = x + (size_t)b * 72200 + oy * 19;
    for (int f = tid; f < 200 * 57; f += 256) {
        int ic = f / 57, r = f - ic * 57;   // r = dy*19+ix, rows contiguous per channel
        xs[f] = xb[ic * 361 + r];
    }
    if (tid < 8) xs[200 * 57 + tid] = 0.f;
    int c = tid & 63, g = tid >> 6;
    float acc[5] = {0.f, 0.f, 0.f, 0.f, 0.f};
    for (int ic0 = 0; ic0 < 200; ic0 += 4) {
        __syncthreads();
        for (int f = tid; f < 4 * 9 * 64; f += 256) wsh[f] = w0t[ic0 * 576 + f];
        __syncthreads();
        #pragma unroll
        for (int icl = 0; icl < 4; ++icl) {
            const float* xr = &xs[(ic0 + icl) * 57];
            const float* wr = &wsh[icl * 576 + c];
            #pragma unroll
            for (int ky = 0; ky < 3; ++ky) {
                float w0v = wr[ky * 192], w1v = wr[ky * 192 + 64], w2v = wr[ky * 192 + 128];
                const float* xq = xr + ky * 19;
                #pragma unroll
                for (int t = 0; t < 5; ++t) {
                    int ox = g + 4 * t;
                    acc[t] += w0v * xq[ox] + w1v * xq[ox + 1] + w2v * xq[ox + 2];
                }
            }
        }
    }
    float bias = b0[c];
    float* outp = c1 + ((size_t)b * 64 + c) * 289 + oy * 17;
    #pragma unroll
    for (int t = 0; t < 5; ++t) {
        int ox = g + 4 * t;
        if (ox < 17) { float v = acc[t] + bias; outp[ox] = v > 0.f ? v : 0.f; }
    }
}

// ------------------------------- conv1 (dil=2) -----------------------------
__global__ __launch_bounds__(256) void sac_conv1(const float* __restrict__ c1,
                                                 const float* __restrict__ w1t,
                                                 const float* __restrict__ b1,
                                                 float* __restrict__ c2) {
    int blk = blockIdx.x;
    int b = blk / 13, oy = blk % 13;
    __shared__ float xs[64 * 51 + 8];
    __shared__ float wsh[16 * 9 * 64];
    int tid = threadIdx.x;
    for (int f = tid; f < 64 * 51; f += 256) {
        int ic = f / 51, r = f - ic * 51;
        int dy = r / 17, ix = r - dy * 17;
        xs[f] = c1[((size_t)(b * 64 + ic) * 17 + oy + 2 * dy) * 17 + ix];
    }
    if (tid < 8) xs[64 * 51 + tid] = 0.f;
    int c = tid & 63, g = tid >> 6;
    float acc[4] = {0.f, 0.f, 0.f, 0.f};
    for (int ic0 = 0; ic0 < 64; ic0 += 16) {
        __syncthreads();
        for (int f = tid; f < 16 * 9 * 64; f += 256) wsh[f] = w1t[ic0 * 576 + f];
        __syncthreads();
        #pragma unroll 4
        for (int icl = 0; icl < 16; ++icl) {
            const float* xr = &xs[(ic0 + icl) * 51];
            const float* wr = &wsh[icl * 576 + c];
            #pragma unroll
            for (int ky = 0; ky < 3; ++ky) {
                float w0v = wr[ky * 192], w1v = wr[ky * 192 + 64], w2v = wr[ky * 192 + 128];
                const float* xq = xr + ky * 17;
                #pragma unroll
                for (int t = 0; t < 4; ++t) {
                    int ox = g + 4 * t;
                    acc[t] += w0v * xq[ox] + w1v * xq[ox + 2] + w2v * xq[ox + 4];
                }
            }
        }
    }
    float bias = b1[c];
    float* outp = c2 + ((size_t)b * 64 + c) * 169 + oy * 13;
    #pragma unroll
    for (int t = 0; t < 4; ++t) {
        int ox = g + 4 * t;
        if (ox < 13) { float v = acc[t] + bias; outp[ox] = v > 0.f ? v : 0.f; }
    }
}

// ------------------------------- conv2 (dil=3) -----------------------------
__global__ __launch_bounds__(256) void sac_conv2(const float* __restrict__ c2,
                                                 const float* __restrict__ w2t,
                                                 const float* __restrict__ b2,
                                                 float* __restrict__ xx1) {
    int b = blockIdx.x;
    __shared__ float xs[64 * 169];
    __shared__ float wsh[8 * 9 * 64];
    int tid = threadIdx.x;
    for (int f = tid; f < 64 * 169; f += 256) xs[f] = c2[(size_t)b * 10816 + f];
    int c = tid & 63, g = tid >> 6;
    int pyv[13], pxv[13];
    #pragma unroll
    for (int t = 0; t < 13; ++t) { int p = g + 4 * t; pyv[t] = p / 7; pxv[t] = p - (p / 7) * 7; }
    float acc[13];
    #pragma unroll
    for (int t = 0; t < 13; ++t) acc[t] = 0.f;
    for (int ic0 = 0; ic0 < 64; ic0 += 8) {
        __syncthreads();
        for (int f = tid; f < 8 * 9 * 64; f += 256) wsh[f] = w2t[ic0 * 576 + f];
        __syncthreads();
        #pragma unroll 2
        for (int icl = 0; icl < 8; ++icl) {
            const float* xr = &xs[(ic0 + icl) * 169];
            const float* wr = &wsh[icl * 576 + c];
            #pragma unroll
            for (int ky = 0; ky < 3; ++ky) {
                float w0v = wr[ky * 192], w1v = wr[ky * 192 + 64], w2v = wr[ky * 192 + 128];
                #pragma unroll
                for (int t = 0; t < 13; ++t) {
                    int p = g + 4 * t;
                    if (p < 49) {
                        const float* xq = xr + (pyv[t] + 3 * ky) * 13 + pxv[t];
                        acc[t] += w0v * xq[0] + w1v * xq[3] + w2v * xq[6];
                    }
                }
            }
        }
    }
    float bias = b2[c];
    float* outp = xx1 + ((size_t)b * 64 + c) * 49;
    #pragma unroll
    for (int t = 0; t < 13; ++t) {
        int p = g + 4 * t;
        if (p < 49) { float v = acc[t] + bias; outp[p] = v > 0.f ? v : 0.f; }
    }
}

// ------------------- 1x1 convs a/b/g (relu only on g) ----------------------
__global__ __launch_bounds__(256) void sac_abg(const float* __restrict__ xx1,
                                               const float* __restrict__ wa,
                                               const float* __restrict__ wb,
                                               const float* __restrict__ wg,
                                               float* __restrict__ alpha,
                                               float* __restrict__ beta,
                                               float* __restrict__ gam) {
    int b = blockIdx.x, tid = threadIdx.x;
    __shared__ float xsm[3136];
    __shared__ float ws3[3 * 2048];
    for (int f = tid; f < 3136; f += 256) xsm[f] = xx1[(size_t)b * 3136 + f];
    for (int f = tid; f < 2048; f += 256) {
        ws3[f] = wa[f]; ws3[2048 + f] = wb[f]; ws3[4096 + f] = wg[f];
    }
    __syncthreads();
    for (int f = tid; f < 4704; f += 256) {
        int which = f / 1568, r = f - which * 1568;
        int t = r / 49, p = r - t * 49;
        const float* w = &ws3[which * 2048 + t * 64];
        float s = 0.f;
        #pragma unroll 8
        for (int c = 0; c < 64; ++c) s += w[c] * xsm[c * 49 + p];
        if (which == 2) s = s > 0.f ? s : 0.f;
        float* o = (which == 0) ? alpha : (which == 1) ? beta : gam;
        o[(size_t)b * 1568 + r] = s;
    }
}

// --------------------- ctx = alpha(raw reshape) @ beta ---------------------
__global__ __launch_bounds__(256) void sac_ctx(const float* __restrict__ alpha,
                                               const float* __restrict__ beta,
                                               float* __restrict__ ctx) {
    int b = blockIdx.x, tid = threadIdx.x;
    __shared__ float af[1568];
    __shared__ float bt[1568];
    for (int f = tid; f < 1568; f += 256) {
        af[f] = alpha[(size_t)b * 1568 + f];
        bt[f] = beta[(size_t)b * 1568 + f];
    }
    __syncthreads();
    for (int f = tid; f < 2401; f += 256) {
        int i = f / 49, l = f - i * 49;
        float s = 0.f;
        #pragma unroll 8
        for (int j = 0; j < 32; ++j) s += af[i * 32 + j] * bt[j * 49 + l];
        ctx[(size_t)b * 2401 + f] = s;
    }
}

// --------------------- softmax over BATCH axis (dim 0) ---------------------
__global__ __launch_bounds__(256) void sac_softmax0(float* __restrict__ ctx) {
    int pos = blockIdx.x;              // 0..2400
    int tid = threadIdx.x;
    float v0 = ctx[(size_t)tid * 2401 + pos];
    float v1 = ctx[(size_t)(tid + 256) * 2401 + pos];
    float m = fmaxf(v0, v1);
    #pragma unroll
    for (int off = 32; off > 0; off >>= 1) m = fmaxf(m, __shfl_xor(m, off, 64));
    __shared__ float sred[4];
    __shared__ float ssum[4];
    int lane = tid & 63, wid = tid >> 6;
    if (lane == 0) sred[wid] = m;
    __syncthreads();
    m = fmaxf(fmaxf(sred[0], sred[1]), fmaxf(sred[2], sred[3]));
    float e0 = expf(v0 - m), e1 = expf(v1 - m);
    float s = e0 + e1;
    #pragma unroll
    for (int off = 32; off > 0; off >>= 1) s += __shfl_xor(s, off, 64);
    if (lane == 0) ssum[wid] = s;
    __syncthreads();
    float inv = 1.f / (ssum[0] + ssum[1] + ssum[2] + ssum[3]);
    ctx[(size_t)tid * 2401 + pos] = e0 * inv;
    ctx[(size_t)(tid + 256) * 2401 + pos] = e1 * inv;
}

// --------------------------- ctx2 = gam @ ctx ------------------------------
__global__ __launch_bounds__(256) void sac_ctx2(const float* __restrict__ gam,
                                                const float* __restrict__ ctx,
                                                float* __restrict__ ctx2) {
    int b = blockIdx.x, tid = threadIdx.x;
    __shared__ float gs[1568];
    __shared__ float cs[2401];
    for (int f = tid; f < 1568; f += 256) gs[f] = gam[(size_t)b * 1568 + f];
    for (int f = tid; f < 2401; f += 256) cs[f] = ctx[(size_t)b * 2401 + f];
    __syncthreads();
    for (int f = tid; f < 1568; f += 256) {
        int t = f / 49, l = f - t * 49;
        float s = 0.f;
        #pragma unroll 7
        for (int i = 0; i < 49; ++i) s += gs[t * 49 + i] * cs[i * 49 + l];
        ctx2[(size_t)b * 1568 + f] = s;
    }
}

// ----------------- xx2 = relu(wd @ ctx2) + xx1 -----------------------------
__global__ __launch_bounds__(256) void sac_xx2(const float* __restrict__ ctx2,
                                               const float* __restrict__ wd,
                                               const float* __restrict__ xx1,
                                               float* __restrict__ xx2) {
    int b = blockIdx.x, tid = threadIdx.x;
    __shared__ float cs[1568];
    __shared__ float wds[2048];
    for (int f = tid; f < 1568; f += 256) cs[f] = ctx2[(size_t)b * 1568 + f];
    for (int f = tid; f < 2048; f += 256) wds[f] = wd[f];
    __syncthreads();
    for (int f = tid; f < 3136; f += 256) {
        int c = f / 49, p = f - c * 49;
        float s = 0.f;
        #pragma unroll 8
        for (int t = 0; t < 32; ++t) s += wds[c * 32 + t] * cs[t * 49 + p];
        s = s > 0.f ? s : 0.f;
        xx2[(size_t)b * 3136 + f] = s + xx1[(size_t)b * 3136 + f];
    }
}

// ------------------- Z = relu(wenc @ xx2), layout (b,p,d) ------------------
__global__ __launch_bounds__(256) void sac_z(const float* __restrict__ xx2,
                                             const float* __restrict__ wenc,
                                             float* __restrict__ Z) {
    int b = blockIdx.x, tid = threadIdx.x;
    __shared__ float xsm[3136];
    __shared__ float wt[2048];   // [c][d]
    for (int f = tid; f < 3136; f += 256) xsm[f] = xx2[(size_t)b * 3136 + f];
    for (int f = tid; f < 2048; f += 256) { int d = f >> 6, c = f & 63; wt[c * 32 + d] = wenc[f]; }
    __syncthreads();
    for (int f = tid; f < 1568; f += 256) {
        int p = f >> 5, d = f & 31;
        float s = 0.f;
        #pragma unroll 8
        for (int c = 0; c < 64; ++c) s += wt[c * 32 + d] * xsm[c * 49 + p];
        Z[(size_t)b * 1568 + f] = s > 0.f ? s : 0.f;
    }
}

// ----------------------- dist (pre-softmax) --------------------------------
__global__ __launch_bounds__(256) void sac_dist(const float* __restrict__ Z,
                                                const float* __restrict__ cw,
                                                const float* __restrict__ scale,
                                                float* __restrict__ A) {
    __shared__ float cws[1536];
    __shared__ float c2s[48];
    __shared__ float scs[48];
    int tid = threadIdx.x;
    for (int f = tid; f < 1536; f += 256) cws[f] = cw[f];
    if (tid < 48) scs[tid] = scale[tid];
    __syncthreads();
    if (tid < 48) {
        float s = 0.f;
        for (int d = 0; d < 32; ++d) { float v = cws[tid * 32 + d]; s += v * v; }
        c2s[tid] = s;
    }
    __syncthreads();
    int idx = blockIdx.x * 256 + tid;      // (b,p) over 25088
    if (idx >= 25088) return;
    const float4* zp = (const float4*)(Z + (size_t)idx * 32);
    float zr[32];
    #pragma unroll
    for (int q = 0; q < 8; ++q) {
        float4 v = zp[q];
        zr[q * 4] = v.x; zr[q * 4 + 1] = v.y; zr[q * 4 + 2] = v.z; zr[q * 4 + 3] = v.w;
    }
    float z2 = 0.f;
    #pragma unroll
    for (int d = 0; d < 32; ++d) z2 += zr[d] * zr[d];
    float* ap = A + (size_t)idx * 48;
    for (int k = 0; k < 48; ++k) {
        float dot = 0.f;
        #pragma unroll
        for (int d = 0; d < 32; ++d) dot += zr[d] * cws[k * 32 + d];
        ap[k] = scs[k] * (z2 + c2s[k] - 2.f * dot);
    }
}

// ----------------------- softmax over k (48) -------------------------------
__global__ __launch_bounds__(256) void sac_asoft(float* __restrict__ A) {
    int idx = blockIdx.x * 256 + threadIdx.x;
    if (idx >= 25088) return;
    float* ap = A + (size_t)idx * 48;
    float v[48];
    float m = -1e30f;
    #pragma unroll
    for (int k = 0; k < 48; ++k) { v[k] = ap[k]; m = fmaxf(m, v[k]); }
    float s = 0.f;
    #pragma unroll
    for (int k = 0; k < 48; ++k) { v[k] = expf(v[k] - m); s += v[k]; }
    float inv = 1.f / s;
    #pragma unroll
    for (int k = 0; k < 48; ++k) ap[k] = v[k] * inv;
}

// ------------- E[b,k,d] = sum_p A*Z - (sum_p A) * C ------------------------
__global__ __launch_bounds__(256) void sac_e(const float* __restrict__ A,
                                             const float* __restrict__ Z,
                                             const float* __restrict__ cw,
                                             float* __restrict__ E) {
    int b = blockIdx.x, tid = threadIdx.x;
    __shared__ float As[2352];
    __shared__ float Zs[1568];
    __shared__ float asum[48];
    for (int f = tid; f < 2352; f += 256) As[f] = A[(size_t)b * 2352 + f];
    for (int f = tid; f < 1568; f += 256) Zs[f] = Z[(size_t)b * 1568 + f];
    __syncthreads();
    if (tid < 48) {
        float s = 0.f;
        for (int p = 0; p < 49; ++p) s += As[p * 48 + tid];
        asum[tid] = s;
    }
    __syncthreads();
    for (int f = tid; f < 1536; f += 256) {
        int k = f >> 5, d = f & 31;
        float s = 0.f;
        #pragma unroll 7
        for (int p = 0; p < 49; ++p) s += As[p * 48 + k] * Zs[p * 32 + d];
        E[(size_t)b * 1536 + f] = s - asum[k] * cw[f];
    }
}

// ------------------- BatchNorm stats per code k ----------------------------
__global__ __launch_bounds__(256) void sac_bnstat(const float* __restrict__ E,
                                                  float* __restrict__ bns) {
    int k = blockIdx.x, tid = threadIdx.x;
    __shared__ float sr[4];
    float s = 0.f;
    for (int i = tid; i < 16384; i += 256) {
        int b = i >> 5, d = i & 31;
        s += E[((size_t)b * 48 + k) * 32 + d];
    }
    #pragma unroll
    for (int off = 32; off > 0; off >>= 1) s += __shfl_xor(s, off, 64);
    int lane = tid & 63, wid = tid >> 6;
    if (lane == 0) sr[wid] = s;
    __syncthreads();
    float mu = (sr[0] + sr[1] + sr[2] + sr[3]) / 16384.f;
    float q = 0.f;
    for (int i = tid; i < 16384; i += 256) {
        int b = i >> 5, d = i & 31;
        float v = E[((size_t)b * 48 + k) * 32 + d] - mu;
        q += v * v;
    }
    #pragma unroll
    for (int off = 32; off > 0; off >>= 1) q += __shfl_xor(q, off, 64);
    __syncthreads();
    if (lane == 0) sr[wid] = q;
    __syncthreads();
    if (tid == 0) {
        float var = (sr[0] + sr[1] + sr[2] + sr[3]) / 16384.f;
        bns[k] = mu;
        bns[48 + k] = rsqrtf(var + 1e-5f);
    }
}

// ---------------- BN+relu -> E_sum -> gate -> xx3 --------------------------
__global__ __launch_bounds__(256) void sac_gate(const float* __restrict__ E,
                                                const float* __restrict__ bns,
                                                const float* __restrict__ bn_g,
                                                const float* __restrict__ bn_b,
                                                const float* __restrict__ w_att,
                                                const float* __restrict__ b_att,
                                                const float* __restrict__ xx2,
                                                float* __restrict__ xx3) {
    int b = blockIdx.x, tid = threadIdx.x;
    __shared__ float esd[32];
    __shared__ float gs[64];
    if (tid < 32) {
        int d = tid;
        float s = 0.f;
        for (int k = 0; k < 48; ++k) {
            float v = (E[((size_t)b * 48 + k) * 32 + d] - bns[k]) * bns[48 + k] * bn_g[k] + bn_b[k];
            s += v > 0.f ? v : 0.f;
        }
        esd[d] = s;
    }
    __syncthreads();
    if (tid < 64) {
        int c = tid;
        float a = b_att[c];
        #pragma unroll 8
        for (int d = 0; d < 32; ++d) a += esd[d] * w_att[c * 32 + d];
        gs[c] = 1.f / (1.f + expf(-a)) + 1.f;     // 1 + gate
    }
    __syncthreads();
    for (int f = tid; f < 3136; f += 256) {
        int c = f / 49;
        xx3[(size_t)b * 3136 + f] = xx2[(size_t)b * 3136 + f] * gs[c];
    }
}

// ---------------- d1 GEMM (split-K over 7 slab-aligned chunks) -------------
// h1p[s][b][o] partials.  chunks: c1 4x4624, c2 2x5408, xx3 1x3136
__global__ __launch_bounds__(256) void sac_d1gemm(const float* __restrict__ c1,
                                                  const float* __restrict__ c2,
                                                  const float* __restrict__ xx3,
                                                  const float* __restrict__ weff1,
                                                  const float* __restrict__ weff2,
                                                  const float* __restrict__ weff3,
                                                  float* __restrict__ h1p) {
    int blk = blockIdx.x;            // 7*32
    int s = blk >> 5;
    int r = blk & 31;
    int b0 = (r >> 2) * 64, o0 = (r & 3) * 64;
    const float* Ab; const float* Wb; int astr, klen;
    if (s < 4)      { Ab = c1 + s * 4624;       Wb = weff1 + s * 4624;       astr = 18496; klen = 4624; }
    else if (s < 6) { Ab = c2 + (s - 4) * 5408; Wb = weff2 + (s - 4) * 5408; astr = 10816; klen = 5408; }
    else            { Ab = xx3;                 Wb = weff3;                  astr = 3136;  klen = 3136; }
    __shared__ float As[16][68];
    __shared__ float Wsh[16][68];
    int tid = threadIdx.x;
    int tx = tid & 15, ty = tid >> 4;
    int bi = tid >> 2, kq = tid & 3;
    const float* aP = Ab + (size_t)(b0 + bi) * astr + kq * 4;
    const float* wP = Wb + (size_t)(o0 + bi) * astr + kq * 4;
    float acc[4][4];
    #pragma unroll
    for (int i = 0; i < 4; ++i)
        #pragma unroll
        for (int j = 0; j < 4; ++j) acc[i][j] = 0.f;
    for (int k0 = 0; k0 < klen; k0 += 16) {
        float4 av = *(const float4*)(aP + k0);
        float4 wv = *(const float4*)(wP + k0);
        __syncthreads();
        As[kq * 4 + 0][bi] = av.x; As[kq * 4 + 1][bi] = av.y;
        As[kq * 4 + 2][bi] = av.z; As[kq * 4 + 3][bi] = av.w;
        Wsh[kq * 4 + 0][bi] = wv.x; Wsh[kq * 4 + 1][bi] = wv.y;
        Wsh[kq * 4 + 2][bi] = wv.z; Wsh[kq * 4 + 3][bi] = wv.w;
        __syncthreads();
        #pragma unroll
        for (int kk = 0; kk < 16; ++kk) {
            float4 a4 = *(const float4*)&As[kk][ty * 4];
            float4 w4 = *(const float4*)&Wsh[kk][tx * 4];
            acc[0][0] += a4.x * w4.x; acc[0][1] += a4.x * w4.y; acc[0][2] += a4.x * w4.z; acc[0][3] += a4.x * w4.w;
            acc[1][0] += a4.y * w4.x; acc[1][1] += a4.y * w4.y; acc[1][2] += a4.y * w4.z; acc[1][3] += a4.y * w4.w;
            acc[2][0] += a4.z * w4.x; acc[2][1] += a4.z * w4.y; acc[2][2] += a4.z * w4.z; acc[2][3] += a4.z * w4.w;
            acc[3][0] += a4.w * w4.x; acc[3][1] += a4.w * w4.y; acc[3][2] += a4.w * w4.z; acc[3][3] += a4.w * w4.w;
        }
    }
    float* op = h1p + ((size_t)s * 512 + b0 + ty * 4) * 256 + o0 + tx * 4;
    #pragma unroll
    for (int i = 0; i < 4; ++i) {
        float4 v; v.x = acc[i][0]; v.y = acc[i][1]; v.z = acc[i][2]; v.w = acc[i][3];
        *(float4*)(op + i * 256) = v;
    }
}

// ---------------- h1 = relu(sum partials + bias) ---------------------------
__global__ __launch_bounds__(256) void sac_h1red(const float* __restrict__ h1p,
                                                 const float* __restrict__ b_d1,
                                                 float* __restrict__ h1) {
    int i = blockIdx.x * 256 + threadIdx.x;    // 131072
    int o = i & 255;
    float s = b_d1[o];
    #pragma unroll
    for (int t = 0; t < 7; ++t) s += h1p[(size_t)t * 131072 + i];
    h1[i] = s > 0.f ? s : 0.f;
}

// ---------------- h2 = relu(h1 @ w_d2.T + b_d2) ----------------------------
__global__ __launch_bounds__(256) void sac_h2(const float* __restrict__ h1,
                                              const float* __restrict__ w_d2,
                                              const float* __restrict__ b_d2,
                                              float* __restrict__ h2) {
    int idx = blockIdx.x * 256 + threadIdx.x;  // 65536
    int b = idx >> 7, o = idx & 127;
    const float* hp = h1 + b * 256;
    const float* wp = w_d2 + o * 256;
    float s = b_d2[o];
    #pragma unroll 4
    for (int k = 0; k < 256; ++k) s += hp[k] * wp[k];
    h2[idx] = s > 0.f ? s : 0.f;
}

// ---------------- out = h2 @ w_d3.T + b_d3 ---------------------------------
__global__ __launch_bounds__(256) void sac_out(const float* __restrict__ h2,
                                               const float* __restrict__ w_d3,
                                               const float* __restrict__ b_d3,
                                               float* __restrict__ out) {
    int idx = blockIdx.x * 256 + threadIdx.x;  // 8192
    int b = idx >> 4, j = idx & 15;
    const float* hp = h2 + b * 128;
    const float* wp = w_d3 + j * 128;
    float s = b_d3[j];
    #pragma unroll 4
    for (int k = 0; k < 128; ++k) s += hp[k] * wp[k];
    out[idx] = s;
}

// ---------------------------------------------------------------------------
extern "C" void kernel_launch(void* const* d_in, const int* in_sizes, int n_in,
                              void* d_out, int out_size, void* d_ws, size_t ws_size,
                              hipStream_t stream) {
    (void)in_sizes; (void)n_in; (void)out_size; (void)ws_size;
    const float* x     = (const float*)d_in[0];
    const float* w0    = (const float*)d_in[1];
    const float* b0    = (const float*)d_in[2];
    const float* w1    = (const float*)d_in[3];
    const float* b1    = (const float*)d_in[4];
    const float* w2    = (const float*)d_in[5];
    const float* b2    = (const float*)d_in[6];
    const float* wa    = (const float*)d_in[7];
    const float* wb    = (const float*)d_in[8];
    const float* wg    = (const float*)d_in[9];
    const float* wd    = (const float*)d_in[10];
    const float* wenc  = (const float*)d_in[11];
    const float* cw    = (const float*)d_in[12];
    const float* scale = (const float*)d_in[13];
    const float* w_att = (const float*)d_in[14];
    const float* b_att = (const float*)d_in[15];
    const float* bn_g  = (const float*)d_in[16];
    const float* bn_b  = (const float*)d_in[17];
    const float* w_d1  = (const float*)d_in[18];
    const float* b_d1  = (const float*)d_in[19];
    const float* w_d2  = (const float*)d_in[20];
    const float* b_d2  = (const float*)d_in[21];
    const float* w_d3  = (const float*)d_in[22];
    const float* b_d3  = (const float*)d_in[23];

    float* ws    = (float*)d_ws;
    float* W0T   = ws + OFF_W0T;
    float* W1T   = ws + OFF_W1T;
    float* W2T   = ws + OFF_W2T;
    float* WEFF1 = ws + OFF_WEFF1;
    float* WEFF2 = ws + OFF_WEFF2;
    float* WEFF3 = ws + OFF_WEFF3;
    float* TMP   = ws + OFF_C1;     // alias: weff build finishes before conv0 writes C1
    float* C1    = ws + OFF_C1;
    float* C2    = ws + OFF_C2;
    float* XX1   = ws + OFF_XX1;
    float* ALPHA = ws + OFF_ALPHA;
    float* BETA  = ws + OFF_BETA;
    float* GAM   = ws + OFF_GAM;
    float* CTX   = ws + OFF_CTX;
    float* H1P   = ws + OFF_CTX;    // alias: ctx dead after sac_ctx2
    float* CTX2  = ws + OFF_CTX2;
    float* XX2   = ws + OFF_XX2;
    float* Z     = ws + OFF_Z;
    float* A     = ws + OFF_A;
    float* E     = ws + OFF_E;
    float* BNS   = ws + OFF_BNS;
    float* XX3   = ws + OFF_XX3;
    float* H1    = ws + OFF_H1;
    float* H2    = ws + OFF_H2;

    // weight transposes
    sac_twt<<<450, 256, 0, stream>>>(w0, W0T, 200);
    sac_twt<<<144, 256, 0, stream>>>(w1, W1T, 64);
    sac_twt<<<144, 256, 0, stream>>>(w2, W2T, 64);

    // fold bilinear upsample into w_d1 (three parts: c1u, c2u, ctx3)
    sac_upA<<<20672, 256, 0, stream>>>(w_d1, TMP, 17, 0);
    sac_upB<<<18496, 256, 0, stream>>>(TMP, WEFF1, 17);
    sac_upA<<<15808, 256, 0, stream>>>(w_d1, TMP, 13, 64);
    sac_upB<<<10816, 256, 0, stream>>>(TMP, WEFF2, 13);
    sac_upA<<<8512, 256, 0, stream>>>(w_d1, TMP, 7, 128);
    sac_upB<<<3136, 256, 0, stream>>>(TMP, WEFF3, 7);

    // backbone
    sac_conv0<<<512 * 17, 256, 0, stream>>>(x, W0T, b0, C1);
    sac_conv1<<<512 * 13, 256, 0, stream>>>(C1, W1T, b1, C2);
    sac_conv2<<<512, 256, 0, stream>>>(C2, W2T, b2, XX1);

    // non-local block
    sac_abg<<<512, 256, 0, stream>>>(XX1, wa, wb, wg, ALPHA, BETA, GAM);
    sac_ctx<<<512, 256, 0, stream>>>(ALPHA, BETA, CTX);
    sac_softmax0<<<2401, 256, 0, stream>>>(CTX);
    sac_ctx2<<<512, 256, 0, stream>>>(GAM, CTX, CTX2);
    sac_xx2<<<512, 256, 0, stream>>>(CTX2, wd, XX1, XX2);

    // soft VQ encoding + gate
    sac_z<<<512, 256, 0, stream>>>(XX2, wenc, Z);
    sac_dist<<<98, 256, 0, stream>>>(Z, cw, scale, A);
    sac_asoft<<<98, 256, 0, stream>>>(A);
    sac_e<<<512, 256, 0, stream>>>(A, Z, cw, E);
    sac_bnstat<<<48, 256, 0, stream>>>(E, BNS);
    sac_gate<<<512, 256, 0, stream>>>(E, BNS, bn_g, bn_b, w_att, b_att, XX2, XX3);

    // dense head (upsample folded into WEFF)
    sac_d1gemm<<<224, 256, 0, stream>>>(C1, C2, XX3, WEFF1, WEFF2, WEFF3, H1P);
    sac_h1red<<<512, 256, 0, stream>>>(H1P, b_d1, H1);
    sac_h2<<<256, 256, 0, stream>>>(H1, w_d2, b_d2, H2);
    sac_out<<<32, 256, 0, stream>>>(H2, w_d3, b_d3, (float*)d_out);
}

// Round 3
// 1553.941 us; speedup vs baseline: 2.7827x; 2.7827x over previous
//
#include <hip/hip_runtime.h>
#include <math.h>

// ---------------------------------------------------------------------------
// SACNet forward. conv0 = split-bf16 MFMA implicit GEMM; rest fp32.
// B=512, IN=200, P=19, CF=64, TF=32, K=48, D=32, NC=16
// ---------------------------------------------------------------------------

typedef __attribute__((ext_vector_type(8))) short short8v;   // 8 bf16
typedef __attribute__((ext_vector_type(4))) float f32x4;

// workspace offsets (in floats)
#define OFF_W0T   0u           // (unused now) 115200
#define OFF_W1T   115200u      // 64*9*64  = 36864
#define OFF_W2T   152064u      // 36864
#define OFF_WEFF1 188928u      // 256*64*289 = 4734976
#define OFF_WEFF2 4923904u     // 256*64*169 = 2768896
#define OFF_WEFF3 7692800u     // 256*64*49  = 802816
#define OFF_C1    8495616u     // 512*64*289 = 9469952 (TMP aliases this while building weff)
#define OFF_C2    17965568u    // 512*64*169 = 5537792
#define OFF_XX1   23503360u    // 512*64*49  = 1605632
#define OFF_ALPHA 25108992u    // 512*1568   (WH/WL alias this region pre-abg)
#define OFF_BETA  25911808u
#define OFF_GAM   26714624u
#define OFF_CTX   27517440u    // 512*2401 (H1P aliases this at dense phase)
#define OFF_CTX2  28746752u
#define OFF_XX2   29549568u    // 512*3136
#define OFF_Z     31155200u    // 512*49*32
#define OFF_A     31958016u    // 512*49*48
#define OFF_E     33162240u    // 512*48*32
#define OFF_BNS   33948672u    // 96
#define OFF_XX3   33948768u    // 512*3136
#define OFF_H1    35554400u    // 512*256
#define OFF_H2    35685472u    // 512*128

// WH/WL: 9*64*224 = 129024 shorts = 258048 bytes = 64512 FLOATS each.
// (Round-2 bug: used 32256 -> WL overlapped WH's second half -> race.)
#define OFF_WH    OFF_ALPHA
#define OFF_WL    (OFF_ALPHA + 64512u)
// WH+WL end at OFF_ALPHA+129024 = 25238016 < OFF_BETA (25911808). OK.

__device__ __forceinline__ unsigned bf16_rne_bits(float v) {
    unsigned u = __float_as_uint(v);
    return (u + 0x7FFFu + ((u >> 16) & 1u)) >> 16;
}

// --------------------------- weight transpose ------------------------------
__global__ __launch_bounds__(256) void sac_twt(const float* __restrict__ w,
                                               float* __restrict__ wt, int inC) {
    int idx = blockIdx.x * 256 + threadIdx.x;
    int total = 64 * inC * 9;
    if (idx >= total) return;
    int c = idx & 63;
    int q = idx >> 6;
    int kx = q % 3, ky = (q / 3) % 3, ic = q / 9;
    wt[idx] = w[((c * inC + ic) * 3 + ky) * 3 + kx];
}

// -------------------- split w0 into bf16 hi/lo [s][c][ic224] ---------------
__global__ __launch_bounds__(256) void sac_wsplit(const float* __restrict__ w0,
                                                  unsigned short* __restrict__ WH,
                                                  unsigned short* __restrict__ WL) {
    int idx = blockIdx.x * 256 + threadIdx.x;   // 9*64*224 = 129024
    if (idx >= 129024) return;
    int ic = idx % 224;
    int c  = (idx / 224) % 64;
    int s  = idx / (224 * 64);
    int ky = s / 3, kx = s % 3;
    float v = 0.f;
    if (ic < 200) v = w0[((c * 200 + ic) * 3 + ky) * 3 + kx];
    unsigned hb = bf16_rne_bits(v);
    float hf = __uint_as_float(hb << 16);
    unsigned lb = bf16_rne_bits(v - hf);
    WH[idx] = (unsigned short)hb;
    WL[idx] = (unsigned short)lb;
}

// --------------------- fold bilinear upsample into w_d1 --------------------
__global__ __launch_bounds__(256) void sac_upA(const float* __restrict__ w_d1,
                                               float* __restrict__ tmp, int S, int co) {
    int idx = blockIdx.x * 256 + threadIdx.x;
    int total = 256 * 64 * 19 * S;
    if (idx >= total) return;
    int xp = idx % S;
    int j  = (idx / S) % 19;
    int c  = (idx / (S * 19)) % 64;
    int o  = idx / (S * 19 * 64);
    const float* wrow = w_d1 + (size_t)o * 69312 + (size_t)(co + c) * 361 + j * 19;
    float ratio = (float)(S - 1) / 18.0f;
    float s = 0.f;
    for (int i = 0; i < 19; ++i) {
        float xs = i * ratio;
        int x0 = (int)floorf(xs);
        float wx = xs - (float)x0;
        int x1 = x0 + 1; if (x1 > S - 1) x1 = S - 1;
        float cf = (xp == x0 ? 1.f - wx : 0.f) + (xp == x1 ? wx : 0.f);
        s += cf * wrow[i];
    }
    tmp[idx] = s;
}
__global__ __launch_bounds__(256) void sac_upB(const float* __restrict__ tmp,
                                               float* __restrict__ weff, int S) {
    int idx = blockIdx.x * 256 + threadIdx.x;
    int total = 256 * 64 * S * S;
    if (idx >= total) return;
    int xp = idx % S;
    int yp = (idx / S) % S;
    int c  = (idx / (S * S)) % 64;
    int o  = idx / (S * S * 64);
    const float* tp = tmp + (((size_t)o * 64 + c) * 19) * S + xp;
    float ratio = (float)(S - 1) / 18.0f;
    float s = 0.f;
    for (int j = 0; j < 19; ++j) {
        float ys = j * ratio;
        int y0 = (int)floorf(ys);
        float wy = ys - (float)y0;
        int y1 = y0 + 1; if (y1 > S - 1) y1 = S - 1;
        float cf = (yp == y0 ? 1.f - wy : 0.f) + (yp == y1 ? wy : 0.f);
        s += cf * tp[j * S];
    }
    weff[idx] = s;
}

// ------------------- conv0 via split-bf16 MFMA implicit GEMM ---------------
// grid: 512 b x 5 m-tiles. block: 256 thr = 4 waves (2x2 of 32x32).
// out c1[b][c][pix], pix = oy*17+ox (289 pixels).
__global__ __launch_bounds__(256) void sac_conv0_mfma(const float* __restrict__ x,
                                                      const unsigned short* __restrict__ WH,
                                                      const unsigned short* __restrict__ WL,
                                                      const float* __restrict__ b0,
                                                      float* __restrict__ c1) {
    int blk = blockIdx.x;
    int b = blk / 5, mt = blk % 5;
    int tid = threadIdx.x;
    int w = tid >> 6, l = tid & 63;
    int wm = w >> 1, wn = w & 1;
    int q = l >> 4, r = l & 15;
    int p_base = mt * 64 + wm * 32;
    int n_base = wn * 32;
    int pixA = p_base + r;       if (pixA > 288) pixA = 288;
    int pixB = p_base + 16 + r;  if (pixB > 288) pixB = 288;
    int pyA = pixA / 17, pxa = pixA - pyA * 17;
    int pyB = pixB / 17, pxb = pixB - pyB * 17;
    const float* xb = x + (size_t)b * 72200 + q * 8 * 361;  // ic-subgroup base

    f32x4 acc[2][2];
    #pragma unroll
    for (int i = 0; i < 2; ++i)
        #pragma unroll
        for (int j = 0; j < 2; ++j) { acc[i][j].x = 0.f; acc[i][j].y = 0.f; acc[i][j].z = 0.f; acc[i][j].w = 0.f; }

    for (int ky = 0; ky < 3; ++ky) {
        for (int kx = 0; kx < 3; ++kx) {
            int s = ky * 3 + kx;
            const float* pA0 = xb + (pyA + ky) * 19 + (pxa + kx);
            const float* pA1 = xb + (pyB + ky) * 19 + (pxb + kx);
            const unsigned short* pWH = WH + ((size_t)(s * 64 + n_base + r)) * 224 + q * 8;
            const unsigned short* pWL = WL + ((size_t)(s * 64 + n_base + r)) * 224 + q * 8;
            #pragma unroll 1
            for (int icc = 0; icc < 7; ++icc) {
                int ic0 = icc * 32;
                short8v ah0, al0, ah1, al1;
                if (icc == 6 && q != 0) {
                    #pragma unroll
                    for (int j = 0; j < 8; ++j) { ah0[j] = 0; al0[j] = 0; ah1[j] = 0; al1[j] = 0; }
                } else {
                    #pragma unroll
                    for (int j = 0; j < 8; ++j) {
                        float v0 = pA0[(ic0 + j) * 361];
                        unsigned h0 = bf16_rne_bits(v0);
                        float hf0 = __uint_as_float(h0 << 16);
                        ah0[j] = (short)h0;
                        al0[j] = (short)bf16_rne_bits(v0 - hf0);
                        float v1 = pA1[(ic0 + j) * 361];
                        unsigned h1 = bf16_rne_bits(v1);
                        float hf1 = __uint_as_float(h1 << 16);
                        ah1[j] = (short)h1;
                        al1[j] = (short)bf16_rne_bits(v1 - hf1);
                    }
                }
                short8v bh0 = *(const short8v*)(pWH + ic0);
                short8v bh1 = *(const short8v*)(pWH + ic0 + 16 * 224);
                short8v bl0 = *(const short8v*)(pWL + ic0);
                short8v bl1 = *(const short8v*)(pWL + ic0 + 16 * 224);
                acc[0][0] = __builtin_amdgcn_mfma_f32_16x16x32_bf16(ah0, bh0, acc[0][0], 0, 0, 0);
                acc[0][1] = __builtin_amdgcn_mfma_f32_16x16x32_bf16(ah0, bh1, acc[0][1], 0, 0, 0);
                acc[1][0] = __builtin_amdgcn_mfma_f32_16x16x32_bf16(ah1, bh0, acc[1][0], 0, 0, 0);
                acc[1][1] = __builtin_amdgcn_mfma_f32_16x16x32_bf16(ah1, bh1, acc[1][1], 0, 0, 0);
                acc[0][0] = __builtin_amdgcn_mfma_f32_16x16x32_bf16(ah0, bl0, acc[0][0], 0, 0, 0);
                acc[0][1] = __builtin_amdgcn_mfma_f32_16x16x32_bf16(ah0, bl1, acc[0][1], 0, 0, 0);
                acc[1][0] = __builtin_amdgcn_mfma_f32_16x16x32_bf16(ah1, bl0, acc[1][0], 0, 0, 0);
                acc[1][1] = __builtin_amdgcn_mfma_f32_16x16x32_bf16(ah1, bl1, acc[1][1], 0, 0, 0);
                acc[0][0] = __builtin_amdgcn_mfma_f32_16x16x32_bf16(al0, bh0, acc[0][0], 0, 0, 0);
                acc[0][1] = __builtin_amdgcn_mfma_f32_16x16x32_bf16(al0, bh1, acc[0][1], 0, 0, 0);
                acc[1][0] = __builtin_amdgcn_mfma_f32_16x16x32_bf16(al1, bh0, acc[1][0], 0, 0, 0);
                acc[1][1] = __builtin_amdgcn_mfma_f32_16x16x32_bf16(al1, bh1, acc[1][1], 0, 0, 0);
            }
        }
    }
    // epilogue: C[row=pixel][col=channel]; row=(l>>4)*4+j, col=l&15
    float bias0 = b0[n_base + r];
    float bias1 = b0[n_base + 16 + r];
    #pragma unroll
    for (int mf = 0; mf < 2; ++mf) {
        #pragma unroll
        for (int nf = 0; nf < 2; ++nf) {
            int ch = n_base + nf * 16 + r;
            float bias = nf ? bias1 : bias0;
            float* op = c1 + ((size_t)b * 64 + ch) * 289;
            #pragma unroll
            for (int j = 0; j < 4; ++j) {
                int pix = p_base + mf * 16 + q * 4 + j;
                if (pix < 289) {
                    float v = acc[mf][nf][j] + bias;
                    op[pix] = v > 0.f ? v : 0.f;
                }
            }
        }
    }
}

// ------------------------------- conv1 (dil=2) -----------------------------
__global__ __launch_bounds__(256) void sac_conv1(const float* __restrict__ c1,
                                                 const float* __restrict__ w1t,
                                                 const float* __restrict__ b1,
                                                 float* __restrict__ c2) {
    int blk = blockIdx.x;
    int b = blk / 13, oy = blk % 13;
    __shared__ float xs[64 * 51 + 8];
    __shared__ float wsh[16 * 9 * 64];
    int tid = threadIdx.x;
    for (int f = tid; f < 64 * 51; f += 256) {
        int ic = f / 51, r = f - ic * 51;
        int dy = r / 17, ix = r - dy * 17;
        xs[f] = c1[((size_t)(b * 64 + ic) * 17 + oy + 2 * dy) * 17 + ix];
    }
    if (tid < 8) xs[64 * 51 + tid] = 0.f;
    int c = tid & 63, g = tid >> 6;
    float acc[4] = {0.f, 0.f, 0.f, 0.f};
    for (int ic0 = 0; ic0 < 64; ic0 += 16) {
        __syncthreads();
        for (int f = tid; f < 16 * 9 * 64; f += 256) wsh[f] = w1t[ic0 * 576 + f];
        __syncthreads();
        #pragma unroll 4
        for (int icl = 0; icl < 16; ++icl) {
            const float* xr = &xs[(ic0 + icl) * 51];
            const float* wr = &wsh[icl * 576 + c];
            #pragma unroll
            for (int ky = 0; ky < 3; ++ky) {
                float w0v = wr[ky * 192], w1v = wr[ky * 192 + 64], w2v = wr[ky * 192 + 128];
                const float* xq = xr + ky * 17;
                #pragma unroll
                for (int t = 0; t < 4; ++t) {
                    int ox = g + 4 * t;
                    acc[t] += w0v * xq[ox] + w1v * xq[ox + 2] + w2v * xq[ox + 4];
                }
            }
        }
    }
    float bias = b1[c];
    float* outp = c2 + ((size_t)b * 64 + c) * 169 + oy * 13;
    #pragma unroll
    for (int t = 0; t < 4; ++t) {
        int ox = g + 4 * t;
        if (ox < 13) { float v = acc[t] + bias; outp[ox] = v > 0.f ? v : 0.f; }
    }
}

// ------------------------------- conv2 (dil=3) -----------------------------
__global__ __launch_bounds__(256) void sac_conv2(const float* __restrict__ c2,
                                                 const float* __restrict__ w2t,
                                                 const float* __restrict__ b2,
                                                 float* __restrict__ xx1) {
    int b = blockIdx.x;
    __shared__ float xs[64 * 169];
    __shared__ float wsh[8 * 9 * 64];
    int tid = threadIdx.x;
    for (int f = tid; f < 64 * 169; f += 256) xs[f] = c2[(size_t)b * 10816 + f];
    int c = tid & 63, g = tid >> 6;
    int pyv[13], pxv[13];
    #pragma unroll
    for (int t = 0; t < 13; ++t) { int p = g + 4 * t; pyv[t] = p / 7; pxv[t] = p - (p / 7) * 7; }
    float acc[13];
    #pragma unroll
    for (int t = 0; t < 13; ++t) acc[t] = 0.f;
    for (int ic0 = 0; ic0 < 64; ic0 += 8) {
        __syncthreads();
        for (int f = tid; f < 8 * 9 * 64; f += 256) wsh[f] = w2t[ic0 * 576 + f];
        __syncthreads();
        #pragma unroll 2
        for (int icl = 0; icl < 8; ++icl) {
            const float* xr = &xs[(ic0 + icl) * 169];
            const float* wr = &wsh[icl * 576 + c];
            #pragma unroll
            for (int ky = 0; ky < 3; ++ky) {
                float w0v = wr[ky * 192], w1v = wr[ky * 192 + 64], w2v = wr[ky * 192 + 128];
                #pragma unroll
                for (int t = 0; t < 13; ++t) {
                    int p = g + 4 * t;
                    if (p < 49) {
                        const float* xq = xr + (pyv[t] + 3 * ky) * 13 + pxv[t];
                        acc[t] += w0v * xq[0] + w1v * xq[3] + w2v * xq[6];
                    }
                }
            }
        }
    }
    float bias = b2[c];
    float* outp = xx1 + ((size_t)b * 64 + c) * 49;
    #pragma unroll
    for (int t = 0; t < 13; ++t) {
        int p = g + 4 * t;
        if (p < 49) { float v = acc[t] + bias; outp[p] = v > 0.f ? v : 0.f; }
    }
}

// ------------------- 1x1 convs a/b/g (relu only on g) ----------------------
__global__ __launch_bounds__(256) void sac_abg(const float* __restrict__ xx1,
                                               const float* __restrict__ wa,
                                               const float* __restrict__ wb,
                                               const float* __restrict__ wg,
                                               float* __restrict__ alpha,
                                               float* __restrict__ beta,
                                               float* __restrict__ gam) {
    int b = blockIdx.x, tid = threadIdx.x;
    __shared__ float xsm[3136];
    __shared__ float ws3[3 * 2048];
    for (int f = tid; f < 3136; f += 256) xsm[f] = xx1[(size_t)b * 3136 + f];
    for (int f = tid; f < 2048; f += 256) {
        ws3[f] = wa[f]; ws3[2048 + f] = wb[f]; ws3[4096 + f] = wg[f];
    }
    __syncthreads();
    for (int f = tid; f < 4704; f += 256) {
        int which = f / 1568, r = f - which * 1568;
        int t = r / 49, p = r - t * 49;
        const float* w = &ws3[which * 2048 + t * 64];
        float s = 0.f;
        #pragma unroll 8
        for (int c = 0; c < 64; ++c) s += w[c] * xsm[c * 49 + p];
        if (which == 2) s = s > 0.f ? s : 0.f;
        float* o = (which == 0) ? alpha : (which == 1) ? beta : gam;
        o[(size_t)b * 1568 + r] = s;
    }
}

// --------------------- ctx = alpha(raw reshape) @ beta ---------------------
__global__ __launch_bounds__(256) void sac_ctx(const float* __restrict__ alpha,
                                               const float* __restrict__ beta,
                                               float* __restrict__ ctx) {
    int b = blockIdx.x, tid = threadIdx.x;
    __shared__ float af[1568];
    __shared__ float bt[1568];
    for (int f = tid; f < 1568; f += 256) {
        af[f] = alpha[(size_t)b * 1568 + f];
        bt[f] = beta[(size_t)b * 1568 + f];
    }
    __syncthreads();
    for (int f = tid; f < 2401; f += 256) {
        int i = f / 49, l = f - i * 49;
        float s = 0.f;
        #pragma unroll 8
        for (int j = 0; j < 32; ++j) s += af[i * 32 + j] * bt[j * 49 + l];
        ctx[(size_t)b * 2401 + f] = s;
    }
}

// --------------------- softmax over BATCH axis (dim 0) ---------------------
__global__ __launch_bounds__(256) void sac_softmax0(float* __restrict__ ctx) {
    int pos = blockIdx.x;              // 0..2400
    int tid = threadIdx.x;
    float v0 = ctx[(size_t)tid * 2401 + pos];
    float v1 = ctx[(size_t)(tid + 256) * 2401 + pos];
    float m = fmaxf(v0, v1);
    #pragma unroll
    for (int off = 32; off > 0; off >>= 1) m = fmaxf(m, __shfl_xor(m, off, 64));
    __shared__ float sred[4];
    __shared__ float ssum[4];
    int lane = tid & 63, wid = tid >> 6;
    if (lane == 0) sred[wid] = m;
    __syncthreads();
    m = fmaxf(fmaxf(sred[0], sred[1]), fmaxf(sred[2], sred[3]));
    float e0 = expf(v0 - m), e1 = expf(v1 - m);
    float s = e0 + e1;
    #pragma unroll
    for (int off = 32; off > 0; off >>= 1) s += __shfl_xor(s, off, 64);
    if (lane == 0) ssum[wid] = s;
    __syncthreads();
    float inv = 1.f / (ssum[0] + ssum[1] + ssum[2] + ssum[3]);
    ctx[(size_t)tid * 2401 + pos] = e0 * inv;
    ctx[(size_t)(tid + 256) * 2401 + pos] = e1 * inv;
}

// --------------------------- ctx2 = gam @ ctx ------------------------------
__global__ __launch_bounds__(256) void sac_ctx2(const float* __restrict__ gam,
                                                const float* __restrict__ ctx,
                                                float* __restrict__ ctx2) {
    int b = blockIdx.x, tid = threadIdx.x;
    __shared__ float gs[1568];
    __shared__ float cs[2401];
    for (int f = tid; f < 1568; f += 256) gs[f] = gam[(size_t)b * 1568 + f];
    for (int f = tid; f < 2401; f += 256) cs[f] = ctx[(size_t)b * 2401 + f];
    __syncthreads();
    for (int f = tid; f < 1568; f += 256) {
        int t = f / 49, l = f - t * 49;
        float s = 0.f;
        #pragma unroll 7
        for (int i = 0; i < 49; ++i) s += gs[t * 49 + i] * cs[i * 49 + l];
        ctx2[(size_t)b * 1568 + f] = s;
    }
}

// ----------------- xx2 = relu(wd @ ctx2) + xx1 -----------------------------
__global__ __launch_bounds__(256) void sac_xx2(const float* __restrict__ ctx2,
                                               const float* __restrict__ wd,
                                               const float* __restrict__ xx1,
                                               float* __restrict__ xx2) {
    int b = blockIdx.x, tid = threadIdx.x;
    __shared__ float cs[1568];
    __shared__ float wds[2048];
    for (int f = tid; f < 1568; f += 256) cs[f] = ctx2[(size_t)b * 1568 + f];
    for (int f = tid; f < 2048; f += 256) wds[f] = wd[f];
    __syncthreads();
    for (int f = tid; f < 3136; f += 256) {
        int c = f / 49, p = f - c * 49;
        float s = 0.f;
        #pragma unroll 8
        for (int t = 0; t < 32; ++t) s += wds[c * 32 + t] * cs[t * 49 + p];
        s = s > 0.f ? s : 0.f;
        xx2[(size_t)b * 3136 + f] = s + xx1[(size_t)b * 3136 + f];
    }
}

// ------------------- Z = relu(wenc @ xx2), layout (b,p,d) ------------------
__global__ __launch_bounds__(256) void sac_z(const float* __restrict__ xx2,
                                             const float* __restrict__ wenc,
                                             float* __restrict__ Z) {
    int b = blockIdx.x, tid = threadIdx.x;
    __shared__ float xsm[3136];
    __shared__ float wt[2048];   // [c][d]
    for (int f = tid; f < 3136; f += 256) xsm[f] = xx2[(size_t)b * 3136 + f];
    for (int f = tid; f < 2048; f += 256) { int d = f >> 6, c = f & 63; wt[c * 32 + d] = wenc[f]; }
    __syncthreads();
    for (int f = tid; f < 1568; f += 256) {
        int p = f >> 5, d = f & 31;
        float s = 0.f;
        #pragma unroll 8
        for (int c = 0; c < 64; ++c) s += wt[c * 32 + d] * xsm[c * 49 + p];
        Z[(size_t)b * 1568 + f] = s > 0.f ? s : 0.f;
    }
}

// ----------------------- dist (pre-softmax) --------------------------------
__global__ __launch_bounds__(256) void sac_dist(const float* __restrict__ Z,
                                                const float* __restrict__ cw,
                                                const float* __restrict__ scale,
                                                float* __restrict__ A) {
    __shared__ float cws[1536];
    __shared__ float c2s[48];
    __shared__ float scs[48];
    int tid = threadIdx.x;
    for (int f = tid; f < 1536; f += 256) cws[f] = cw[f];
    if (tid < 48) scs[tid] = scale[tid];
    __syncthreads();
    if (tid < 48) {
        float s = 0.f;
        for (int d = 0; d < 32; ++d) { float v = cws[tid * 32 + d]; s += v * v; }
        c2s[tid] = s;
    }
    __syncthreads();
    int idx = blockIdx.x * 256 + tid;      // (b,p) over 25088
    if (idx >= 25088) return;
    const float4* zp = (const float4*)(Z + (size_t)idx * 32);
    float zr[32];
    #pragma unroll
    for (int q = 0; q < 8; ++q) {
        float4 v = zp[q];
        zr[q * 4] = v.x; zr[q * 4 + 1] = v.y; zr[q * 4 + 2] = v.z; zr[q * 4 + 3] = v.w;
    }
    float z2 = 0.f;
    #pragma unroll
    for (int d = 0; d < 32; ++d) z2 += zr[d] * zr[d];
    float* ap = A + (size_t)idx * 48;
    for (int k = 0; k < 48; ++k) {
        float dot = 0.f;
        #pragma unroll
        for (int d = 0; d < 32; ++d) dot += zr[d] * cws[k * 32 + d];
        ap[k] = scs[k] * (z2 + c2s[k] - 2.f * dot);
    }
}

// ----------------------- softmax over k (48) -------------------------------
__global__ __launch_bounds__(256) void sac_asoft(float* __restrict__ A) {
    int idx = blockIdx.x * 256 + threadIdx.x;
    if (idx >= 25088) return;
    float* ap = A + (size_t)idx * 48;
    float v[48];
    float m = -1e30f;
    #pragma unroll
    for (int k = 0; k < 48; ++k) { v[k] = ap[k]; m = fmaxf(m, v[k]); }
    float s = 0.f;
    #pragma unroll
    for (int k = 0; k < 48; ++k) { v[k] = expf(v[k] - m); s += v[k]; }
    float inv = 1.f / s;
    #pragma unroll
    for (int k = 0; k < 48; ++k) ap[k] = v[k] * inv;
}

// ------------- E[b,k,d] = sum_p A*Z - (sum_p A) * C ------------------------
__global__ __launch_bounds__(256) void sac_e(const float* __restrict__ A,
                                             const float* __restrict__ Z,
                                             const float* __restrict__ cw,
                                             float* __restrict__ E) {
    int b = blockIdx.x, tid = threadIdx.x;
    __shared__ float As[2352];
    __shared__ float Zs[1568];
    __shared__ float asum[48];
    for (int f = tid; f < 2352; f += 256) As[f] = A[(size_t)b * 2352 + f];
    for (int f = tid; f < 1568; f += 256) Zs[f] = Z[(size_t)b * 1568 + f];
    __syncthreads();
    if (tid < 48) {
        float s = 0.f;
        for (int p = 0; p < 49; ++p) s += As[p * 48 + tid];
        asum[tid] = s;
    }
    __syncthreads();
    for (int f = tid; f < 1536; f += 256) {
        int k = f >> 5, d = f & 31;
        float s = 0.f;
        #pragma unroll 7
        for (int p = 0; p < 49; ++p) s += As[p * 48 + k] * Zs[p * 32 + d];
        E[(size_t)b * 1536 + f] = s - asum[k] * cw[f];
    }
}

// ------------------- BatchNorm stats per code k ----------------------------
__global__ __launch_bounds__(256) void sac_bnstat(const float* __restrict__ E,
                                                  float* __restrict__ bns) {
    int k = blockIdx.x, tid = threadIdx.x;
    __shared__ float sr[4];
    float s = 0.f;
    for (int i = tid; i < 16384; i += 256) {
        int b = i >> 5, d = i & 31;
        s += E[((size_t)b * 48 + k) * 32 + d];
    }
    #pragma unroll
    for (int off = 32; off > 0; off >>= 1) s += __shfl_xor(s, off, 64);
    int lane = tid & 63, wid = tid >> 6;
    if (lane == 0) sr[wid] = s;
    __syncthreads();
    float mu = (sr[0] + sr[1] + sr[2] + sr[3]) / 16384.f;
    float q = 0.f;
    for (int i = tid; i < 16384; i += 256) {
        int b = i >> 5, d = i & 31;
        float v = E[((size_t)b * 48 + k) * 32 + d] - mu;
        q += v * v;
    }
    #pragma unroll
    for (int off = 32; off > 0; off >>= 1) q += __shfl_xor(q, off, 64);
    __syncthreads();
    if (lane == 0) sr[wid] = q;
    __syncthreads();
    if (tid == 0) {
        float var = (sr[0] + sr[1] + sr[2] + sr[3]) / 16384.f;
        bns[k] = mu;
        bns[48 + k] = rsqrtf(var + 1e-5f);
    }
}

// ---------------- BN+relu -> E_sum -> gate -> xx3 --------------------------
__global__ __launch_bounds__(256) void sac_gate(const float* __restrict__ E,
                                                const float* __restrict__ bns,
                                                const float* __restrict__ bn_g,
                                                const float* __restrict__ bn_b,
                                                const float* __restrict__ w_att,
                                                const float* __restrict__ b_att,
                                                const float* __restrict__ xx2,
                                                float* __restrict__ xx3) {
    int b = blockIdx.x, tid = threadIdx.x;
    __shared__ float esd[32];
    __shared__ float gs[64];
    if (tid < 32) {
        int d = tid;
        float s = 0.f;
        for (int k = 0; k < 48; ++k) {
            float v = (E[((size_t)b * 48 + k) * 32 + d] - bns[k]) * bns[48 + k] * bn_g[k] + bn_b[k];
            s += v > 0.f ? v : 0.f;
        }
        esd[d] = s;
    }
    __syncthreads();
    if (tid < 64) {
        int c = tid;
        float a = b_att[c];
        #pragma unroll 8
        for (int d = 0; d < 32; ++d) a += esd[d] * w_att[c * 32 + d];
        gs[c] = 1.f / (1.f + expf(-a)) + 1.f;     // 1 + gate
    }
    __syncthreads();
    for (int f = tid; f < 3136; f += 256) {
        int c = f / 49;
        xx3[(size_t)b * 3136 + f] = xx2[(size_t)b * 3136 + f] * gs[c];
    }
}

// ---------------- d1 GEMM (split-K over 7 slab-aligned chunks) -------------
__global__ __launch_bounds__(256) void sac_d1gemm(const float* __restrict__ c1,
                                                  const float* __restrict__ c2,
                                                  const float* __restrict__ xx3,
                                                  const float* __restrict__ weff1,
                                                  const float* __restrict__ weff2,
                                                  const float* __restrict__ weff3,
                                                  float* __restrict__ h1p) {
    int blk = blockIdx.x;            // 7*32
    int s = blk >> 5;
    int r = blk & 31;
    int b0 = (r >> 2) * 64, o0 = (r & 3) * 64;
    const float* Ab; const float* Wb; int astr, klen;
    if (s < 4)      { Ab = c1 + s * 4624;       Wb = weff1 + s * 4624;       astr = 18496; klen = 4624; }
    else if (s < 6) { Ab = c2 + (s - 4) * 5408; Wb = weff2 + (s - 4) * 5408; astr = 10816; klen = 5408; }
    else            { Ab = xx3;                 Wb = weff3;                  astr = 3136;  klen = 3136; }
    __shared__ float As[16][68];
    __shared__ float Wsh[16][68];
    int tid = threadIdx.x;
    int tx = tid & 15, ty = tid >> 4;
    int bi = tid >> 2, kq = tid & 3;
    const float* aP = Ab + (size_t)(b0 + bi) * astr + kq * 4;
    const float* wP = Wb + (size_t)(o0 + bi) * astr + kq * 4;
    float acc[4][4];
    #pragma unroll
    for (int i = 0; i < 4; ++i)
        #pragma unroll
        for (int j = 0; j < 4; ++j) acc[i][j] = 0.f;
    for (int k0 = 0; k0 < klen; k0 += 16) {
        float4 av = *(const float4*)(aP + k0);
        float4 wv = *(const float4*)(wP + k0);
        __syncthreads();
        As[kq * 4 + 0][bi] = av.x; As[kq * 4 + 1][bi] = av.y;
        As[kq * 4 + 2][bi] = av.z; As[kq * 4 + 3][bi] = av.w;
        Wsh[kq * 4 + 0][bi] = wv.x; Wsh[kq * 4 + 1][bi] = wv.y;
        Wsh[kq * 4 + 2][bi] = wv.z; Wsh[kq * 4 + 3][bi] = wv.w;
        __syncthreads();
        #pragma unroll
        for (int kk = 0; kk < 16; ++kk) {
            float4 a4 = *(const float4*)&As[kk][ty * 4];
            float4 w4 = *(const float4*)&Wsh[kk][tx * 4];
            acc[0][0] += a4.x * w4.x; acc[0][1] += a4.x * w4.y; acc[0][2] += a4.x * w4.z; acc[0][3] += a4.x * w4.w;
            acc[1][0] += a4.y * w4.x; acc[1][1] += a4.y * w4.y; acc[1][2] += a4.y * w4.z; acc[1][3] += a4.y * w4.w;
            acc[2][0] += a4.z * w4.x; acc[2][1] += a4.z * w4.y; acc[2][2] += a4.z * w4.z; acc[2][3] += a4.z * w4.w;
            acc[3][0] += a4.w * w4.x; acc[3][1] += a4.w * w4.y; acc[3][2] += a4.w * w4.z; acc[3][3] += a4.w * w4.w;
        }
    }
    float* op = h1p + ((size_t)s * 512 + b0 + ty * 4) * 256 + o0 + tx * 4;
    #pragma unroll
    for (int i = 0; i < 4; ++i) {
        float4 v; v.x = acc[i][0]; v.y = acc[i][1]; v.z = acc[i][2]; v.w = acc[i][3];
        *(float4*)(op + i * 256) = v;
    }
}

// ---------------- h1 = relu(sum partials + bias) ---------------------------
__global__ __launch_bounds__(256) void sac_h1red(const float* __restrict__ h1p,
                                                 const float* __restrict__ b_d1,
                                                 float* __restrict__ h1) {
    int i = blockIdx.x * 256 + threadIdx.x;    // 131072
    int o = i & 255;
    float s = b_d1[o];
    #pragma unroll
    for (int t = 0; t < 7; ++t) s += h1p[(size_t)t * 131072 + i];
    h1[i] = s > 0.f ? s : 0.f;
}

// ---------------- h2 = relu(h1 @ w_d2.T + b_d2) ----------------------------
__global__ __launch_bounds__(256) void sac_h2(const float* __restrict__ h1,
                                              const float* __restrict__ w_d2,
                                              const float* __restrict__ b_d2,
                                              float* __restrict__ h2) {
    int idx = blockIdx.x * 256 + threadIdx.x;  // 65536
    int b = idx >> 7, o = idx & 127;
    const float* hp = h1 + b * 256;
    const float* wp = w_d2 + o * 256;
    float s = b_d2[o];
    #pragma unroll 4
    for (int k = 0; k < 256; ++k) s += hp[k] * wp[k];
    h2[idx] = s > 0.f ? s : 0.f;
}

// ---------------- out = h2 @ w_d3.T + b_d3 ---------------------------------
__global__ __launch_bounds__(256) void sac_out(const float* __restrict__ h2,
                                               const float* __restrict__ w_d3,
                                               const float* __restrict__ b_d3,
                                               float* __restrict__ out) {
    int idx = blockIdx.x * 256 + threadIdx.x;  // 8192
    int b = idx >> 4, j = idx & 15;
    const float* hp = h2 + b * 128;
    const float* wp = w_d3 + j * 128;
    float s = b_d3[j];
    #pragma unroll 4
    for (int k = 0; k < 128; ++k) s += hp[k] * wp[k];
    out[idx] = s;
}

// ---------------------------------------------------------------------------
extern "C" void kernel_launch(void* const* d_in, const int* in_sizes, int n_in,
                              void* d_out, int out_size, void* d_ws, size_t ws_size,
                              hipStream_t stream) {
    (void)in_sizes; (void)n_in; (void)out_size; (void)ws_size;
    const float* x     = (const float*)d_in[0];
    const float* w0    = (const float*)d_in[1];
    const float* b0    = (const float*)d_in[2];
    const float* w1    = (const float*)d_in[3];
    const float* b1    = (const float*)d_in[4];
    const float* w2    = (const float*)d_in[5];
    const float* b2    = (const float*)d_in[6];
    const float* wa    = (const float*)d_in[7];
    const float* wb    = (const float*)d_in[8];
    const float* wg    = (const float*)d_in[9];
    const float* wd    = (const float*)d_in[10];
    const float* wenc  = (const float*)d_in[11];
    const float* cw    = (const float*)d_in[12];
    const float* scale = (const float*)d_in[13];
    const float* w_att = (const float*)d_in[14];
    const float* b_att = (const float*)d_in[15];
    const float* bn_g  = (const float*)d_in[16];
    const float* bn_b  = (const float*)d_in[17];
    const float* w_d1  = (const float*)d_in[18];
    const float* b_d1  = (const float*)d_in[19];
    const float* w_d2  = (const float*)d_in[20];
    const float* b_d2  = (const float*)d_in[21];
    const float* w_d3  = (const float*)d_in[22];
    const float* b_d3  = (const float*)d_in[23];

    float* ws    = (float*)d_ws;
    float* W1T   = ws + OFF_W1T;
    float* W2T   = ws + OFF_W2T;
    float* WEFF1 = ws + OFF_WEFF1;
    float* WEFF2 = ws + OFF_WEFF2;
    float* WEFF3 = ws + OFF_WEFF3;
    float* TMP   = ws + OFF_C1;     // alias: weff build finishes before conv0 writes C1
    float* C1    = ws + OFF_C1;
    float* C2    = ws + OFF_C2;
    float* XX1   = ws + OFF_XX1;
    float* ALPHA = ws + OFF_ALPHA;
    float* BETA  = ws + OFF_BETA;
    float* GAM   = ws + OFF_GAM;
    float* CTX   = ws + OFF_CTX;
    float* H1P   = ws + OFF_CTX;    // alias: ctx dead after sac_ctx2
    float* CTX2  = ws + OFF_CTX2;
    float* XX2   = ws + OFF_XX2;
    float* Z     = ws + OFF_Z;
    float* A     = ws + OFF_A;
    float* E     = ws + OFF_E;
    float* BNS   = ws + OFF_BNS;
    float* XX3   = ws + OFF_XX3;
    float* H1    = ws + OFF_H1;
    float* H2    = ws + OFF_H2;
    unsigned short* WH = (unsigned short*)(ws + OFF_WH);  // alias ALPHA (dead until sac_abg)
    unsigned short* WL = (unsigned short*)(ws + OFF_WL);

    // weight prep
    sac_twt<<<144, 256, 0, stream>>>(w1, W1T, 64);
    sac_twt<<<144, 256, 0, stream>>>(w2, W2T, 64);
    sac_wsplit<<<504, 256, 0, stream>>>(w0, WH, WL);

    // fold bilinear upsample into w_d1 (three parts: c1u, c2u, ctx3)
    sac_upA<<<20672, 256, 0, stream>>>(w_d1, TMP, 17, 0);
    sac_upB<<<18496, 256, 0, stream>>>(TMP, WEFF1, 17);
    sac_upA<<<15808, 256, 0, stream>>>(w_d1, TMP, 13, 64);
    sac_upB<<<10816, 256, 0, stream>>>(TMP, WEFF2, 13);
    sac_upA<<<8512, 256, 0, stream>>>(w_d1, TMP, 7, 128);
    sac_upB<<<3136, 256, 0, stream>>>(TMP, WEFF3, 7);

    // backbone
    sac_conv0_mfma<<<2560, 256, 0, stream>>>(x, WH, WL, b0, C1);
    sac_conv1<<<512 * 13, 256, 0, stream>>>(C1, W1T, b1, C2);
    sac_conv2<<<512, 256, 0, stream>>>(C2, W2T, b2, XX1);

    // non-local block
    sac_abg<<<512, 256, 0, stream>>>(XX1, wa, wb, wg, ALPHA, BETA, GAM);
    sac_ctx<<<512, 256, 0, stream>>>(ALPHA, BETA, CTX);
    sac_softmax0<<<2401, 256, 0, stream>>>(CTX);
    sac_ctx2<<<512, 256, 0, stream>>>(GAM, CTX, CTX2);
    sac_xx2<<<512, 256, 0, stream>>>(CTX2, wd, XX1, XX2);

    // soft VQ encoding + gate
    sac_z<<<512, 256, 0, stream>>>(XX2, wenc, Z);
    sac_dist<<<98, 256, 0, stream>>>(Z, cw, scale, A);
    sac_asoft<<<98, 256, 0, stream>>>(A);
    sac_e<<<512, 256, 0, stream>>>(A, Z, cw, E);
    sac_bnstat<<<48, 256, 0, stream>>>(E, BNS);
    sac_gate<<<512, 256, 0, stream>>>(E, BNS, bn_g, bn_b, w_att, b_att, XX2, XX3);

    // dense head (upsample folded into WEFF)
    sac_d1gemm<<<224, 256, 0, stream>>>(C1, C2, XX3, WEFF1, WEFF2, WEFF3, H1P);
    sac_h1red<<<512, 256, 0, stream>>>(H1P, b_d1, H1);
    sac_h2<<<256, 256, 0, stream>>>(H1, w_d2, b_d2, H2);
    sac_out<<<32, 256, 0, stream>>>(H2, w_d3, b_d3, (float*)d_out);
}

// Round 4
// 1091.226 us; speedup vs baseline: 3.9626x; 1.4240x over previous
//
#include <hip/hip_runtime.h>
#include <math.h>

// ---------------------------------------------------------------------------
// SACNet forward. conv0/1/2 = split-bf16 MFMA implicit GEMM (LDS-staged);
// rest fp32.  B=512, IN=200, P=19, CF=64, TF=32, K=48, D=32, NC=16
// ---------------------------------------------------------------------------

typedef __attribute__((ext_vector_type(8))) short short8v;   // 8 bf16
typedef __attribute__((ext_vector_type(4))) float f32x4;

// workspace offsets (in floats)
#define OFF_W1T   115200u      // (unused)
#define OFF_WEFF1 188928u      // 256*64*289 = 4734976
#define OFF_WEFF2 4923904u     // 256*64*169 = 2768896
#define OFF_WEFF3 7692800u     // 256*64*49  = 802816
#define OFF_C1    8495616u     // 512*64*289 = 9469952 (TMP aliases this while building weff)
#define OFF_C2    17965568u    // 512*64*169 = 5537792
#define OFF_XX1   23503360u    // 512*64*49  = 1605632
#define OFF_ALPHA 25108992u    // 512*1568   (weight splits alias this region pre-abg)
#define OFF_BETA  25911808u
#define OFF_GAM   26714624u
#define OFF_CTX   27517440u    // 512*2401 (H1P aliases this at dense phase)
#define OFF_CTX2  28746752u
#define OFF_XX2   29549568u    // 512*3136
#define OFF_Z     31155200u    // 512*49*32
#define OFF_A     31958016u    // 512*49*48
#define OFF_E     33162240u    // 512*48*32
#define OFF_BNS   33948672u    // 96
#define OFF_XX3   33948768u    // 512*3136
#define OFF_H1    35554400u    // 512*256
#define OFF_H2    35685472u    // 512*128

// conv0 weights: 9*64*224 = 129024 shorts = 64512 floats each.
#define OFF_WH    OFF_ALPHA
#define OFF_WL    (OFF_ALPHA + 64512u)
// conv1/conv2 weights: 9*64*64 = 36864 shorts = 18432 floats each.
#define OFF_W1H   (OFF_ALPHA + 129024u)
#define OFF_W1L   (OFF_W1H + 18432u)
#define OFF_W2H   (OFF_W1L + 18432u)
#define OFF_W2L   (OFF_W2H + 18432u)
// ends at OFF_ALPHA+202752 = 25311744 < OFF_BETA (25911808). All dead before sac_abg.

__device__ __forceinline__ unsigned bf16_rne_bits(float v) {
    unsigned u = __float_as_uint(v);
    return (u + 0x7FFFu + ((u >> 16) & 1u)) >> 16;
}

// -------------------- split w0 into bf16 hi/lo [s][c][224] -----------------
__global__ __launch_bounds__(256) void sac_wsplit(const float* __restrict__ w0,
                                                  unsigned short* __restrict__ WH,
                                                  unsigned short* __restrict__ WL) {
    int idx = blockIdx.x * 256 + threadIdx.x;   // 9*64*224 = 129024
    if (idx >= 129024) return;
    int ic = idx % 224;
    int c  = (idx / 224) % 64;
    int s  = idx / (224 * 64);
    int ky = s / 3, kx = s % 3;
    float v = 0.f;
    if (ic < 200) v = w0[((c * 200 + ic) * 3 + ky) * 3 + kx];
    unsigned hb = bf16_rne_bits(v);
    float hf = __uint_as_float(hb << 16);
    unsigned lb = bf16_rne_bits(v - hf);
    WH[idx] = (unsigned short)hb;
    WL[idx] = (unsigned short)lb;
}

// -------------------- split 64x64x3x3 weights into [s][c][64] --------------
__global__ __launch_bounds__(256) void sac_wsplit64(const float* __restrict__ wsrc,
                                                    unsigned short* __restrict__ WHo,
                                                    unsigned short* __restrict__ WLo) {
    int idx = blockIdx.x * 256 + threadIdx.x;   // 36864
    if (idx >= 36864) return;
    int ic = idx & 63;
    int c  = (idx >> 6) & 63;
    int s  = idx >> 12;
    int ky = s / 3, kx = s - ky * 3;
    float v = wsrc[((c * 64 + ic) * 3 + ky) * 3 + kx];
    unsigned hb = bf16_rne_bits(v);
    float hf = __uint_as_float(hb << 16);
    unsigned lb = bf16_rne_bits(v - hf);
    WHo[idx] = (unsigned short)hb;
    WLo[idx] = (unsigned short)lb;
}

// --------------------- fold bilinear upsample into w_d1 --------------------
__global__ __launch_bounds__(256) void sac_upA(const float* __restrict__ w_d1,
                                               float* __restrict__ tmp, int S, int co) {
    int idx = blockIdx.x * 256 + threadIdx.x;
    int total = 256 * 64 * 19 * S;
    if (idx >= total) return;
    int xp = idx % S;
    int j  = (idx / S) % 19;
    int c  = (idx / (S * 19)) % 64;
    int o  = idx / (S * 19 * 64);
    const float* wrow = w_d1 + (size_t)o * 69312 + (size_t)(co + c) * 361 + j * 19;
    float ratio = (float)(S - 1) / 18.0f;
    float s = 0.f;
    for (int i = 0; i < 19; ++i) {
        float xs = i * ratio;
        int x0 = (int)floorf(xs);
        float wx = xs - (float)x0;
        int x1 = x0 + 1; if (x1 > S - 1) x1 = S - 1;
        float cf = (xp == x0 ? 1.f - wx : 0.f) + (xp == x1 ? wx : 0.f);
        s += cf * wrow[i];
    }
    tmp[idx] = s;
}
__global__ __launch_bounds__(256) void sac_upB(const float* __restrict__ tmp,
                                               float* __restrict__ weff, int S) {
    int idx = blockIdx.x * 256 + threadIdx.x;
    int total = 256 * 64 * S * S;
    if (idx >= total) return;
    int xp = idx % S;
    int yp = (idx / S) % S;
    int c  = (idx / (S * S)) % 64;
    int o  = idx / (S * S * 64);
    const float* tp = tmp + (((size_t)o * 64 + c) * 19) * S + xp;
    float ratio = (float)(S - 1) / 18.0f;
    float s = 0.f;
    for (int j = 0; j < 19; ++j) {
        float ys = j * ratio;
        int y0 = (int)floorf(ys);
        float wy = ys - (float)y0;
        int y1 = y0 + 1; if (y1 > S - 1) y1 = S - 1;
        float cf = (yp == y0 ? 1.f - wy : 0.f) + (yp == y1 ? wy : 0.f);
        s += cf * tp[j * S];
    }
    weff[idx] = s;
}

// ---------------- generic 3x3 dilated conv, split-bf16 MFMA ----------------
// One block = (batch b, m-tile of 64 output pixels). 4 waves (2x2 of 32x32).
// Input staged once in LDS as hi/lo bf16 with channel-contiguous layout
// ([rc][ch], rc = local input row*IW+col), XOR-swizzled; each A fragment is a
// single ds_read_b128 reused across all 9 taps.
// Weights pre-split to [s][c][WSTR] bf16 hi/lo (WSTR = ch rounded up to 32).
template<int IW, int OW, int DIL, int TOTCH, int WSTR, int NMT, int CPAD, int NCHUNK, int NIRMAX>
__global__ __launch_bounds__(256) void sac_convmfma(const float* __restrict__ x,
                                                    const unsigned short* __restrict__ WHp,
                                                    const unsigned short* __restrict__ WLp,
                                                    const float* __restrict__ bias,
                                                    float* __restrict__ out) {
    constexpr int OP = OW * OW;
    constexpr int ISZ = IW * IW;
    constexpr int TOT32 = ((TOTCH + 31) / 32) * 32;
    __shared__ unsigned short XH[NIRMAX * IW * CPAD];
    __shared__ unsigned short XL[NIRMAX * IW * CPAD];
    int blk = blockIdx.x;
    int b = blk / NMT, mt = blk - b * NMT;
    int tid = threadIdx.x;
    int w = tid >> 6, l = tid & 63;
    int wm = w >> 1, wn = w & 1;
    int q = l >> 4, r = l & 15;
    int p_base = mt * 64 + wm * 32;
    int n_base = wn * 32;
    int pixA = p_base + r;      if (pixA > OP - 1) pixA = OP - 1;
    int pixB = p_base + 16 + r; if (pixB > OP - 1) pixB = OP - 1;
    int pyA = pixA / OW, pxa = pixA - pyA * OW;
    int pyB = pixB / OW, pxb = pixB - pyB * OW;
    int pb0 = mt * 64;
    int ir0 = pb0 / OW;                                 // first input row staged
    int plast = pb0 + 63; if (plast > OP - 1) plast = OP - 1;
    int nir = plast / OW + 2 * DIL - ir0 + 1;           // rows staged (<= NIRMAX)
    int NRC = nir * IW;

    f32x4 acc[2][2];
    #pragma unroll
    for (int i = 0; i < 2; ++i)
        #pragma unroll
        for (int j = 0; j < 2; ++j) { acc[i][j].x = 0.f; acc[i][j].y = 0.f; acc[i][j].z = 0.f; acc[i][j].w = 0.f; }

    for (int cc = 0; cc < NCHUNK; ++cc) {
        int ch0 = cc * CPAD;
        int nch = TOT32 - ch0; if (nch > CPAD) nch = CPAD;
        __syncthreads();
        // ---- stage chunk: global fp32 -> LDS bf16 hi/lo, 2 channels/thread-iter
        int tot = (nch >> 1) * NRC;
        for (int f = tid; f < tot; f += 256) {
            int chl2 = f / NRC, rc = f - chl2 * NRC;
            int ch = ch0 + (chl2 << 1);
            const float* gp = x + (size_t)b * (size_t)(TOTCH * ISZ) + (size_t)ch * ISZ + ir0 * IW + rc;
            float v0 = (ch < TOTCH) ? gp[0] : 0.f;
            float v1 = (ch + 1 < TOTCH) ? gp[ISZ] : 0.f;
            unsigned h0 = bf16_rne_bits(v0); float hf0 = __uint_as_float(h0 << 16);
            unsigned l0 = bf16_rne_bits(v0 - hf0);
            unsigned h1 = bf16_rne_bits(v1); float hf1 = __uint_as_float(h1 << 16);
            unsigned l1 = bf16_rne_bits(v1 - hf1);
            unsigned bo = ((unsigned)((rc * CPAD + (chl2 << 1)) << 1)) ^ (unsigned)(((rc >> 1) & 7) << 4);
            *(unsigned*)((char*)XH + bo) = h0 | (h1 << 16);
            *(unsigned*)((char*)XL + bo) = l0 | (l1 << 16);
        }
        __syncthreads();
        // ---- 9 taps x K-chunks of 32
        int nicc = nch >> 5;
        for (int s = 0; s < 9; ++s) {
            int ky = s / 3, kx = s - ky * 3;
            int rcA = (pyA + DIL * ky - ir0) * IW + pxa + DIL * kx;
            int rcB = (pyB + DIL * ky - ir0) * IW + pxb + DIL * kx;
            const unsigned short* pWH = WHp + (size_t)(s * 64 + n_base + r) * WSTR + ch0 + q * 8;
            const unsigned short* pWL = WLp + (size_t)(s * 64 + n_base + r) * WSTR + ch0 + q * 8;
            for (int icc = 0; icc < nicc; ++icc) {
                int ko = icc * 32;
                unsigned byA = ((unsigned)((rcA * CPAD + ko + q * 8) << 1)) ^ (unsigned)(((rcA >> 1) & 7) << 4);
                unsigned byB = ((unsigned)((rcB * CPAD + ko + q * 8) << 1)) ^ (unsigned)(((rcB >> 1) & 7) << 4);
                short8v ah0 = *(const short8v*)((const char*)XH + byA);
                short8v al0 = *(const short8v*)((const char*)XL + byA);
                short8v ah1 = *(const short8v*)((const char*)XH + byB);
                short8v al1 = *(const short8v*)((const char*)XL + byB);
                short8v bh0 = *(const short8v*)(pWH + ko);
                short8v bh1 = *(const short8v*)(pWH + ko + 16 * WSTR);
                short8v bl0 = *(const short8v*)(pWL + ko);
                short8v bl1 = *(const short8v*)(pWL + ko + 16 * WSTR);
                acc[0][0] = __builtin_amdgcn_mfma_f32_16x16x32_bf16(ah0, bh0, acc[0][0], 0, 0, 0);
                acc[0][1] = __builtin_amdgcn_mfma_f32_16x16x32_bf16(ah0, bh1, acc[0][1], 0, 0, 0);
                acc[1][0] = __builtin_amdgcn_mfma_f32_16x16x32_bf16(ah1, bh0, acc[1][0], 0, 0, 0);
                acc[1][1] = __builtin_amdgcn_mfma_f32_16x16x32_bf16(ah1, bh1, acc[1][1], 0, 0, 0);
                acc[0][0] = __builtin_amdgcn_mfma_f32_16x16x32_bf16(ah0, bl0, acc[0][0], 0, 0, 0);
                acc[0][1] = __builtin_amdgcn_mfma_f32_16x16x32_bf16(ah0, bl1, acc[0][1], 0, 0, 0);
                acc[1][0] = __builtin_amdgcn_mfma_f32_16x16x32_bf16(ah1, bl0, acc[1][0], 0, 0, 0);
                acc[1][1] = __builtin_amdgcn_mfma_f32_16x16x32_bf16(ah1, bl1, acc[1][1], 0, 0, 0);
                acc[0][0] = __builtin_amdgcn_mfma_f32_16x16x32_bf16(al0, bh0, acc[0][0], 0, 0, 0);
                acc[0][1] = __builtin_amdgcn_mfma_f32_16x16x32_bf16(al0, bh1, acc[0][1], 0, 0, 0);
                acc[1][0] = __builtin_amdgcn_mfma_f32_16x16x32_bf16(al1, bh0, acc[1][0], 0, 0, 0);
                acc[1][1] = __builtin_amdgcn_mfma_f32_16x16x32_bf16(al1, bh1, acc[1][1], 0, 0, 0);
            }
        }
    }
    // epilogue: C row = pixel = (l>>4)*4+j, col = channel = l&15
    float bias0 = bias[n_base + r];
    float bias1 = bias[n_base + 16 + r];
    #pragma unroll
    for (int mf = 0; mf < 2; ++mf) {
        #pragma unroll
        for (int nf = 0; nf < 2; ++nf) {
            int ch = n_base + nf * 16 + r;
            float bs = nf ? bias1 : bias0;
            float* op = out + ((size_t)b * 64 + ch) * OP;
            #pragma unroll
            for (int j = 0; j < 4; ++j) {
                int pix = p_base + mf * 16 + q * 4 + j;
                if (pix < OP) {
                    float v = acc[mf][nf][j] + bs;
                    op[pix] = v > 0.f ? v : 0.f;
                }
            }
        }
    }
}

// ------------------- 1x1 convs a/b/g (relu only on g) ----------------------
__global__ __launch_bounds__(256) void sac_abg(const float* __restrict__ xx1,
                                               const float* __restrict__ wa,
                                               const float* __restrict__ wb,
                                               const float* __restrict__ wg,
                                               float* __restrict__ alpha,
                                               float* __restrict__ beta,
                                               float* __restrict__ gam) {
    int b = blockIdx.x, tid = threadIdx.x;
    __shared__ float xsm[3136];
    __shared__ float ws3[3 * 2048];
    for (int f = tid; f < 3136; f += 256) xsm[f] = xx1[(size_t)b * 3136 + f];
    for (int f = tid; f < 2048; f += 256) {
        ws3[f] = wa[f]; ws3[2048 + f] = wb[f]; ws3[4096 + f] = wg[f];
    }
    __syncthreads();
    for (int f = tid; f < 4704; f += 256) {
        int which = f / 1568, r = f - which * 1568;
        int t = r / 49, p = r - t * 49;
        const float* w = &ws3[which * 2048 + t * 64];
        float s = 0.f;
        #pragma unroll 8
        for (int c = 0; c < 64; ++c) s += w[c] * xsm[c * 49 + p];
        if (which == 2) s = s > 0.f ? s : 0.f;
        float* o = (which == 0) ? alpha : (which == 1) ? beta : gam;
        o[(size_t)b * 1568 + r] = s;
    }
}

// --------------------- ctx = alpha(raw reshape) @ beta ---------------------
__global__ __launch_bounds__(256) void sac_ctx(const float* __restrict__ alpha,
                                               const float* __restrict__ beta,
                                               float* __restrict__ ctx) {
    int b = blockIdx.x, tid = threadIdx.x;
    __shared__ float af[1568];
    __shared__ float bt[1568];
    for (int f = tid; f < 1568; f += 256) {
        af[f] = alpha[(size_t)b * 1568 + f];
        bt[f] = beta[(size_t)b * 1568 + f];
    }
    __syncthreads();
    for (int f = tid; f < 2401; f += 256) {
        int i = f / 49, l = f - i * 49;
        float s = 0.f;
        #pragma unroll 8
        for (int j = 0; j < 32; ++j) s += af[i * 32 + j] * bt[j * 49 + l];
        ctx[(size_t)b * 2401 + f] = s;
    }
}

// --------------------- softmax over BATCH axis (dim 0) ---------------------
__global__ __launch_bounds__(256) void sac_softmax0(float* __restrict__ ctx) {
    int pos = blockIdx.x;              // 0..2400
    int tid = threadIdx.x;
    float v0 = ctx[(size_t)tid * 2401 + pos];
    float v1 = ctx[(size_t)(tid + 256) * 2401 + pos];
    float m = fmaxf(v0, v1);
    #pragma unroll
    for (int off = 32; off > 0; off >>= 1) m = fmaxf(m, __shfl_xor(m, off, 64));
    __shared__ float sred[4];
    __shared__ float ssum[4];
    int lane = tid & 63, wid = tid >> 6;
    if (lane == 0) sred[wid] = m;
    __syncthreads();
    m = fmaxf(fmaxf(sred[0], sred[1]), fmaxf(sred[2], sred[3]));
    float e0 = expf(v0 - m), e1 = expf(v1 - m);
    float s = e0 + e1;
    #pragma unroll
    for (int off = 32; off > 0; off >>= 1) s += __shfl_xor(s, off, 64);
    if (lane == 0) ssum[wid] = s;
    __syncthreads();
    float inv = 1.f / (ssum[0] + ssum[1] + ssum[2] + ssum[3]);
    ctx[(size_t)tid * 2401 + pos] = e0 * inv;
    ctx[(size_t)(tid + 256) * 2401 + pos] = e1 * inv;
}

// --------------------------- ctx2 = gam @ ctx ------------------------------
__global__ __launch_bounds__(256) void sac_ctx2(const float* __restrict__ gam,
                                                const float* __restrict__ ctx,
                                                float* __restrict__ ctx2) {
    int b = blockIdx.x, tid = threadIdx.x;
    __shared__ float gs[1568];
    __shared__ float cs[2401];
    for (int f = tid; f < 1568; f += 256) gs[f] = gam[(size_t)b * 1568 + f];
    for (int f = tid; f < 2401; f += 256) cs[f] = ctx[(size_t)b * 2401 + f];
    __syncthreads();
    for (int f = tid; f < 1568; f += 256) {
        int t = f / 49, l = f - t * 49;
        float s = 0.f;
        #pragma unroll 7
        for (int i = 0; i < 49; ++i) s += gs[t * 49 + i] * cs[i * 49 + l];
        ctx2[(size_t)b * 1568 + f] = s;
    }
}

// ----------------- xx2 = relu(wd @ ctx2) + xx1 -----------------------------
__global__ __launch_bounds__(256) void sac_xx2(const float* __restrict__ ctx2,
                                               const float* __restrict__ wd,
                                               const float* __restrict__ xx1,
                                               float* __restrict__ xx2) {
    int b = blockIdx.x, tid = threadIdx.x;
    __shared__ float cs[1568];
    __shared__ float wds[2048];
    for (int f = tid; f < 1568; f += 256) cs[f] = ctx2[(size_t)b * 1568 + f];
    for (int f = tid; f < 2048; f += 256) wds[f] = wd[f];
    __syncthreads();
    for (int f = tid; f < 3136; f += 256) {
        int c = f / 49, p = f - c * 49;
        float s = 0.f;
        #pragma unroll 8
        for (int t = 0; t < 32; ++t) s += wds[c * 32 + t] * cs[t * 49 + p];
        s = s > 0.f ? s : 0.f;
        xx2[(size_t)b * 3136 + f] = s + xx1[(size_t)b * 3136 + f];
    }
}

// ------------------- Z = relu(wenc @ xx2), layout (b,p,d) ------------------
__global__ __launch_bounds__(256) void sac_z(const float* __restrict__ xx2,
                                             const float* __restrict__ wenc,
                                             float* __restrict__ Z) {
    int b = blockIdx.x, tid = threadIdx.x;
    __shared__ float xsm[3136];
    __shared__ float wt[2048];   // [c][d]
    for (int f = tid; f < 3136; f += 256) xsm[f] = xx2[(size_t)b * 3136 + f];
    for (int f = tid; f < 2048; f += 256) { int d = f >> 6, c = f & 63; wt[c * 32 + d] = wenc[f]; }
    __syncthreads();
    for (int f = tid; f < 1568; f += 256) {
        int p = f >> 5, d = f & 31;
        float s = 0.f;
        #pragma unroll 8
        for (int c = 0; c < 64; ++c) s += wt[c * 32 + d] * xsm[c * 49 + p];
        Z[(size_t)b * 1568 + f] = s > 0.f ? s : 0.f;
    }
}

// ----------------------- dist (pre-softmax) --------------------------------
__global__ __launch_bounds__(256) void sac_dist(const float* __restrict__ Z,
                                                const float* __restrict__ cw,
                                                const float* __restrict__ scale,
                                                float* __restrict__ A) {
    __shared__ float cws[1536];
    __shared__ float c2s[48];
    __shared__ float scs[48];
    int tid = threadIdx.x;
    for (int f = tid; f < 1536; f += 256) cws[f] = cw[f];
    if (tid < 48) scs[tid] = scale[tid];
    __syncthreads();
    if (tid < 48) {
        float s = 0.f;
        for (int d = 0; d < 32; ++d) { float v = cws[tid * 32 + d]; s += v * v; }
        c2s[tid] = s;
    }
    __syncthreads();
    int idx = blockIdx.x * 256 + tid;      // (b,p) over 25088
    if (idx >= 25088) return;
    const float4* zp = (const float4*)(Z + (size_t)idx * 32);
    float zr[32];
    #pragma unroll
    for (int q = 0; q < 8; ++q) {
        float4 v = zp[q];
        zr[q * 4] = v.x; zr[q * 4 + 1] = v.y; zr[q * 4 + 2] = v.z; zr[q * 4 + 3] = v.w;
    }
    float z2 = 0.f;
    #pragma unroll
    for (int d = 0; d < 32; ++d) z2 += zr[d] * zr[d];
    float* ap = A + (size_t)idx * 48;
    for (int k = 0; k < 48; ++k) {
        float dot = 0.f;
        #pragma unroll
        for (int d = 0; d < 32; ++d) dot += zr[d] * cws[k * 32 + d];
        ap[k] = scs[k] * (z2 + c2s[k] - 2.f * dot);
    }
}

// ----------------------- softmax over k (48) -------------------------------
__global__ __launch_bounds__(256) void sac_asoft(float* __restrict__ A) {
    int idx = blockIdx.x * 256 + threadIdx.x;
    if (idx >= 25088) return;
    float* ap = A + (size_t)idx * 48;
    float v[48];
    float m = -1e30f;
    #pragma unroll
    for (int k = 0; k < 48; ++k) { v[k] = ap[k]; m = fmaxf(m, v[k]); }
    float s = 0.f;
    #pragma unroll
    for (int k = 0; k < 48; ++k) { v[k] = expf(v[k] - m); s += v[k]; }
    float inv = 1.f / s;
    #pragma unroll
    for (int k = 0; k < 48; ++k) ap[k] = v[k] * inv;
}

// ------------- E[b,k,d] = sum_p A*Z - (sum_p A) * C ------------------------
__global__ __launch_bounds__(256) void sac_e(const float* __restrict__ A,
                                             const float* __restrict__ Z,
                                             const float* __restrict__ cw,
                                             float* __restrict__ E) {
    int b = blockIdx.x, tid = threadIdx.x;
    __shared__ float As[2352];
    __shared__ float Zs[1568];
    __shared__ float asum[48];
    for (int f = tid; f < 2352; f += 256) As[f] = A[(size_t)b * 2352 + f];
    for (int f = tid; f < 1568; f += 256) Zs[f] = Z[(size_t)b * 1568 + f];
    __syncthreads();
    if (tid < 48) {
        float s = 0.f;
        for (int p = 0; p < 49; ++p) s += As[p * 48 + tid];
        asum[tid] = s;
    }
    __syncthreads();
    for (int f = tid; f < 1536; f += 256) {
        int k = f >> 5, d = f & 31;
        float s = 0.f;
        #pragma unroll 7
        for (int p = 0; p < 49; ++p) s += As[p * 48 + k] * Zs[p * 32 + d];
        E[(size_t)b * 1536 + f] = s - asum[k] * cw[f];
    }
}

// ------------------- BatchNorm stats per code k ----------------------------
__global__ __launch_bounds__(256) void sac_bnstat(const float* __restrict__ E,
                                                  float* __restrict__ bns) {
    int k = blockIdx.x, tid = threadIdx.x;
    __shared__ float sr[4];
    float s = 0.f;
    for (int i = tid; i < 16384; i += 256) {
        int b = i >> 5, d = i & 31;
        s += E[((size_t)b * 48 + k) * 32 + d];
    }
    #pragma unroll
    for (int off = 32; off > 0; off >>= 1) s += __shfl_xor(s, off, 64);
    int lane = tid & 63, wid = tid >> 6;
    if (lane == 0) sr[wid] = s;
    __syncthreads();
    float mu = (sr[0] + sr[1] + sr[2] + sr[3]) / 16384.f;
    float q = 0.f;
    for (int i = tid; i < 16384; i += 256) {
        int b = i >> 5, d = i & 31;
        float v = E[((size_t)b * 48 + k) * 32 + d] - mu;
        q += v * v;
    }
    #pragma unroll
    for (int off = 32; off > 0; off >>= 1) q += __shfl_xor(q, off, 64);
    __syncthreads();
    if (lane == 0) sr[wid] = q;
    __syncthreads();
    if (tid == 0) {
        float var = (sr[0] + sr[1] + sr[2] + sr[3]) / 16384.f;
        bns[k] = mu;
        bns[48 + k] = rsqrtf(var + 1e-5f);
    }
}

// ---------------- BN+relu -> E_sum -> gate -> xx3 --------------------------
__global__ __launch_bounds__(256) void sac_gate(const float* __restrict__ E,
                                                const float* __restrict__ bns,
                                                const float* __restrict__ bn_g,
                                                const float* __restrict__ bn_b,
                                                const float* __restrict__ w_att,
                                                const float* __restrict__ b_att,
                                                const float* __restrict__ xx2,
                                                float* __restrict__ xx3) {
    int b = blockIdx.x, tid = threadIdx.x;
    __shared__ float esd[32];
    __shared__ float gs[64];
    if (tid < 32) {
        int d = tid;
        float s = 0.f;
        for (int k = 0; k < 48; ++k) {
            float v = (E[((size_t)b * 48 + k) * 32 + d] - bns[k]) * bns[48 + k] * bn_g[k] + bn_b[k];
            s += v > 0.f ? v : 0.f;
        }
        esd[d] = s;
    }
    __syncthreads();
    if (tid < 64) {
        int c = tid;
        float a = b_att[c];
        #pragma unroll 8
        for (int d = 0; d < 32; ++d) a += esd[d] * w_att[c * 32 + d];
        gs[c] = 1.f / (1.f + expf(-a)) + 1.f;     // 1 + gate
    }
    __syncthreads();
    for (int f = tid; f < 3136; f += 256) {
        int c = f / 49;
        xx3[(size_t)b * 3136 + f] = xx2[(size_t)b * 3136 + f] * gs[c];
    }
}

// ---------------- d1 GEMM (split-K over 7 slab-aligned chunks) -------------
__global__ __launch_bounds__(256) void sac_d1gemm(const float* __restrict__ c1,
                                                  const float* __restrict__ c2,
                                                  const float* __restrict__ xx3,
                                                  const float* __restrict__ weff1,
                                                  const float* __restrict__ weff2,
                                                  const float* __restrict__ weff3,
                                                  float* __restrict__ h1p) {
    int blk = blockIdx.x;            // 7*32
    int s = blk >> 5;
    int r = blk & 31;
    int b0 = (r >> 2) * 64, o0 = (r & 3) * 64;
    const float* Ab; const float* Wb; int astr, klen;
    if (s < 4)      { Ab = c1 + s * 4624;       Wb = weff1 + s * 4624;       astr = 18496; klen = 4624; }
    else if (s < 6) { Ab = c2 + (s - 4) * 5408; Wb = weff2 + (s - 4) * 5408; astr = 10816; klen = 5408; }
    else            { Ab = xx3;                 Wb = weff3;                  astr = 3136;  klen = 3136; }
    __shared__ float As[16][68];
    __shared__ float Wsh[16][68];
    int tid = threadIdx.x;
    int tx = tid & 15, ty = tid >> 4;
    int bi = tid >> 2, kq = tid & 3;
    const float* aP = Ab + (size_t)(b0 + bi) * astr + kq * 4;
    const float* wP = Wb + (size_t)(o0 + bi) * astr + kq * 4;
    float acc[4][4];
    #pragma unroll
    for (int i = 0; i < 4; ++i)
        #pragma unroll
        for (int j = 0; j < 4; ++j) acc[i][j] = 0.f;
    for (int k0 = 0; k0 < klen; k0 += 16) {
        float4 av = *(const float4*)(aP + k0);
        float4 wv = *(const float4*)(wP + k0);
        __syncthreads();
        As[kq * 4 + 0][bi] = av.x; As[kq * 4 + 1][bi] = av.y;
        As[kq * 4 + 2][bi] = av.z; As[kq * 4 + 3][bi] = av.w;
        Wsh[kq * 4 + 0][bi] = wv.x; Wsh[kq * 4 + 1][bi] = wv.y;
        Wsh[kq * 4 + 2][bi] = wv.z; Wsh[kq * 4 + 3][bi] = wv.w;
        __syncthreads();
        #pragma unroll
        for (int kk = 0; kk < 16; ++kk) {
            float4 a4 = *(const float4*)&As[kk][ty * 4];
            float4 w4 = *(const float4*)&Wsh[kk][tx * 4];
            acc[0][0] += a4.x * w4.x; acc[0][1] += a4.x * w4.y; acc[0][2] += a4.x * w4.z; acc[0][3] += a4.x * w4.w;
            acc[1][0] += a4.y * w4.x; acc[1][1] += a4.y * w4.y; acc[1][2] += a4.y * w4.z; acc[1][3] += a4.y * w4.w;
            acc[2][0] += a4.z * w4.x; acc[2][1] += a4.z * w4.y; acc[2][2] += a4.z * w4.z; acc[2][3] += a4.z * w4.w;
            acc[3][0] += a4.w * w4.x; acc[3][1] += a4.w * w4.y; acc[3][2] += a4.w * w4.z; acc[3][3] += a4.w * w4.w;
        }
    }
    float* op = h1p + ((size_t)s * 512 + b0 + ty * 4) * 256 + o0 + tx * 4;
    #pragma unroll
    for (int i = 0; i < 4; ++i) {
        float4 v; v.x = acc[i][0]; v.y = acc[i][1]; v.z = acc[i][2]; v.w = acc[i][3];
        *(float4*)(op + i * 256) = v;
    }
}

// ---------------- h1 = relu(sum partials + bias) ---------------------------
__global__ __launch_bounds__(256) void sac_h1red(const float* __restrict__ h1p,
                                                 const float* __restrict__ b_d1,
                                                 float* __restrict__ h1) {
    int i = blockIdx.x * 256 + threadIdx.x;    // 131072
    int o = i & 255;
    float s = b_d1[o];
    #pragma unroll
    for (int t = 0; t < 7; ++t) s += h1p[(size_t)t * 131072 + i];
    h1[i] = s > 0.f ? s : 0.f;
}

// ---------------- h2 = relu(h1 @ w_d2.T + b_d2) ----------------------------
__global__ __launch_bounds__(256) void sac_h2(const float* __restrict__ h1,
                                              const float* __restrict__ w_d2,
                                              const float* __restrict__ b_d2,
                                              float* __restrict__ h2) {
    int idx = blockIdx.x * 256 + threadIdx.x;  // 65536
    int b = idx >> 7, o = idx & 127;
    const float* hp = h1 + b * 256;
    const float* wp = w_d2 + o * 256;
    float s = b_d2[o];
    #pragma unroll 4
    for (int k = 0; k < 256; ++k) s += hp[k] * wp[k];
    h2[idx] = s > 0.f ? s : 0.f;
}

// ---------------- out = h2 @ w_d3.T + b_d3 ---------------------------------
__global__ __launch_bounds__(256) void sac_out(const float* __restrict__ h2,
                                               const float* __restrict__ w_d3,
                                               const float* __restrict__ b_d3,
                                               float* __restrict__ out) {
    int idx = blockIdx.x * 256 + threadIdx.x;  // 8192
    int b = idx >> 4, j = idx & 15;
    const float* hp = h2 + b * 128;
    const float* wp = w_d3 + j * 128;
    float s = b_d3[j];
    #pragma unroll 4
    for (int k = 0; k < 128; ++k) s += hp[k] * wp[k];
    out[idx] = s;
}

// ---------------------------------------------------------------------------
extern "C" void kernel_launch(void* const* d_in, const int* in_sizes, int n_in,
                              void* d_out, int out_size, void* d_ws, size_t ws_size,
                              hipStream_t stream) {
    (void)in_sizes; (void)n_in; (void)out_size; (void)ws_size;
    const float* x     = (const float*)d_in[0];
    const float* w0    = (const float*)d_in[1];
    const float* b0    = (const float*)d_in[2];
    const float* w1    = (const float*)d_in[3];
    const float* b1    = (const float*)d_in[4];
    const float* w2    = (const float*)d_in[5];
    const float* b2    = (const float*)d_in[6];
    const float* wa    = (const float*)d_in[7];
    const float* wb    = (const float*)d_in[8];
    const float* wg    = (const float*)d_in[9];
    const float* wd    = (const float*)d_in[10];
    const float* wenc  = (const float*)d_in[11];
    const float* cw    = (const float*)d_in[12];
    const float* scale = (const float*)d_in[13];
    const float* w_att = (const float*)d_in[14];
    const float* b_att = (const float*)d_in[15];
    const float* bn_g  = (const float*)d_in[16];
    const float* bn_b  = (const float*)d_in[17];
    const float* w_d1  = (const float*)d_in[18];
    const float* b_d1  = (const float*)d_in[19];
    const float* w_d2  = (const float*)d_in[20];
    const float* b_d2  = (const float*)d_in[21];
    const float* w_d3  = (const float*)d_in[22];
    const float* b_d3  = (const float*)d_in[23];

    float* ws    = (float*)d_ws;
    float* WEFF1 = ws + OFF_WEFF1;
    float* WEFF2 = ws + OFF_WEFF2;
    float* WEFF3 = ws + OFF_WEFF3;
    float* TMP   = ws + OFF_C1;     // alias: weff build finishes before conv0 writes C1
    float* C1    = ws + OFF_C1;
    float* C2    = ws + OFF_C2;
    float* XX1   = ws + OFF_XX1;
    float* ALPHA = ws + OFF_ALPHA;
    float* BETA  = ws + OFF_BETA;
    float* GAM   = ws + OFF_GAM;
    float* CTX   = ws + OFF_CTX;
    float* H1P   = ws + OFF_CTX;    // alias: ctx dead after sac_ctx2
    float* CTX2  = ws + OFF_CTX2;
    float* XX2   = ws + OFF_XX2;
    float* Z     = ws + OFF_Z;
    float* A     = ws + OFF_A;
    float* E     = ws + OFF_E;
    float* BNS   = ws + OFF_BNS;
    float* XX3   = ws + OFF_XX3;
    float* H1    = ws + OFF_H1;
    float* H2    = ws + OFF_H2;
    unsigned short* WH  = (unsigned short*)(ws + OFF_WH);   // alias ALPHA (dead until sac_abg)
    unsigned short* WL  = (unsigned short*)(ws + OFF_WL);
    unsigned short* W1H = (unsigned short*)(ws + OFF_W1H);
    unsigned short* W1L = (unsigned short*)(ws + OFF_W1L);
    unsigned short* W2H = (unsigned short*)(ws + OFF_W2H);
    unsigned short* W2L = (unsigned short*)(ws + OFF_W2L);

    // weight prep (bf16 hi/lo splits)
    sac_wsplit<<<504, 256, 0, stream>>>(w0, WH, WL);
    sac_wsplit64<<<144, 256, 0, stream>>>(w1, W1H, W1L);
    sac_wsplit64<<<144, 256, 0, stream>>>(w2, W2H, W2L);

    // fold bilinear upsample into w_d1 (three parts: c1u, c2u, ctx3)
    sac_upA<<<20672, 256, 0, stream>>>(w_d1, TMP, 17, 0);
    sac_upB<<<18496, 256, 0, stream>>>(TMP, WEFF1, 17);
    sac_upA<<<15808, 256, 0, stream>>>(w_d1, TMP, 13, 64);
    sac_upB<<<10816, 256, 0, stream>>>(TMP, WEFF2, 13);
    sac_upA<<<8512, 256, 0, stream>>>(w_d1, TMP, 7, 128);
    sac_upB<<<3136, 256, 0, stream>>>(TMP, WEFF3, 7);

    // backbone: 3 dilated convs via split-bf16 MFMA, LDS-staged
    //            <IW, OW, DIL, TOTCH, WSTR, NMT, CPAD, NCHUNK, NIRMAX>
    sac_convmfma<19, 17, 1, 200, 224, 5, 96, 3, 7 ><<<2560, 256, 0, stream>>>(x,  WH,  WL,  b0, C1);
    sac_convmfma<17, 13, 2,  64,  64, 3, 64, 1, 10><<<1536, 256, 0, stream>>>(C1, W1H, W1L, b1, C2);
    sac_convmfma<13,  7, 3,  64,  64, 1, 64, 1, 13><<< 512, 256, 0, stream>>>(C2, W2H, W2L, b2, XX1);

    // non-local block
    sac_abg<<<512, 256, 0, stream>>>(XX1, wa, wb, wg, ALPHA, BETA, GAM);
    sac_ctx<<<512, 256, 0, stream>>>(ALPHA, BETA, CTX);
    sac_softmax0<<<2401, 256, 0, stream>>>(CTX);
    sac_ctx2<<<512, 256, 0, stream>>>(GAM, CTX, CTX2);
    sac_xx2<<<512, 256, 0, stream>>>(CTX2, wd, XX1, XX2);

    // soft VQ encoding + gate
    sac_z<<<512, 256, 0, stream>>>(XX2, wenc, Z);
    sac_dist<<<98, 256, 0, stream>>>(Z, cw, scale, A);
    sac_asoft<<<98, 256, 0, stream>>>(A);
    sac_e<<<512, 256, 0, stream>>>(A, Z, cw, E);
    sac_bnstat<<<48, 256, 0, stream>>>(E, BNS);
    sac_gate<<<512, 256, 0, stream>>>(E, BNS, bn_g, bn_b, w_att, b_att, XX2, XX3);

    // dense head (upsample folded into WEFF)
    sac_d1gemm<<<224, 256, 0, stream>>>(C1, C2, XX3, WEFF1, WEFF2, WEFF3, H1P);
    sac_h1red<<<512, 256, 0, stream>>>(H1P, b_d1, H1);
    sac_h2<<<256, 256, 0, stream>>>(H1, w_d2, b_d2, H2);
    sac_out<<<32, 256, 0, stream>>>(H2, w_d3, b_d3, (float*)d_out);
}

// Round 5
// 1069.500 us; speedup vs baseline: 4.0431x; 1.0203x over previous
//
#include <hip/hip_runtime.h>
#include <math.h>

// ---------------------------------------------------------------------------
// SACNet forward. conv0/1/2 + d1 GEMM = split-bf16 MFMA; rest fp32.
// B=512, IN=200, P=19, CF=64, TF=32, K=48, D=32, NC=16
// ---------------------------------------------------------------------------

typedef __attribute__((ext_vector_type(8))) short short8v;   // 8 bf16
typedef __attribute__((ext_vector_type(4))) float f32x4;

// workspace offsets (in floats)
// weff is now stored as bf16 hi/lo (same total footprint as fp32 weff):
#define OFF_WE1H  188928u      // 4734976 shorts = 2367488 floats
#define OFF_WE1L  2556416u
#define OFF_WE2H  4923904u     // 2768896 shorts = 1384448 floats
#define OFF_WE2L  6308352u
#define OFF_WE3H  7692800u     // 802816 shorts = 401408 floats
#define OFF_WE3L  8094208u     // ends 8495616 = OFF_C1
#define OFF_C1    8495616u     // 512*64*289 = 9469952 (TMP aliases this while building weff)
#define OFF_C2    17965568u    // 512*64*169 = 5537792
#define OFF_XX1   23503360u    // 512*64*49  = 1605632
#define OFF_ALPHA 25108992u    // 512*1568   (weight splits alias this region pre-abg)
#define OFF_BETA  25911808u
#define OFF_GAM   26714624u
#define OFF_CTX   27517440u    // 512*2401 (H1P aliases this at dense phase)
#define OFF_CTX2  28746752u
#define OFF_XX2   29549568u    // 512*3136
#define OFF_Z     31155200u    // 512*49*32
#define OFF_A     31958016u    // 512*49*48
#define OFF_E     33162240u    // 512*48*32
#define OFF_BNS   33948672u    // 96
#define OFF_XX3   33948768u    // 512*3136
#define OFF_H1    35554400u    // 512*256
#define OFF_H2    35685472u    // 512*128

// conv0 weights: 9*64*224 = 129024 shorts = 64512 floats each.
#define OFF_WH    OFF_ALPHA
#define OFF_WL    (OFF_ALPHA + 64512u)
// conv1/conv2 weights: 9*64*64 = 36864 shorts = 18432 floats each.
#define OFF_W1H   (OFF_ALPHA + 129024u)
#define OFF_W1L   (OFF_W1H + 18432u)
#define OFF_W2H   (OFF_W1L + 18432u)
#define OFF_W2L   (OFF_W2H + 18432u)
// ends 25311744 < OFF_BETA (25911808). All dead before sac_abg.

__device__ __forceinline__ unsigned bf16_rne_bits(float v) {
    unsigned u = __float_as_uint(v);
    return (u + 0x7FFFu + ((u >> 16) & 1u)) >> 16;
}

// -------------------- split w0 into bf16 hi/lo [s][c][224] -----------------
__global__ __launch_bounds__(256) void sac_wsplit(const float* __restrict__ w0,
                                                  unsigned short* __restrict__ WH,
                                                  unsigned short* __restrict__ WL) {
    int idx = blockIdx.x * 256 + threadIdx.x;   // 9*64*224 = 129024
    if (idx >= 129024) return;
    int ic = idx % 224;
    int c  = (idx / 224) % 64;
    int s  = idx / (224 * 64);
    int ky = s / 3, kx = s % 3;
    float v = 0.f;
    if (ic < 200) v = w0[((c * 200 + ic) * 3 + ky) * 3 + kx];
    unsigned hb = bf16_rne_bits(v);
    float hf = __uint_as_float(hb << 16);
    unsigned lb = bf16_rne_bits(v - hf);
    WH[idx] = (unsigned short)hb;
    WL[idx] = (unsigned short)lb;
}

// -------------------- split 64x64x3x3 weights into [s][c][64] --------------
__global__ __launch_bounds__(256) void sac_wsplit64(const float* __restrict__ wsrc,
                                                    unsigned short* __restrict__ WHo,
                                                    unsigned short* __restrict__ WLo) {
    int idx = blockIdx.x * 256 + threadIdx.x;   // 36864
    if (idx >= 36864) return;
    int ic = idx & 63;
    int c  = (idx >> 6) & 63;
    int s  = idx >> 12;
    int ky = s / 3, kx = s - ky * 3;
    float v = wsrc[((c * 64 + ic) * 3 + ky) * 3 + kx];
    unsigned hb = bf16_rne_bits(v);
    float hf = __uint_as_float(hb << 16);
    unsigned lb = bf16_rne_bits(v - hf);
    WHo[idx] = (unsigned short)hb;
    WLo[idx] = (unsigned short)lb;
}

// --------------------- fold bilinear upsample into w_d1 --------------------
__global__ __launch_bounds__(256) void sac_upA(const float* __restrict__ w_d1,
                                               float* __restrict__ tmp, int S, int co) {
    int idx = blockIdx.x * 256 + threadIdx.x;
    int total = 256 * 64 * 19 * S;
    if (idx >= total) return;
    int xp = idx % S;
    int j  = (idx / S) % 19;
    int c  = (idx / (S * 19)) % 64;
    int o  = idx / (S * 19 * 64);
    const float* wrow = w_d1 + (size_t)o * 69312 + (size_t)(co + c) * 361 + j * 19;
    float ratio = (float)(S - 1) / 18.0f;
    float s = 0.f;
    for (int i = 0; i < 19; ++i) {
        float xs = i * ratio;
        int x0 = (int)floorf(xs);
        float wx = xs - (float)x0;
        int x1 = x0 + 1; if (x1 > S - 1) x1 = S - 1;
        float cf = (xp == x0 ? 1.f - wx : 0.f) + (xp == x1 ? wx : 0.f);
        s += cf * wrow[i];
    }
    tmp[idx] = s;
}
// upB now emits bf16 hi/lo directly (consumed by the MFMA d1 GEMM)
__global__ __launch_bounds__(256) void sac_upB_bf16(const float* __restrict__ tmp,
                                                    unsigned short* __restrict__ WEH,
                                                    unsigned short* __restrict__ WEL, int S) {
    int idx = blockIdx.x * 256 + threadIdx.x;
    int total = 256 * 64 * S * S;
    if (idx >= total) return;
    int xp = idx % S;
    int yp = (idx / S) % S;
    int c  = (idx / (S * S)) % 64;
    int o  = idx / (S * S * 64);
    const float* tp = tmp + (((size_t)o * 64 + c) * 19) * S + xp;
    float ratio = (float)(S - 1) / 18.0f;
    float s = 0.f;
    for (int j = 0; j < 19; ++j) {
        float ys = j * ratio;
        int y0 = (int)floorf(ys);
        float wy = ys - (float)y0;
        int y1 = y0 + 1; if (y1 > S - 1) y1 = S - 1;
        float cf = (yp == y0 ? 1.f - wy : 0.f) + (yp == y1 ? wy : 0.f);
        s += cf * tp[j * S];
    }
    unsigned hb = bf16_rne_bits(s);
    float hf = __uint_as_float(hb << 16);
    unsigned lb = bf16_rne_bits(s - hf);
    WEH[idx] = (unsigned short)hb;
    WEL[idx] = (unsigned short)lb;
}

// ---------------- generic 3x3 dilated conv, split-bf16 MFMA ----------------
// One block = (batch, m-tile of 64 output pixels). 4 waves (2x2 of 32x32).
// K chunked in 32-channel slices (compile-time trip counts everywhere) so the
// compiler can unroll + software-pipeline. LDS ~17-22 KB -> 4 blocks/CU.
// LDS layout [rc][ch32], XOR-swizzled: frag reads conflict-free (2 lanes/bank
// group), staging writes 8-way (halved via b64-packed 4ch/iter).
template<int IW, int OW, int DIL, int TOTCH, int WSTR, int NMT, int NIRMAX>
__global__ __launch_bounds__(256, 4) void sac_convmfma(const float* __restrict__ x,
                                                       const unsigned short* __restrict__ WHp,
                                                       const unsigned short* __restrict__ WLp,
                                                       const float* __restrict__ bias,
                                                       float* __restrict__ out) {
    constexpr int OP = OW * OW;
    constexpr int ISZ = IW * IW;
    constexpr int NCHUNK = WSTR / 32;
    constexpr int NRC = NIRMAX * IW;
    __shared__ unsigned short XH[NRC * 32 + 64];
    __shared__ unsigned short XL[NRC * 32 + 64];
    int blk = blockIdx.x;
    int b = blk / NMT, mt = blk - b * NMT;
    int tid = threadIdx.x;
    int w = tid >> 6, l = tid & 63;
    int wm = w >> 1, wn = w & 1;
    int q = l >> 4, r = l & 15;
    int p_base = mt * 64 + wm * 32;
    int n_base = wn * 32;
    int pixA = p_base + r;      if (pixA > OP - 1) pixA = OP - 1;
    int pixB = p_base + 16 + r; if (pixB > OP - 1) pixB = OP - 1;
    int pyA = pixA / OW, pxa = pixA - pyA * OW;
    int pyB = pixB / OW, pxb = pixB - pyB * OW;
    int ir0 = (mt * 64) / OW;
    int rcA0 = (pyA - ir0) * IW + pxa;
    int rcB0 = (pyB - ir0) * IW + pxb;

    f32x4 acc[2][2];
    #pragma unroll
    for (int i = 0; i < 2; ++i)
        #pragma unroll
        for (int j = 0; j < 2; ++j) { acc[i][j].x = 0.f; acc[i][j].y = 0.f; acc[i][j].z = 0.f; acc[i][j].w = 0.f; }

    for (int cc = 0; cc < NCHUNK; ++cc) {
        int ch0 = cc * 32;
        __syncthreads();
        // ---- stage 32 channels x NRC rows: fp32 -> bf16 hi/lo, 4 ch/iter
        for (int f = tid; f < 8 * NRC; f += 256) {
            int chl4 = f / NRC, rc = f - chl4 * NRC;
            int ch = ch0 + chl4 * 4;
            int idx = ir0 * IW + rc; if (idx > ISZ - 1) idx = ISZ - 1;
            const float* gp = x + (size_t)b * (TOTCH * ISZ) + (size_t)ch * ISZ + idx;
            float v0 = (ch + 0 < TOTCH) ? gp[0] : 0.f;
            float v1 = (ch + 1 < TOTCH) ? gp[ISZ] : 0.f;
            float v2 = (ch + 2 < TOTCH) ? gp[2 * ISZ] : 0.f;
            float v3 = (ch + 3 < TOTCH) ? gp[3 * ISZ] : 0.f;
            unsigned h0 = bf16_rne_bits(v0); unsigned l0 = bf16_rne_bits(v0 - __uint_as_float(h0 << 16));
            unsigned h1 = bf16_rne_bits(v1); unsigned l1 = bf16_rne_bits(v1 - __uint_as_float(h1 << 16));
            unsigned h2 = bf16_rne_bits(v2); unsigned l2 = bf16_rne_bits(v2 - __uint_as_float(h2 << 16));
            unsigned h3 = bf16_rne_bits(v3); unsigned l3 = bf16_rne_bits(v3 - __uint_as_float(h3 << 16));
            unsigned bo = ((unsigned)(rc * 64 + chl4 * 8)) ^ (unsigned)((rc & 7) << 4);
            uint2 hv; hv.x = h0 | (h1 << 16); hv.y = h2 | (h3 << 16);
            uint2 lv; lv.x = l0 | (l1 << 16); lv.y = l2 | (l3 << 16);
            *(uint2*)((char*)XH + bo) = hv;
            *(uint2*)((char*)XL + bo) = lv;
        }
        __syncthreads();
        // ---- 9 taps, one K=32 step each (all trip counts compile-time)
        #pragma unroll 3
        for (int s9 = 0; s9 < 9; ++s9) {
            int ky = s9 / 3, kx = s9 - ky * 3;
            int rcA = rcA0 + DIL * (ky * IW + kx);
            int rcB = rcB0 + DIL * (ky * IW + kx);
            unsigned byA = ((unsigned)(rcA * 64 + q * 16)) ^ (unsigned)((rcA & 7) << 4);
            unsigned byB = ((unsigned)(rcB * 64 + q * 16)) ^ (unsigned)((rcB & 7) << 4);
            short8v ah0 = *(const short8v*)((const char*)XH + byA);
            short8v al0 = *(const short8v*)((const char*)XL + byA);
            short8v ah1 = *(const short8v*)((const char*)XH + byB);
            short8v al1 = *(const short8v*)((const char*)XL + byB);
            const unsigned short* pWH = WHp + (size_t)(s9 * 64 + n_base + r) * WSTR + ch0 + q * 8;
            const unsigned short* pWL = WLp + (size_t)(s9 * 64 + n_base + r) * WSTR + ch0 + q * 8;
            short8v bh0 = *(const short8v*)(pWH);
            short8v bh1 = *(const short8v*)(pWH + 16 * WSTR);
            short8v bl0 = *(const short8v*)(pWL);
            short8v bl1 = *(const short8v*)(pWL + 16 * WSTR);
            acc[0][0] = __builtin_amdgcn_mfma_f32_16x16x32_bf16(ah0, bh0, acc[0][0], 0, 0, 0);
            acc[0][1] = __builtin_amdgcn_mfma_f32_16x16x32_bf16(ah0, bh1, acc[0][1], 0, 0, 0);
            acc[1][0] = __builtin_amdgcn_mfma_f32_16x16x32_bf16(ah1, bh0, acc[1][0], 0, 0, 0);
            acc[1][1] = __builtin_amdgcn_mfma_f32_16x16x32_bf16(ah1, bh1, acc[1][1], 0, 0, 0);
            acc[0][0] = __builtin_amdgcn_mfma_f32_16x16x32_bf16(ah0, bl0, acc[0][0], 0, 0, 0);
            acc[0][1] = __builtin_amdgcn_mfma_f32_16x16x32_bf16(ah0, bl1, acc[0][1], 0, 0, 0);
            acc[1][0] = __builtin_amdgcn_mfma_f32_16x16x32_bf16(ah1, bl0, acc[1][0], 0, 0, 0);
            acc[1][1] = __builtin_amdgcn_mfma_f32_16x16x32_bf16(ah1, bl1, acc[1][1], 0, 0, 0);
            acc[0][0] = __builtin_amdgcn_mfma_f32_16x16x32_bf16(al0, bh0, acc[0][0], 0, 0, 0);
            acc[0][1] = __builtin_amdgcn_mfma_f32_16x16x32_bf16(al0, bh1, acc[0][1], 0, 0, 0);
            acc[1][0] = __builtin_amdgcn_mfma_f32_16x16x32_bf16(al1, bh0, acc[1][0], 0, 0, 0);
            acc[1][1] = __builtin_amdgcn_mfma_f32_16x16x32_bf16(al1, bh1, acc[1][1], 0, 0, 0);
        }
    }
    // epilogue: C row = pixel = (l>>4)*4+j, col = channel = l&15
    float bias0 = bias[n_base + r];
    float bias1 = bias[n_base + 16 + r];
    #pragma unroll
    for (int mf = 0; mf < 2; ++mf) {
        #pragma unroll
        for (int nf = 0; nf < 2; ++nf) {
            int ch = n_base + nf * 16 + r;
            float bs = nf ? bias1 : bias0;
            float* op = out + ((size_t)b * 64 + ch) * OP;
            #pragma unroll
            for (int j = 0; j < 4; ++j) {
                int pix = p_base + mf * 16 + q * 4 + j;
                if (pix < OP) {
                    float v = acc[mf][nf][j] + bs;
                    op[pix] = v > 0.f ? v : 0.f;
                }
            }
        }
    }
}

// ------------------- 1x1 convs a/b/g (relu only on g) ----------------------
__global__ __launch_bounds__(256) void sac_abg(const float* __restrict__ xx1,
                                               const float* __restrict__ wa,
                                               const float* __restrict__ wb,
                                               const float* __restrict__ wg,
                                               float* __restrict__ alpha,
                                               float* __restrict__ beta,
                                               float* __restrict__ gam) {
    int b = blockIdx.x, tid = threadIdx.x;
    __shared__ float xsm[3136];
    __shared__ float ws3[3 * 2048];
    for (int f = tid; f < 3136; f += 256) xsm[f] = xx1[(size_t)b * 3136 + f];
    for (int f = tid; f < 2048; f += 256) {
        ws3[f] = wa[f]; ws3[2048 + f] = wb[f]; ws3[4096 + f] = wg[f];
    }
    __syncthreads();
    for (int f = tid; f < 4704; f += 256) {
        int which = f / 1568, r = f - which * 1568;
        int t = r / 49, p = r - t * 49;
        const float* w = &ws3[which * 2048 + t * 64];
        float s = 0.f;
        #pragma unroll 8
        for (int c = 0; c < 64; ++c) s += w[c] * xsm[c * 49 + p];
        if (which == 2) s = s > 0.f ? s : 0.f;
        float* o = (which == 0) ? alpha : (which == 1) ? beta : gam;
        o[(size_t)b * 1568 + r] = s;
    }
}

// --------------------- ctx = alpha(raw reshape) @ beta ---------------------
__global__ __launch_bounds__(256) void sac_ctx(const float* __restrict__ alpha,
                                               const float* __restrict__ beta,
                                               float* __restrict__ ctx) {
    int b = blockIdx.x, tid = threadIdx.x;
    __shared__ float af[1568];
    __shared__ float bt[1568];
    for (int f = tid; f < 1568; f += 256) {
        af[f] = alpha[(size_t)b * 1568 + f];
        bt[f] = beta[(size_t)b * 1568 + f];
    }
    __syncthreads();
    for (int f = tid; f < 2401; f += 256) {
        int i = f / 49, l = f - i * 49;
        float s = 0.f;
        #pragma unroll 8
        for (int j = 0; j < 32; ++j) s += af[i * 32 + j] * bt[j * 49 + l];
        ctx[(size_t)b * 2401 + f] = s;
    }
}

// --------------------- softmax over BATCH axis (dim 0) ---------------------
__global__ __launch_bounds__(256) void sac_softmax0(float* __restrict__ ctx) {
    int pos = blockIdx.x;              // 0..2400
    int tid = threadIdx.x;
    float v0 = ctx[(size_t)tid * 2401 + pos];
    float v1 = ctx[(size_t)(tid + 256) * 2401 + pos];
    float m = fmaxf(v0, v1);
    #pragma unroll
    for (int off = 32; off > 0; off >>= 1) m = fmaxf(m, __shfl_xor(m, off, 64));
    __shared__ float sred[4];
    __shared__ float ssum[4];
    int lane = tid & 63, wid = tid >> 6;
    if (lane == 0) sred[wid] = m;
    __syncthreads();
    m = fmaxf(fmaxf(sred[0], sred[1]), fmaxf(sred[2], sred[3]));
    float e0 = expf(v0 - m), e1 = expf(v1 - m);
    float s = e0 + e1;
    #pragma unroll
    for (int off = 32; off > 0; off >>= 1) s += __shfl_xor(s, off, 64);
    if (lane == 0) ssum[wid] = s;
    __syncthreads();
    float inv = 1.f / (ssum[0] + ssum[1] + ssum[2] + ssum[3]);
    ctx[(size_t)tid * 2401 + pos] = e0 * inv;
    ctx[(size_t)(tid + 256) * 2401 + pos] = e1 * inv;
}

// --------------------------- ctx2 = gam @ ctx ------------------------------
__global__ __launch_bounds__(256) void sac_ctx2(const float* __restrict__ gam,
                                                const float* __restrict__ ctx,
                                                float* __restrict__ ctx2) {
    int b = blockIdx.x, tid = threadIdx.x;
    __shared__ float gs[1568];
    __shared__ float cs[2401];
    for (int f = tid; f < 1568; f += 256) gs[f] = gam[(size_t)b * 1568 + f];
    for (int f = tid; f < 2401; f += 256) cs[f] = ctx[(size_t)b * 2401 + f];
    __syncthreads();
    for (int f = tid; f < 1568; f += 256) {
        int t = f / 49, l = f - t * 49;
        float s = 0.f;
        #pragma unroll 7
        for (int i = 0; i < 49; ++i) s += gs[t * 49 + i] * cs[i * 49 + l];
        ctx2[(size_t)b * 1568 + f] = s;
    }
}

// ----------------- xx2 = relu(wd @ ctx2) + xx1 -----------------------------
__global__ __launch_bounds__(256) void sac_xx2(const float* __restrict__ ctx2,
                                               const float* __restrict__ wd,
                                               const float* __restrict__ xx1,
                                               float* __restrict__ xx2) {
    int b = blockIdx.x, tid = threadIdx.x;
    __shared__ float cs[1568];
    __shared__ float wds[2048];
    for (int f = tid; f < 1568; f += 256) cs[f] = ctx2[(size_t)b * 1568 + f];
    for (int f = tid; f < 2048; f += 256) wds[f] = wd[f];
    __syncthreads();
    for (int f = tid; f < 3136; f += 256) {
        int c = f / 49, p = f - c * 49;
        float s = 0.f;
        #pragma unroll 8
        for (int t = 0; t < 32; ++t) s += wds[c * 32 + t] * cs[t * 49 + p];
        s = s > 0.f ? s : 0.f;
        xx2[(size_t)b * 3136 + f] = s + xx1[(size_t)b * 3136 + f];
    }
}

// ------------------- Z = relu(wenc @ xx2), layout (b,p,d) ------------------
__global__ __launch_bounds__(256) void sac_z(const float* __restrict__ xx2,
                                             const float* __restrict__ wenc,
                                             float* __restrict__ Z) {
    int b = blockIdx.x, tid = threadIdx.x;
    __shared__ float xsm[3136];
    __shared__ float wt[2048];   // [c][d]
    for (int f = tid; f < 3136; f += 256) xsm[f] = xx2[(size_t)b * 3136 + f];
    for (int f = tid; f < 2048; f += 256) { int d = f >> 6, c = f & 63; wt[c * 32 + d] = wenc[f]; }
    __syncthreads();
    for (int f = tid; f < 1568; f += 256) {
        int p = f >> 5, d = f & 31;
        float s = 0.f;
        #pragma unroll 8
        for (int c = 0; c < 64; ++c) s += wt[c * 32 + d] * xsm[c * 49 + p];
        Z[(size_t)b * 1568 + f] = s > 0.f ? s : 0.f;
    }
}

// ----------------------- dist (pre-softmax) --------------------------------
__global__ __launch_bounds__(256) void sac_dist(const float* __restrict__ Z,
                                                const float* __restrict__ cw,
                                                const float* __restrict__ scale,
                                                float* __restrict__ A) {
    __shared__ float cws[1536];
    __shared__ float c2s[48];
    __shared__ float scs[48];
    int tid = threadIdx.x;
    for (int f = tid; f < 1536; f += 256) cws[f] = cw[f];
    if (tid < 48) scs[tid] = scale[tid];
    __syncthreads();
    if (tid < 48) {
        float s = 0.f;
        for (int d = 0; d < 32; ++d) { float v = cws[tid * 32 + d]; s += v * v; }
        c2s[tid] = s;
    }
    __syncthreads();
    int idx = blockIdx.x * 256 + tid;      // (b,p) over 25088
    if (idx >= 25088) return;
    const float4* zp = (const float4*)(Z + (size_t)idx * 32);
    float zr[32];
    #pragma unroll
    for (int q = 0; q < 8; ++q) {
        float4 v = zp[q];
        zr[q * 4] = v.x; zr[q * 4 + 1] = v.y; zr[q * 4 + 2] = v.z; zr[q * 4 + 3] = v.w;
    }
    float z2 = 0.f;
    #pragma unroll
    for (int d = 0; d < 32; ++d) z2 += zr[d] * zr[d];
    float* ap = A + (size_t)idx * 48;
    for (int k = 0; k < 48; ++k) {
        float dot = 0.f;
        #pragma unroll
        for (int d = 0; d < 32; ++d) dot += zr[d] * cws[k * 32 + d];
        ap[k] = scs[k] * (z2 + c2s[k] - 2.f * dot);
    }
}

// ----------------------- softmax over k (48) -------------------------------
__global__ __launch_bounds__(256) void sac_asoft(float* __restrict__ A) {
    int idx = blockIdx.x * 256 + threadIdx.x;
    if (idx >= 25088) return;
    float* ap = A + (size_t)idx * 48;
    float v[48];
    float m = -1e30f;
    #pragma unroll
    for (int k = 0; k < 48; ++k) { v[k] = ap[k]; m = fmaxf(m, v[k]); }
    float s = 0.f;
    #pragma unroll
    for (int k = 0; k < 48; ++k) { v[k] = expf(v[k] - m); s += v[k]; }
    float inv = 1.f / s;
    #pragma unroll
    for (int k = 0; k < 48; ++k) ap[k] = v[k] * inv;
}

// ------------- E[b,k,d] = sum_p A*Z - (sum_p A) * C ------------------------
__global__ __launch_bounds__(256) void sac_e(const float* __restrict__ A,
                                             const float* __restrict__ Z,
                                             const float* __restrict__ cw,
                                             float* __restrict__ E) {
    int b = blockIdx.x, tid = threadIdx.x;
    __shared__ float As[2352];
    __shared__ float Zs[1568];
    __shared__ float asum[48];
    for (int f = tid; f < 2352; f += 256) As[f] = A[(size_t)b * 2352 + f];
    for (int f = tid; f < 1568; f += 256) Zs[f] = Z[(size_t)b * 1568 + f];
    __syncthreads();
    if (tid < 48) {
        float s = 0.f;
        for (int p = 0; p < 49; ++p) s += As[p * 48 + tid];
        asum[tid] = s;
    }
    __syncthreads();
    for (int f = tid; f < 1536; f += 256) {
        int k = f >> 5, d = f & 31;
        float s = 0.f;
        #pragma unroll 7
        for (int p = 0; p < 49; ++p) s += As[p * 48 + k] * Zs[p * 32 + d];
        E[(size_t)b * 1536 + f] = s - asum[k] * cw[f];
    }
}

// ------------------- BatchNorm stats per code k ----------------------------
__global__ __launch_bounds__(256) void sac_bnstat(const float* __restrict__ E,
                                                  float* __restrict__ bns) {
    int k = blockIdx.x, tid = threadIdx.x;
    __shared__ float sr[4];
    float s = 0.f;
    for (int i = tid; i < 16384; i += 256) {
        int b = i >> 5, d = i & 31;
        s += E[((size_t)b * 48 + k) * 32 + d];
    }
    #pragma unroll
    for (int off = 32; off > 0; off >>= 1) s += __shfl_xor(s, off, 64);
    int lane = tid & 63, wid = tid >> 6;
    if (lane == 0) sr[wid] = s;
    __syncthreads();
    float mu = (sr[0] + sr[1] + sr[2] + sr[3]) / 16384.f;
    float q = 0.f;
    for (int i = tid; i < 16384; i += 256) {
        int b = i >> 5, d = i & 31;
        float v = E[((size_t)b * 48 + k) * 32 + d] - mu;
        q += v * v;
    }
    #pragma unroll
    for (int off = 32; off > 0; off >>= 1) q += __shfl_xor(q, off, 64);
    __syncthreads();
    if (lane == 0) sr[wid] = q;
    __syncthreads();
    if (tid == 0) {
        float var = (sr[0] + sr[1] + sr[2] + sr[3]) / 16384.f;
        bns[k] = mu;
        bns[48 + k] = rsqrtf(var + 1e-5f);
    }
}

// ---------------- BN+relu -> E_sum -> gate -> xx3 --------------------------
__global__ __launch_bounds__(256) void sac_gate(const float* __restrict__ E,
                                                const float* __restrict__ bns,
                                                const float* __restrict__ bn_g,
                                                const float* __restrict__ bn_b,
                                                const float* __restrict__ w_att,
                                                const float* __restrict__ b_att,
                                                const float* __restrict__ xx2,
                                                float* __restrict__ xx3) {
    int b = blockIdx.x, tid = threadIdx.x;
    __shared__ float esd[32];
    __shared__ float gs[64];
    if (tid < 32) {
        int d = tid;
        float s = 0.f;
        for (int k = 0; k < 48; ++k) {
            float v = (E[((size_t)b * 48 + k) * 32 + d] - bns[k]) * bns[48 + k] * bn_g[k] + bn_b[k];
            s += v > 0.f ? v : 0.f;
        }
        esd[d] = s;
    }
    __syncthreads();
    if (tid < 64) {
        int c = tid;
        float a = b_att[c];
        #pragma unroll 8
        for (int d = 0; d < 32; ++d) a += esd[d] * w_att[c * 32 + d];
        gs[c] = 1.f / (1.f + expf(-a)) + 1.f;     // 1 + gate
    }
    __syncthreads();
    for (int f = tid; f < 3136; f += 256) {
        int c = f / 49;
        xx3[(size_t)b * 3136 + f] = xx2[(size_t)b * 3136 + f] * gs[c];
    }
}

// ---------------- d1 GEMM via split-bf16 MFMA ------------------------------
// 224 blocks: 7 slabs x (8 m-tiles of 64 batches x 4 n-tiles of 64 outs).
// A (fp32 activations) staged in LDS with inline hi/lo split; B read direct
// from pre-split bf16 weff. Partials to h1p[s][b][o].
__global__ __launch_bounds__(256) void sac_d1gemm_mfma(const float* __restrict__ c1,
                                                       const float* __restrict__ c2,
                                                       const float* __restrict__ xx3,
                                                       const unsigned short* __restrict__ we1h,
                                                       const unsigned short* __restrict__ we1l,
                                                       const unsigned short* __restrict__ we2h,
                                                       const unsigned short* __restrict__ we2l,
                                                       const unsigned short* __restrict__ we3h,
                                                       const unsigned short* __restrict__ we3l,
                                                       float* __restrict__ h1p) {
    constexpr int KCH = 256;
    __shared__ unsigned short AH[64 * KCH + 64];
    __shared__ unsigned short AL[64 * KCH + 64];
    int blk = blockIdx.x;
    int s = blk >> 5, r5 = blk & 31;
    int b0 = (r5 >> 2) * 64, o0 = (r5 & 3) * 64;
    const float* Ab; const unsigned short *WHb, *WLb; int astr, klen, kbase;
    if (s < 4)      { Ab = c1;  WHb = we1h; WLb = we1l; astr = 18496; klen = 4624; kbase = s * 4624; }
    else if (s < 6) { Ab = c2;  WHb = we2h; WLb = we2l; astr = 10816; klen = 5408; kbase = (s - 4) * 5408; }
    else            { Ab = xx3; WHb = we3h; WLb = we3l; astr = 3136;  klen = 3136; kbase = 0; }
    int tid = threadIdx.x;
    int w = tid >> 6, l = tid & 63;
    int wm = w >> 1, wn = w & 1;
    int q = l >> 4, r = l & 15;

    f32x4 acc[2][2];
    #pragma unroll
    for (int i = 0; i < 2; ++i)
        #pragma unroll
        for (int j = 0; j < 2; ++j) { acc[i][j].x = 0.f; acc[i][j].y = 0.f; acc[i][j].z = 0.f; acc[i][j].w = 0.f; }

    int nkch = (klen + KCH - 1) / KCH;
    for (int kc = 0; kc < nkch; ++kc) {
        int k0 = kc * KCH;
        __syncthreads();
        // stage A-tile 64 rows x 256 K (2 elems/iter, coalesced float2)
        for (int f = tid; f < 64 * (KCH / 2); f += 256) {
            int row = f >> 7, col2 = (f & 127) << 1;
            int kk = k0 + col2;
            float va = 0.f, vb = 0.f;
            if (kk < klen) {
                float2 v = *(const float2*)(Ab + (size_t)(b0 + row) * astr + kbase + kk);
                va = v.x; vb = v.y;
            }
            unsigned h0 = bf16_rne_bits(va); unsigned l0 = bf16_rne_bits(va - __uint_as_float(h0 << 16));
            unsigned h1 = bf16_rne_bits(vb); unsigned l1 = bf16_rne_bits(vb - __uint_as_float(h1 << 16));
            unsigned bo = ((unsigned)(row * 512 + col2 * 2)) ^ (unsigned)((row & 7) << 4);
            *(unsigned*)((char*)AH + bo) = h0 | (h1 << 16);
            *(unsigned*)((char*)AL + bo) = l0 | (l1 << 16);
        }
        __syncthreads();
        #pragma unroll 2
        for (int ks = 0; ks < KCH / 32; ++ks) {
            int k = ks * 32 + q * 8;
            int rowA0 = wm * 32 + r, rowA1 = wm * 32 + 16 + r;
            unsigned byA0 = ((unsigned)(rowA0 * 512 + k * 2)) ^ (unsigned)((rowA0 & 7) << 4);
            unsigned byA1 = ((unsigned)(rowA1 * 512 + k * 2)) ^ (unsigned)((rowA1 & 7) << 4);
            short8v ah0 = *(const short8v*)((const char*)AH + byA0);
            short8v al0 = *(const short8v*)((const char*)AL + byA0);
            short8v ah1 = *(const short8v*)((const char*)AH + byA1);
            short8v al1 = *(const short8v*)((const char*)AL + byA1);
            size_t wofs = (size_t)(o0 + wn * 32 + r) * astr + kbase + k0 + k;
            short8v bh0 = *(const short8v*)(WHb + wofs);
            short8v bh1 = *(const short8v*)(WHb + wofs + (size_t)16 * astr);
            short8v bl0 = *(const short8v*)(WLb + wofs);
            short8v bl1 = *(const short8v*)(WLb + wofs + (size_t)16 * astr);
            acc[0][0] = __builtin_amdgcn_mfma_f32_16x16x32_bf16(ah0, bh0, acc[0][0], 0, 0, 0);
            acc[0][1] = __builtin_amdgcn_mfma_f32_16x16x32_bf16(ah0, bh1, acc[0][1], 0, 0, 0);
            acc[1][0] = __builtin_amdgcn_mfma_f32_16x16x32_bf16(ah1, bh0, acc[1][0], 0, 0, 0);
            acc[1][1] = __builtin_amdgcn_mfma_f32_16x16x32_bf16(ah1, bh1, acc[1][1], 0, 0, 0);
            acc[0][0] = __builtin_amdgcn_mfma_f32_16x16x32_bf16(ah0, bl0, acc[0][0], 0, 0, 0);
            acc[0][1] = __builtin_amdgcn_mfma_f32_16x16x32_bf16(ah0, bl1, acc[0][1], 0, 0, 0);
            acc[1][0] = __builtin_amdgcn_mfma_f32_16x16x32_bf16(ah1, bl0, acc[1][0], 0, 0, 0);
            acc[1][1] = __builtin_amdgcn_mfma_f32_16x16x32_bf16(ah1, bl1, acc[1][1], 0, 0, 0);
            acc[0][0] = __builtin_amdgcn_mfma_f32_16x16x32_bf16(al0, bh0, acc[0][0], 0, 0, 0);
            acc[0][1] = __builtin_amdgcn_mfma_f32_16x16x32_bf16(al0, bh1, acc[0][1], 0, 0, 0);
            acc[1][0] = __builtin_amdgcn_mfma_f32_16x16x32_bf16(al1, bh0, acc[1][0], 0, 0, 0);
            acc[1][1] = __builtin_amdgcn_mfma_f32_16x16x32_bf16(al1, bh1, acc[1][1], 0, 0, 0);
        }
    }
    // epilogue: row = batch = (l>>4)*4+j, col = out = l&15
    #pragma unroll
    for (int mf = 0; mf < 2; ++mf) {
        #pragma unroll
        for (int nf = 0; nf < 2; ++nf) {
            int o = o0 + wn * 32 + nf * 16 + r;
            #pragma unroll
            for (int j = 0; j < 4; ++j) {
                int batch = b0 + wm * 32 + mf * 16 + q * 4 + j;
                h1p[((size_t)s * 512 + batch) * 256 + o] = acc[mf][nf][j];
            }
        }
    }
}

// ---------------- h1 = relu(sum partials + bias) ---------------------------
__global__ __launch_bounds__(256) void sac_h1red(const float* __restrict__ h1p,
                                                 const float* __restrict__ b_d1,
                                                 float* __restrict__ h1) {
    int i = blockIdx.x * 256 + threadIdx.x;    // 131072
    int o = i & 255;
    float s = b_d1[o];
    #pragma unroll
    for (int t = 0; t < 7; ++t) s += h1p[(size_t)t * 131072 + i];
    h1[i] = s > 0.f ? s : 0.f;
}

// ---------------- h2 = relu(h1 @ w_d2.T + b_d2) ----------------------------
__global__ __launch_bounds__(256) void sac_h2(const float* __restrict__ h1,
                                              const float* __restrict__ w_d2,
                                              const float* __restrict__ b_d2,
                                              float* __restrict__ h2) {
    int idx = blockIdx.x * 256 + threadIdx.x;  // 65536
    int b = idx >> 7, o = idx & 127;
    const float* hp = h1 + b * 256;
    const float* wp = w_d2 + o * 256;
    float s = b_d2[o];
    #pragma unroll 4
    for (int k = 0; k < 256; ++k) s += hp[k] * wp[k];
    h2[idx] = s > 0.f ? s : 0.f;
}

// ---------------- out = h2 @ w_d3.T + b_d3 ---------------------------------
__global__ __launch_bounds__(256) void sac_out(const float* __restrict__ h2,
                                               const float* __restrict__ w_d3,
                                               const float* __restrict__ b_d3,
                                               float* __restrict__ out) {
    int idx = blockIdx.x * 256 + threadIdx.x;  // 8192
    int b = idx >> 4, j = idx & 15;
    const float* hp = h2 + b * 128;
    const float* wp = w_d3 + j * 128;
    float s = b_d3[j];
    #pragma unroll 4
    for (int k = 0; k < 128; ++k) s += hp[k] * wp[k];
    out[idx] = s;
}

// ---------------------------------------------------------------------------
extern "C" void kernel_launch(void* const* d_in, const int* in_sizes, int n_in,
                              void* d_out, int out_size, void* d_ws, size_t ws_size,
                              hipStream_t stream) {
    (void)in_sizes; (void)n_in; (void)out_size; (void)ws_size;
    const float* x     = (const float*)d_in[0];
    const float* w0    = (const float*)d_in[1];
    const float* b0    = (const float*)d_in[2];
    const float* w1    = (const float*)d_in[3];
    const float* b1    = (const float*)d_in[4];
    const float* w2    = (const float*)d_in[5];
    const float* b2    = (const float*)d_in[6];
    const float* wa    = (const float*)d_in[7];
    const float* wb    = (const float*)d_in[8];
    const float* wg    = (const float*)d_in[9];
    const float* wd    = (const float*)d_in[10];
    const float* wenc  = (const float*)d_in[11];
    const float* cw    = (const float*)d_in[12];
    const float* scale = (const float*)d_in[13];
    const float* w_att = (const float*)d_in[14];
    const float* b_att = (const float*)d_in[15];
    const float* bn_g  = (const float*)d_in[16];
    const float* bn_b  = (const float*)d_in[17];
    const float* w_d1  = (const float*)d_in[18];
    const float* b_d1  = (const float*)d_in[19];
    const float* w_d2  = (const float*)d_in[20];
    const float* b_d2  = (const float*)d_in[21];
    const float* w_d3  = (const float*)d_in[22];
    const float* b_d3  = (const float*)d_in[23];

    float* ws    = (float*)d_ws;
    unsigned short* WE1H = (unsigned short*)(ws + OFF_WE1H);
    unsigned short* WE1L = (unsigned short*)(ws + OFF_WE1L);
    unsigned short* WE2H = (unsigned short*)(ws + OFF_WE2H);
    unsigned short* WE2L = (unsigned short*)(ws + OFF_WE2L);
    unsigned short* WE3H = (unsigned short*)(ws + OFF_WE3H);
    unsigned short* WE3L = (unsigned short*)(ws + OFF_WE3L);
    float* TMP   = ws + OFF_C1;     // alias: weff build finishes before conv0 writes C1
    float* C1    = ws + OFF_C1;
    float* C2    = ws + OFF_C2;
    float* XX1   = ws + OFF_XX1;
    float* ALPHA = ws + OFF_ALPHA;
    float* BETA  = ws + OFF_BETA;
    float* GAM   = ws + OFF_GAM;
    float* CTX   = ws + OFF_CTX;
    float* H1P   = ws + OFF_CTX;    // alias: ctx dead after sac_ctx2
    float* CTX2  = ws + OFF_CTX2;
    float* XX2   = ws + OFF_XX2;
    float* Z     = ws + OFF_Z;
    float* A     = ws + OFF_A;
    float* E     = ws + OFF_E;
    float* BNS   = ws + OFF_BNS;
    float* XX3   = ws + OFF_XX3;
    float* H1    = ws + OFF_H1;
    float* H2    = ws + OFF_H2;
    unsigned short* WH  = (unsigned short*)(ws + OFF_WH);   // alias ALPHA (dead until sac_abg)
    unsigned short* WL  = (unsigned short*)(ws + OFF_WL);
    unsigned short* W1H = (unsigned short*)(ws + OFF_W1H);
    unsigned short* W1L = (unsigned short*)(ws + OFF_W1L);
    unsigned short* W2H = (unsigned short*)(ws + OFF_W2H);
    unsigned short* W2L = (unsigned short*)(ws + OFF_W2L);

    // weight prep (bf16 hi/lo splits)
    sac_wsplit<<<504, 256, 0, stream>>>(w0, WH, WL);
    sac_wsplit64<<<144, 256, 0, stream>>>(w1, W1H, W1L);
    sac_wsplit64<<<144, 256, 0, stream>>>(w2, W2H, W2L);

    // fold bilinear upsample into w_d1, emit bf16 hi/lo weff
    sac_upA<<<20672, 256, 0, stream>>>(w_d1, TMP, 17, 0);
    sac_upB_bf16<<<18496, 256, 0, stream>>>(TMP, WE1H, WE1L, 17);
    sac_upA<<<15808, 256, 0, stream>>>(w_d1, TMP, 13, 64);
    sac_upB_bf16<<<10816, 256, 0, stream>>>(TMP, WE2H, WE2L, 13);
    sac_upA<<<8512, 256, 0, stream>>>(w_d1, TMP, 7, 128);
    sac_upB_bf16<<<3136, 256, 0, stream>>>(TMP, WE3H, WE3L, 7);

    // backbone: 3 dilated convs via split-bf16 MFMA
    //            <IW, OW, DIL, TOTCH, WSTR, NMT, NIRMAX>
    sac_convmfma<19, 17, 1, 200, 224, 5, 7 ><<<2560, 256, 0, stream>>>(x,  WH,  WL,  b0, C1);
    sac_convmfma<17, 13, 2,  64,  64, 3, 10><<<1536, 256, 0, stream>>>(C1, W1H, W1L, b1, C2);
    sac_convmfma<13,  7, 3,  64,  64, 1, 13><<< 512, 256, 0, stream>>>(C2, W2H, W2L, b2, XX1);

    // non-local block
    sac_abg<<<512, 256, 0, stream>>>(XX1, wa, wb, wg, ALPHA, BETA, GAM);
    sac_ctx<<<512, 256, 0, stream>>>(ALPHA, BETA, CTX);
    sac_softmax0<<<2401, 256, 0, stream>>>(CTX);
    sac_ctx2<<<512, 256, 0, stream>>>(GAM, CTX, CTX2);
    sac_xx2<<<512, 256, 0, stream>>>(CTX2, wd, XX1, XX2);

    // soft VQ encoding + gate
    sac_z<<<512, 256, 0, stream>>>(XX2, wenc, Z);
    sac_dist<<<98, 256, 0, stream>>>(Z, cw, scale, A);
    sac_asoft<<<98, 256, 0, stream>>>(A);
    sac_e<<<512, 256, 0, stream>>>(A, Z, cw, E);
    sac_bnstat<<<48, 256, 0, stream>>>(E, BNS);
    sac_gate<<<512, 256, 0, stream>>>(E, BNS, bn_g, bn_b, w_att, b_att, XX2, XX3);

    // dense head (upsample folded into bf16 weff)
    sac_d1gemm_mfma<<<224, 256, 0, stream>>>(C1, C2, XX3, WE1H, WE1L, WE2H, WE2L, WE3H, WE3L, H1P);
    sac_h1red<<<512, 256, 0, stream>>>(H1P, b_d1, H1);
    sac_h2<<<256, 256, 0, stream>>>(H1, w_d2, b_d2, H2);
    sac_out<<<32, 256, 0, stream>>>(H2, w_d3, b_d3, (float*)d_out);
}

// Round 6
// 864.648 us; speedup vs baseline: 5.0010x; 1.2369x over previous
//
#include <hip/hip_runtime.h>
#include <math.h>

// ---------------------------------------------------------------------------
// SACNet forward. conv0/1/2 + d1 GEMM = split-bf16 MFMA; rest fp32.
// B=512, IN=200, P=19, CF=64, TF=32, K=48, D=32, NC=16
// ---------------------------------------------------------------------------

typedef __attribute__((ext_vector_type(8))) short short8v;   // 8 bf16
typedef __attribute__((ext_vector_type(4))) float f32x4;

// workspace offsets (in floats)
// weff stored as bf16 hi/lo (same total footprint as fp32 weff):
#define OFF_WE1H  188928u      // 4734976 shorts = 2367488 floats
#define OFF_WE1L  2556416u
#define OFF_WE2H  4923904u     // 2768896 shorts = 1384448 floats
#define OFF_WE2L  6308352u
#define OFF_WE3H  7692800u     // 802816 shorts = 401408 floats
#define OFF_WE3L  8094208u     // ends 8495616 = OFF_C1
#define OFF_C1    8495616u     // 512*64*289 = 9469952 (TMP aliases this while building weff)
#define OFF_C2    17965568u    // 512*64*169 = 5537792
#define OFF_XX1   23503360u    // 512*64*49  = 1605632
#define OFF_ALPHA 25108992u    // 512*1568   (weight splits alias pre-abg; H1P aliases at dense phase)
#define OFF_BETA  25911808u
#define OFF_GAM   26714624u
#define OFF_CTX   27517440u    // 512*2401
#define OFF_CTX2  28746752u
#define OFF_XX2   29549568u    // 512*3136
#define OFF_Z     31155200u    // 512*49*32
#define OFF_A     31958016u    // 512*49*48
#define OFF_E     33162240u    // 512*48*32
#define OFF_BNS   33948672u    // 96
#define OFF_XX3   33948768u    // 512*3136
#define OFF_H1    35554400u    // 512*256
#define OFF_H2    35685472u    // 512*128

// H1P: 28 x 512 x 256 = 3670016 floats at OFF_ALPHA (ALPHA..CTX2 all dead at
// dense-head time; ends 28779008 < OFF_XX2 29549568; XX2 also dead by then).
#define OFF_H1P   OFF_ALPHA

// conv0 weights: 9*64*224 = 129024 shorts = 64512 floats each.
#define OFF_WH    OFF_ALPHA
#define OFF_WL    (OFF_ALPHA + 64512u)
// conv1/conv2 weights: 9*64*64 = 36864 shorts = 18432 floats each.
#define OFF_W1H   (OFF_ALPHA + 129024u)
#define OFF_W1L   (OFF_W1H + 18432u)
#define OFF_W2H   (OFF_W1L + 18432u)
#define OFF_W2L   (OFF_W2H + 18432u)
// ends 25311744 < OFF_BETA. All dead before sac_abg.

__device__ __forceinline__ unsigned bf16_rne_bits(float v) {
    unsigned u = __float_as_uint(v);
    return (u + 0x7FFFu + ((u >> 16) & 1u)) >> 16;
}

// -------------------- split w0 into bf16 hi/lo [s][c][224] -----------------
__global__ __launch_bounds__(256) void sac_wsplit(const float* __restrict__ w0,
                                                  unsigned short* __restrict__ WH,
                                                  unsigned short* __restrict__ WL) {
    int idx = blockIdx.x * 256 + threadIdx.x;   // 9*64*224 = 129024
    if (idx >= 129024) return;
    int ic = idx % 224;
    int c  = (idx / 224) % 64;
    int s  = idx / (224 * 64);
    int ky = s / 3, kx = s % 3;
    float v = 0.f;
    if (ic < 200) v = w0[((c * 200 + ic) * 3 + ky) * 3 + kx];
    unsigned hb = bf16_rne_bits(v);
    float hf = __uint_as_float(hb << 16);
    unsigned lb = bf16_rne_bits(v - hf);
    WH[idx] = (unsigned short)hb;
    WL[idx] = (unsigned short)lb;
}

// -------------------- split 64x64x3x3 weights into [s][c][64] --------------
__global__ __launch_bounds__(256) void sac_wsplit64(const float* __restrict__ wsrc,
                                                    unsigned short* __restrict__ WHo,
                                                    unsigned short* __restrict__ WLo) {
    int idx = blockIdx.x * 256 + threadIdx.x;   // 36864
    if (idx >= 36864) return;
    int ic = idx & 63;
    int c  = (idx >> 6) & 63;
    int s  = idx >> 12;
    int ky = s / 3, kx = s - ky * 3;
    float v = wsrc[((c * 64 + ic) * 3 + ky) * 3 + kx];
    unsigned hb = bf16_rne_bits(v);
    float hf = __uint_as_float(hb << 16);
    unsigned lb = bf16_rne_bits(v - hf);
    WHo[idx] = (unsigned short)hb;
    WLo[idx] = (unsigned short)lb;
}

// --------------------- fold bilinear upsample into w_d1 --------------------
__global__ __launch_bounds__(256) void sac_upA(const float* __restrict__ w_d1,
                                               float* __restrict__ tmp, int S, int co) {
    int idx = blockIdx.x * 256 + threadIdx.x;
    int total = 256 * 64 * 19 * S;
    if (idx >= total) return;
    int xp = idx % S;
    int j  = (idx / S) % 19;
    int c  = (idx / (S * 19)) % 64;
    int o  = idx / (S * 19 * 64);
    const float* wrow = w_d1 + (size_t)o * 69312 + (size_t)(co + c) * 361 + j * 19;
    float ratio = (float)(S - 1) / 18.0f;
    float s = 0.f;
    for (int i = 0; i < 19; ++i) {
        float xs = i * ratio;
        int x0 = (int)floorf(xs);
        float wx = xs - (float)x0;
        int x1 = x0 + 1; if (x1 > S - 1) x1 = S - 1;
        float cf = (xp == x0 ? 1.f - wx : 0.f) + (xp == x1 ? wx : 0.f);
        s += cf * wrow[i];
    }
    tmp[idx] = s;
}
// upB emits bf16 hi/lo directly (consumed by the MFMA d1 GEMM)
__global__ __launch_bounds__(256) void sac_upB_bf16(const float* __restrict__ tmp,
                                                    unsigned short* __restrict__ WEH,
                                                    unsigned short* __restrict__ WEL, int S) {
    int idx = blockIdx.x * 256 + threadIdx.x;
    int total = 256 * 64 * S * S;
    if (idx >= total) return;
    int xp = idx % S;
    int yp = (idx / S) % S;
    int c  = (idx / (S * S)) % 64;
    int o  = idx / (S * S * 64);
    const float* tp = tmp + (((size_t)o * 64 + c) * 19) * S + xp;
    float ratio = (float)(S - 1) / 18.0f;
    float s = 0.f;
    for (int j = 0; j < 19; ++j) {
        float ys = j * ratio;
        int y0 = (int)floorf(ys);
        float wy = ys - (float)y0;
        int y1 = y0 + 1; if (y1 > S - 1) y1 = S - 1;
        float cf = (yp == y0 ? 1.f - wy : 0.f) + (yp == y1 ? wy : 0.f);
        s += cf * tp[j * S];
    }
    unsigned hb = bf16_rne_bits(s);
    float hf = __uint_as_float(hb << 16);
    unsigned lb = bf16_rne_bits(s - hf);
    WEH[idx] = (unsigned short)hb;
    WEL[idx] = (unsigned short)lb;
}

// ---------------- generic 3x3 dilated conv, split-bf16 MFMA ----------------
template<int IW, int OW, int DIL, int TOTCH, int WSTR, int NMT, int NIRMAX>
__global__ __launch_bounds__(256, 4) void sac_convmfma(const float* __restrict__ x,
                                                       const unsigned short* __restrict__ WHp,
                                                       const unsigned short* __restrict__ WLp,
                                                       const float* __restrict__ bias,
                                                       float* __restrict__ out) {
    constexpr int OP = OW * OW;
    constexpr int ISZ = IW * IW;
    constexpr int NCHUNK = WSTR / 32;
    constexpr int NRC = NIRMAX * IW;
    __shared__ unsigned short XH[NRC * 32 + 64];
    __shared__ unsigned short XL[NRC * 32 + 64];
    int blk = blockIdx.x;
    int b = blk / NMT, mt = blk - b * NMT;
    int tid = threadIdx.x;
    int w = tid >> 6, l = tid & 63;
    int wm = w >> 1, wn = w & 1;
    int q = l >> 4, r = l & 15;
    int p_base = mt * 64 + wm * 32;
    int n_base = wn * 32;
    int pixA = p_base + r;      if (pixA > OP - 1) pixA = OP - 1;
    int pixB = p_base + 16 + r; if (pixB > OP - 1) pixB = OP - 1;
    int pyA = pixA / OW, pxa = pixA - pyA * OW;
    int pyB = pixB / OW, pxb = pixB - pyB * OW;
    int ir0 = (mt * 64) / OW;
    int rcA0 = (pyA - ir0) * IW + pxa;
    int rcB0 = (pyB - ir0) * IW + pxb;

    f32x4 acc[2][2];
    #pragma unroll
    for (int i = 0; i < 2; ++i)
        #pragma unroll
        for (int j = 0; j < 2; ++j) { acc[i][j].x = 0.f; acc[i][j].y = 0.f; acc[i][j].z = 0.f; acc[i][j].w = 0.f; }

    for (int cc = 0; cc < NCHUNK; ++cc) {
        int ch0 = cc * 32;
        __syncthreads();
        // ---- stage 32 channels x NRC rows: fp32 -> bf16 hi/lo, 4 ch/iter
        for (int f = tid; f < 8 * NRC; f += 256) {
            int chl4 = f / NRC, rc = f - chl4 * NRC;
            int ch = ch0 + chl4 * 4;
            int idx = ir0 * IW + rc; if (idx > ISZ - 1) idx = ISZ - 1;
            const float* gp = x + (size_t)b * (TOTCH * ISZ) + (size_t)ch * ISZ + idx;
            float v0 = (ch + 0 < TOTCH) ? gp[0] : 0.f;
            float v1 = (ch + 1 < TOTCH) ? gp[ISZ] : 0.f;
            float v2 = (ch + 2 < TOTCH) ? gp[2 * ISZ] : 0.f;
            float v3 = (ch + 3 < TOTCH) ? gp[3 * ISZ] : 0.f;
            unsigned h0 = bf16_rne_bits(v0); unsigned l0 = bf16_rne_bits(v0 - __uint_as_float(h0 << 16));
            unsigned h1 = bf16_rne_bits(v1); unsigned l1 = bf16_rne_bits(v1 - __uint_as_float(h1 << 16));
            unsigned h2 = bf16_rne_bits(v2); unsigned l2 = bf16_rne_bits(v2 - __uint_as_float(h2 << 16));
            unsigned h3 = bf16_rne_bits(v3); unsigned l3 = bf16_rne_bits(v3 - __uint_as_float(h3 << 16));
            unsigned bo = ((unsigned)(rc * 64 + chl4 * 8)) ^ (unsigned)((rc & 7) << 4);
            uint2 hv; hv.x = h0 | (h1 << 16); hv.y = h2 | (h3 << 16);
            uint2 lv; lv.x = l0 | (l1 << 16); lv.y = l2 | (l3 << 16);
            *(uint2*)((char*)XH + bo) = hv;
            *(uint2*)((char*)XL + bo) = lv;
        }
        __syncthreads();
        // ---- 9 taps, one K=32 step each
        #pragma unroll 3
        for (int s9 = 0; s9 < 9; ++s9) {
            int ky = s9 / 3, kx = s9 - ky * 3;
            int rcA = rcA0 + DIL * (ky * IW + kx);
            int rcB = rcB0 + DIL * (ky * IW + kx);
            unsigned byA = ((unsigned)(rcA * 64 + q * 16)) ^ (unsigned)((rcA & 7) << 4);
            unsigned byB = ((unsigned)(rcB * 64 + q * 16)) ^ (unsigned)((rcB & 7) << 4);
            short8v ah0 = *(const short8v*)((const char*)XH + byA);
            short8v al0 = *(const short8v*)((const char*)XL + byA);
            short8v ah1 = *(const short8v*)((const char*)XH + byB);
            short8v al1 = *(const short8v*)((const char*)XL + byB);
            const unsigned short* pWH = WHp + (size_t)(s9 * 64 + n_base + r) * WSTR + ch0 + q * 8;
            const unsigned short* pWL = WLp + (size_t)(s9 * 64 + n_base + r) * WSTR + ch0 + q * 8;
            short8v bh0 = *(const short8v*)(pWH);
            short8v bh1 = *(const short8v*)(pWH + 16 * WSTR);
            short8v bl0 = *(const short8v*)(pWL);
            short8v bl1 = *(const short8v*)(pWL + 16 * WSTR);
            acc[0][0] = __builtin_amdgcn_mfma_f32_16x16x32_bf16(ah0, bh0, acc[0][0], 0, 0, 0);
            acc[0][1] = __builtin_amdgcn_mfma_f32_16x16x32_bf16(ah0, bh1, acc[0][1], 0, 0, 0);
            acc[1][0] = __builtin_amdgcn_mfma_f32_16x16x32_bf16(ah1, bh0, acc[1][0], 0, 0, 0);
            acc[1][1] = __builtin_amdgcn_mfma_f32_16x16x32_bf16(ah1, bh1, acc[1][1], 0, 0, 0);
            acc[0][0] = __builtin_amdgcn_mfma_f32_16x16x32_bf16(ah0, bl0, acc[0][0], 0, 0, 0);
            acc[0][1] = __builtin_amdgcn_mfma_f32_16x16x32_bf16(ah0, bl1, acc[0][1], 0, 0, 0);
            acc[1][0] = __builtin_amdgcn_mfma_f32_16x16x32_bf16(ah1, bl0, acc[1][0], 0, 0, 0);
            acc[1][1] = __builtin_amdgcn_mfma_f32_16x16x32_bf16(ah1, bl1, acc[1][1], 0, 0, 0);
            acc[0][0] = __builtin_amdgcn_mfma_f32_16x16x32_bf16(al0, bh0, acc[0][0], 0, 0, 0);
            acc[0][1] = __builtin_amdgcn_mfma_f32_16x16x32_bf16(al0, bh1, acc[0][1], 0, 0, 0);
            acc[1][0] = __builtin_amdgcn_mfma_f32_16x16x32_bf16(al1, bh0, acc[1][0], 0, 0, 0);
            acc[1][1] = __builtin_amdgcn_mfma_f32_16x16x32_bf16(al1, bh1, acc[1][1], 0, 0, 0);
        }
    }
    float bias0 = bias[n_base + r];
    float bias1 = bias[n_base + 16 + r];
    #pragma unroll
    for (int mf = 0; mf < 2; ++mf) {
        #pragma unroll
        for (int nf = 0; nf < 2; ++nf) {
            int ch = n_base + nf * 16 + r;
            float bs = nf ? bias1 : bias0;
            float* op = out + ((size_t)b * 64 + ch) * OP;
            #pragma unroll
            for (int j = 0; j < 4; ++j) {
                int pix = p_base + mf * 16 + q * 4 + j;
                if (pix < OP) {
                    float v = acc[mf][nf][j] + bs;
                    op[pix] = v > 0.f ? v : 0.f;
                }
            }
        }
    }
}

// ------------------- 1x1 convs a/b/g (relu only on g) ----------------------
__global__ __launch_bounds__(256) void sac_abg(const float* __restrict__ xx1,
                                               const float* __restrict__ wa,
                                               const float* __restrict__ wb,
                                               const float* __restrict__ wg,
                                               float* __restrict__ alpha,
                                               float* __restrict__ beta,
                                               float* __restrict__ gam) {
    int b = blockIdx.x, tid = threadIdx.x;
    __shared__ float xsm[3136];
    __shared__ float ws3[3 * 2048];
    for (int f = tid; f < 3136; f += 256) xsm[f] = xx1[(size_t)b * 3136 + f];
    for (int f = tid; f < 2048; f += 256) {
        ws3[f] = wa[f]; ws3[2048 + f] = wb[f]; ws3[4096 + f] = wg[f];
    }
    __syncthreads();
    for (int f = tid; f < 4704; f += 256) {
        int which = f / 1568, r = f - which * 1568;
        int t = r / 49, p = r - t * 49;
        const float* w = &ws3[which * 2048 + t * 64];
        float s = 0.f;
        #pragma unroll 8
        for (int c = 0; c < 64; ++c) s += w[c] * xsm[c * 49 + p];
        if (which == 2) s = s > 0.f ? s : 0.f;
        float* o = (which == 0) ? alpha : (which == 1) ? beta : gam;
        o[(size_t)b * 1568 + r] = s;
    }
}

// --------------------- ctx = alpha(raw reshape) @ beta ---------------------
__global__ __launch_bounds__(256) void sac_ctx(const float* __restrict__ alpha,
                                               const float* __restrict__ beta,
                                               float* __restrict__ ctx) {
    int b = blockIdx.x, tid = threadIdx.x;
    __shared__ float af[1568];
    __shared__ float bt[1568];
    for (int f = tid; f < 1568; f += 256) {
        af[f] = alpha[(size_t)b * 1568 + f];
        bt[f] = beta[(size_t)b * 1568 + f];
    }
    __syncthreads();
    for (int f = tid; f < 2401; f += 256) {
        int i = f / 49, l = f - i * 49;
        float s = 0.f;
        #pragma unroll 8
        for (int j = 0; j < 32; ++j) s += af[i * 32 + j] * bt[j * 49 + l];
        ctx[(size_t)b * 2401 + f] = s;
    }
}

// --------------------- softmax over BATCH axis (dim 0) ---------------------
__global__ __launch_bounds__(256) void sac_softmax0(float* __restrict__ ctx) {
    int pos = blockIdx.x;              // 0..2400
    int tid = threadIdx.x;
    float v0 = ctx[(size_t)tid * 2401 + pos];
    float v1 = ctx[(size_t)(tid + 256) * 2401 + pos];
    float m = fmaxf(v0, v1);
    #pragma unroll
    for (int off = 32; off > 0; off >>= 1) m = fmaxf(m, __shfl_xor(m, off, 64));
    __shared__ float sred[4];
    __shared__ float ssum[4];
    int lane = tid & 63, wid = tid >> 6;
    if (lane == 0) sred[wid] = m;
    __syncthreads();
    m = fmaxf(fmaxf(sred[0], sred[1]), fmaxf(sred[2], sred[3]));
    float e0 = expf(v0 - m), e1 = expf(v1 - m);
    float s = e0 + e1;
    #pragma unroll
    for (int off = 32; off > 0; off >>= 1) s += __shfl_xor(s, off, 64);
    if (lane == 0) ssum[wid] = s;
    __syncthreads();
    float inv = 1.f / (ssum[0] + ssum[1] + ssum[2] + ssum[3]);
    ctx[(size_t)tid * 2401 + pos] = e0 * inv;
    ctx[(size_t)(tid + 256) * 2401 + pos] = e1 * inv;
}

// --------------------------- ctx2 = gam @ ctx ------------------------------
__global__ __launch_bounds__(256) void sac_ctx2(const float* __restrict__ gam,
                                                const float* __restrict__ ctx,
                                                float* __restrict__ ctx2) {
    int b = blockIdx.x, tid = threadIdx.x;
    __shared__ float gs[1568];
    __shared__ float cs[2401];
    for (int f = tid; f < 1568; f += 256) gs[f] = gam[(size_t)b * 1568 + f];
    for (int f = tid; f < 2401; f += 256) cs[f] = ctx[(size_t)b * 2401 + f];
    __syncthreads();
    for (int f = tid; f < 1568; f += 256) {
        int t = f / 49, l = f - t * 49;
        float s = 0.f;
        #pragma unroll 7
        for (int i = 0; i < 49; ++i) s += gs[t * 49 + i] * cs[i * 49 + l];
        ctx2[(size_t)b * 1568 + f] = s;
    }
}

// ----------------- xx2 = relu(wd @ ctx2) + xx1 -----------------------------
__global__ __launch_bounds__(256) void sac_xx2(const float* __restrict__ ctx2,
                                               const float* __restrict__ wd,
                                               const float* __restrict__ xx1,
                                               float* __restrict__ xx2) {
    int b = blockIdx.x, tid = threadIdx.x;
    __shared__ float cs[1568];
    __shared__ float wds[2048];
    for (int f = tid; f < 1568; f += 256) cs[f] = ctx2[(size_t)b * 1568 + f];
    for (int f = tid; f < 2048; f += 256) wds[f] = wd[f];
    __syncthreads();
    for (int f = tid; f < 3136; f += 256) {
        int c = f / 49, p = f - c * 49;
        float s = 0.f;
        #pragma unroll 8
        for (int t = 0; t < 32; ++t) s += wds[c * 32 + t] * cs[t * 49 + p];
        s = s > 0.f ? s : 0.f;
        xx2[(size_t)b * 3136 + f] = s + xx1[(size_t)b * 3136 + f];
    }
}

// ------------------- Z = relu(wenc @ xx2), layout (b,p,d) ------------------
__global__ __launch_bounds__(256) void sac_z(const float* __restrict__ xx2,
                                             const float* __restrict__ wenc,
                                             float* __restrict__ Z) {
    int b = blockIdx.x, tid = threadIdx.x;
    __shared__ float xsm[3136];
    __shared__ float wt[2048];   // [c][d]
    for (int f = tid; f < 3136; f += 256) xsm[f] = xx2[(size_t)b * 3136 + f];
    for (int f = tid; f < 2048; f += 256) { int d = f >> 6, c = f & 63; wt[c * 32 + d] = wenc[f]; }
    __syncthreads();
    for (int f = tid; f < 1568; f += 256) {
        int p = f >> 5, d = f & 31;
        float s = 0.f;
        #pragma unroll 8
        for (int c = 0; c < 64; ++c) s += wt[c * 32 + d] * xsm[c * 49 + p];
        Z[(size_t)b * 1568 + f] = s > 0.f ? s : 0.f;
    }
}

// ----------------------- dist (pre-softmax) --------------------------------
__global__ __launch_bounds__(256) void sac_dist(const float* __restrict__ Z,
                                                const float* __restrict__ cw,
                                                const float* __restrict__ scale,
                                                float* __restrict__ A) {
    __shared__ float cws[1536];
    __shared__ float c2s[48];
    __shared__ float scs[48];
    int tid = threadIdx.x;
    for (int f = tid; f < 1536; f += 256) cws[f] = cw[f];
    if (tid < 48) scs[tid] = scale[tid];
    __syncthreads();
    if (tid < 48) {
        float s = 0.f;
        for (int d = 0; d < 32; ++d) { float v = cws[tid * 32 + d]; s += v * v; }
        c2s[tid] = s;
    }
    __syncthreads();
    int idx = blockIdx.x * 256 + tid;      // (b,p) over 25088
    if (idx >= 25088) return;
    const float4* zp = (const float4*)(Z + (size_t)idx * 32);
    float zr[32];
    #pragma unroll
    for (int q = 0; q < 8; ++q) {
        float4 v = zp[q];
        zr[q * 4] = v.x; zr[q * 4 + 1] = v.y; zr[q * 4 + 2] = v.z; zr[q * 4 + 3] = v.w;
    }
    float z2 = 0.f;
    #pragma unroll
    for (int d = 0; d < 32; ++d) z2 += zr[d] * zr[d];
    float* ap = A + (size_t)idx * 48;
    for (int k = 0; k < 48; ++k) {
        float dot = 0.f;
        #pragma unroll
        for (int d = 0; d < 32; ++d) dot += zr[d] * cws[k * 32 + d];
        ap[k] = scs[k] * (z2 + c2s[k] - 2.f * dot);
    }
}

// ----------------------- softmax over k (48) -------------------------------
__global__ __launch_bounds__(256) void sac_asoft(float* __restrict__ A) {
    int idx = blockIdx.x * 256 + threadIdx.x;
    if (idx >= 25088) return;
    float* ap = A + (size_t)idx * 48;
    float v[48];
    float m = -1e30f;
    #pragma unroll
    for (int k = 0; k < 48; ++k) { v[k] = ap[k]; m = fmaxf(m, v[k]); }
    float s = 0.f;
    #pragma unroll
    for (int k = 0; k < 48; ++k) { v[k] = expf(v[k] - m); s += v[k]; }
    float inv = 1.f / s;
    #pragma unroll
    for (int k = 0; k < 48; ++k) ap[k] = v[k] * inv;
}

// ------------- E[b,k,d] = sum_p A*Z - (sum_p A) * C ------------------------
__global__ __launch_bounds__(256) void sac_e(const float* __restrict__ A,
                                             const float* __restrict__ Z,
                                             const float* __restrict__ cw,
                                             float* __restrict__ E) {
    int b = blockIdx.x, tid = threadIdx.x;
    __shared__ float As[2352];
    __shared__ float Zs[1568];
    __shared__ float asum[48];
    for (int f = tid; f < 2352; f += 256) As[f] = A[(size_t)b * 2352 + f];
    for (int f = tid; f < 1568; f += 256) Zs[f] = Z[(size_t)b * 1568 + f];
    __syncthreads();
    if (tid < 48) {
        float s = 0.f;
        for (int p = 0; p < 49; ++p) s += As[p * 48 + tid];
        asum[tid] = s;
    }
    __syncthreads();
    for (int f = tid; f < 1536; f += 256) {
        int k = f >> 5, d = f & 31;
        float s = 0.f;
        #pragma unroll 7
        for (int p = 0; p < 49; ++p) s += As[p * 48 + k] * Zs[p * 32 + d];
        E[(size_t)b * 1536 + f] = s - asum[k] * cw[f];
    }
}

// ------------------- BatchNorm stats per code k ----------------------------
__global__ __launch_bounds__(256) void sac_bnstat(const float* __restrict__ E,
                                                  float* __restrict__ bns) {
    int k = blockIdx.x, tid = threadIdx.x;
    __shared__ float sr[4];
    float s = 0.f;
    for (int i = tid; i < 16384; i += 256) {
        int b = i >> 5, d = i & 31;
        s += E[((size_t)b * 48 + k) * 32 + d];
    }
    #pragma unroll
    for (int off = 32; off > 0; off >>= 1) s += __shfl_xor(s, off, 64);
    int lane = tid & 63, wid = tid >> 6;
    if (lane == 0) sr[wid] = s;
    __syncthreads();
    float mu = (sr[0] + sr[1] + sr[2] + sr[3]) / 16384.f;
    float q = 0.f;
    for (int i = tid; i < 16384; i += 256) {
        int b = i >> 5, d = i & 31;
        float v = E[((size_t)b * 48 + k) * 32 + d] - mu;
        q += v * v;
    }
    #pragma unroll
    for (int off = 32; off > 0; off >>= 1) q += __shfl_xor(q, off, 64);
    __syncthreads();
    if (lane == 0) sr[wid] = q;
    __syncthreads();
    if (tid == 0) {
        float var = (sr[0] + sr[1] + sr[2] + sr[3]) / 16384.f;
        bns[k] = mu;
        bns[48 + k] = rsqrtf(var + 1e-5f);
    }
}

// ---------------- BN+relu -> E_sum -> gate -> xx3 --------------------------
__global__ __launch_bounds__(256) void sac_gate(const float* __restrict__ E,
                                                const float* __restrict__ bns,
                                                const float* __restrict__ bn_g,
                                                const float* __restrict__ bn_b,
                                                const float* __restrict__ w_att,
                                                const float* __restrict__ b_att,
                                                const float* __restrict__ xx2,
                                                float* __restrict__ xx3) {
    int b = blockIdx.x, tid = threadIdx.x;
    __shared__ float esd[32];
    __shared__ float gs[64];
    if (tid < 32) {
        int d = tid;
        float s = 0.f;
        for (int k = 0; k < 48; ++k) {
            float v = (E[((size_t)b * 48 + k) * 32 + d] - bns[k]) * bns[48 + k] * bn_g[k] + bn_b[k];
            s += v > 0.f ? v : 0.f;
        }
        esd[d] = s;
    }
    __syncthreads();
    if (tid < 64) {
        int c = tid;
        float a = b_att[c];
        #pragma unroll 8
        for (int d = 0; d < 32; ++d) a += esd[d] * w_att[c * 32 + d];
        gs[c] = 1.f / (1.f + expf(-a)) + 1.f;     // 1 + gate
    }
    __syncthreads();
    for (int f = tid; f < 3136; f += 256) {
        int c = f / 49;
        xx3[(size_t)b * 3136 + f] = xx2[(size_t)b * 3136 + f] * gs[c];
    }
}

// ---------------- d1 GEMM via split-bf16 MFMA, fine split-K ----------------
// 28 K-groups (c1: 16 x K=1156, c2: 8 x K=1352, xx3: 4 x K=784) x 32 (m,n)
// tiles = 896 blocks (~3.5/CU; 33 KB LDS -> 4 resident). Partials h1p[g][b][o].
__global__ __launch_bounds__(256, 4) void sac_d1gemm_mfma(const float* __restrict__ c1,
                                                          const float* __restrict__ c2,
                                                          const float* __restrict__ xx3,
                                                          const unsigned short* __restrict__ we1h,
                                                          const unsigned short* __restrict__ we1l,
                                                          const unsigned short* __restrict__ we2h,
                                                          const unsigned short* __restrict__ we2l,
                                                          const unsigned short* __restrict__ we3h,
                                                          const unsigned short* __restrict__ we3l,
                                                          float* __restrict__ h1p) {
    constexpr int KCH = 128;
    __shared__ unsigned short AH[64 * KCH + 64];
    __shared__ unsigned short AL[64 * KCH + 64];
    int blk = blockIdx.x;
    int g = blk >> 5, r5 = blk & 31;
    int b0 = (r5 >> 2) * 64, o0 = (r5 & 3) * 64;
    const float* Ab; const unsigned short *WHb, *WLb; int astr, klen, kbase;
    if (g < 16)      { int slab = g >> 2, kq4 = g & 3;
                       Ab = c1;  WHb = we1h; WLb = we1l; astr = 18496; klen = 1156; kbase = slab * 4624 + kq4 * 1156; }
    else if (g < 24) { int gg = g - 16; int slab = gg >> 2, kq4 = gg & 3;
                       Ab = c2;  WHb = we2h; WLb = we2l; astr = 10816; klen = 1352; kbase = slab * 5408 + kq4 * 1352; }
    else             { int kq4 = g - 24;
                       Ab = xx3; WHb = we3h; WLb = we3l; astr = 3136;  klen = 784;  kbase = kq4 * 784; }
    int tid = threadIdx.x;
    int w = tid >> 6, l = tid & 63;
    int wm = w >> 1, wn = w & 1;
    int q = l >> 4, r = l & 15;

    f32x4 acc[2][2];
    #pragma unroll
    for (int i = 0; i < 2; ++i)
        #pragma unroll
        for (int j = 0; j < 2; ++j) { acc[i][j].x = 0.f; acc[i][j].y = 0.f; acc[i][j].z = 0.f; acc[i][j].w = 0.f; }

    int nkch = (klen + KCH - 1) / KCH;
    for (int kc = 0; kc < nkch; ++kc) {
        int k0 = kc * KCH;
        __syncthreads();
        // stage A-tile 64 rows x 128 K (float2/iter, coalesced; zero-pad tail)
        for (int f = tid; f < 64 * (KCH / 2); f += 256) {
            int row = f >> 6, col2 = (f & 63) << 1;
            int kk = k0 + col2;
            float va = 0.f, vb = 0.f;
            if (kk < klen) {
                float2 v = *(const float2*)(Ab + (size_t)(b0 + row) * astr + kbase + kk);
                va = v.x; vb = v.y;
            }
            unsigned h0 = bf16_rne_bits(va); unsigned l0 = bf16_rne_bits(va - __uint_as_float(h0 << 16));
            unsigned h1 = bf16_rne_bits(vb); unsigned l1 = bf16_rne_bits(vb - __uint_as_float(h1 << 16));
            unsigned bo = ((unsigned)(row * 256 + col2 * 2)) ^ (unsigned)((row & 7) << 4);
            *(unsigned*)((char*)AH + bo) = h0 | (h1 << 16);
            *(unsigned*)((char*)AL + bo) = l0 | (l1 << 16);
        }
        __syncthreads();
        #pragma unroll
        for (int ks = 0; ks < KCH / 32; ++ks) {    // 4
            int k = ks * 32 + q * 8;
            int rowA0 = wm * 32 + r, rowA1 = wm * 32 + 16 + r;
            unsigned byA0 = ((unsigned)(rowA0 * 256 + k * 2)) ^ (unsigned)((rowA0 & 7) << 4);
            unsigned byA1 = ((unsigned)(rowA1 * 256 + k * 2)) ^ (unsigned)((rowA1 & 7) << 4);
            short8v ah0 = *(const short8v*)((const char*)AH + byA0);
            short8v al0 = *(const short8v*)((const char*)AL + byA0);
            short8v ah1 = *(const short8v*)((const char*)AH + byA1);
            short8v al1 = *(const short8v*)((const char*)AL + byA1);
            // tail reads may run past klen into adjacent ws data; A is
            // zero-staged there so products vanish (all values finite).
            size_t wofs = (size_t)(o0 + wn * 32 + r) * astr + kbase + k0 + k;
            short8v bh0 = *(const short8v*)(WHb + wofs);
            short8v bh1 = *(const short8v*)(WHb + wofs + (size_t)16 * astr);
            short8v bl0 = *(const short8v*)(WLb + wofs);
            short8v bl1 = *(const short8v*)(WLb + wofs + (size_t)16 * astr);
            acc[0][0] = __builtin_amdgcn_mfma_f32_16x16x32_bf16(ah0, bh0, acc[0][0], 0, 0, 0);
            acc[0][1] = __builtin_amdgcn_mfma_f32_16x16x32_bf16(ah0, bh1, acc[0][1], 0, 0, 0);
            acc[1][0] = __builtin_amdgcn_mfma_f32_16x16x32_bf16(ah1, bh0, acc[1][0], 0, 0, 0);
            acc[1][1] = __builtin_amdgcn_mfma_f32_16x16x32_bf16(ah1, bh1, acc[1][1], 0, 0, 0);
            acc[0][0] = __builtin_amdgcn_mfma_f32_16x16x32_bf16(ah0, bl0, acc[0][0], 0, 0, 0);
            acc[0][1] = __builtin_amdgcn_mfma_f32_16x16x32_bf16(ah0, bl1, acc[0][1], 0, 0, 0);
            acc[1][0] = __builtin_amdgcn_mfma_f32_16x16x32_bf16(ah1, bl0, acc[1][0], 0, 0, 0);
            acc[1][1] = __builtin_amdgcn_mfma_f32_16x16x32_bf16(ah1, bl1, acc[1][1], 0, 0, 0);
            acc[0][0] = __builtin_amdgcn_mfma_f32_16x16x32_bf16(al0, bh0, acc[0][0], 0, 0, 0);
            acc[0][1] = __builtin_amdgcn_mfma_f32_16x16x32_bf16(al0, bh1, acc[0][1], 0, 0, 0);
            acc[1][0] = __builtin_amdgcn_mfma_f32_16x16x32_bf16(al1, bh0, acc[1][0], 0, 0, 0);
            acc[1][1] = __builtin_amdgcn_mfma_f32_16x16x32_bf16(al1, bh1, acc[1][1], 0, 0, 0);
        }
    }
    // epilogue: row = batch = (l>>4)*4+j, col = out = l&15
    #pragma unroll
    for (int mf = 0; mf < 2; ++mf) {
        #pragma unroll
        for (int nf = 0; nf < 2; ++nf) {
            int o = o0 + wn * 32 + nf * 16 + r;
            #pragma unroll
            for (int j = 0; j < 4; ++j) {
                int batch = b0 + wm * 32 + mf * 16 + q * 4 + j;
                h1p[((size_t)g * 512 + batch) * 256 + o] = acc[mf][nf][j];
            }
        }
    }
}

// ---------------- h1 = relu(sum 28 partials + bias) ------------------------
__global__ __launch_bounds__(256) void sac_h1red(const float* __restrict__ h1p,
                                                 const float* __restrict__ b_d1,
                                                 float* __restrict__ h1) {
    int i = blockIdx.x * 256 + threadIdx.x;    // 131072
    int o = i & 255;
    float s = b_d1[o];
    #pragma unroll
    for (int t = 0; t < 28; ++t) s += h1p[(size_t)t * 131072 + i];
    h1[i] = s > 0.f ? s : 0.f;
}

// ---------------- h2 = relu(h1 @ w_d2.T + b_d2) ----------------------------
__global__ __launch_bounds__(256) void sac_h2(const float* __restrict__ h1,
                                              const float* __restrict__ w_d2,
                                              const float* __restrict__ b_d2,
                                              float* __restrict__ h2) {
    int idx = blockIdx.x * 256 + threadIdx.x;  // 65536
    int b = idx >> 7, o = idx & 127;
    const float* hp = h1 + b * 256;
    const float* wp = w_d2 + o * 256;
    float s = b_d2[o];
    #pragma unroll 4
    for (int k = 0; k < 256; ++k) s += hp[k] * wp[k];
    h2[idx] = s > 0.f ? s : 0.f;
}

// ---------------- out = h2 @ w_d3.T + b_d3 ---------------------------------
__global__ __launch_bounds__(256) void sac_out(const float* __restrict__ h2,
                                               const float* __restrict__ w_d3,
                                               const float* __restrict__ b_d3,
                                               float* __restrict__ out) {
    int idx = blockIdx.x * 256 + threadIdx.x;  // 8192
    int b = idx >> 4, j = idx & 15;
    const float* hp = h2 + b * 128;
    const float* wp = w_d3 + j * 128;
    float s = b_d3[j];
    #pragma unroll 4
    for (int k = 0; k < 128; ++k) s += hp[k] * wp[k];
    out[idx] = s;
}

// ---------------------------------------------------------------------------
extern "C" void kernel_launch(void* const* d_in, const int* in_sizes, int n_in,
                              void* d_out, int out_size, void* d_ws, size_t ws_size,
                              hipStream_t stream) {
    (void)in_sizes; (void)n_in; (void)out_size; (void)ws_size;
    const float* x     = (const float*)d_in[0];
    const float* w0    = (const float*)d_in[1];
    const float* b0    = (const float*)d_in[2];
    const float* w1    = (const float*)d_in[3];
    const float* b1    = (const float*)d_in[4];
    const float* w2    = (const float*)d_in[5];
    const float* b2    = (const float*)d_in[6];
    const float* wa    = (const float*)d_in[7];
    const float* wb    = (const float*)d_in[8];
    const float* wg    = (const float*)d_in[9];
    const float* wd    = (const float*)d_in[10];
    const float* wenc  = (const float*)d_in[11];
    const float* cw    = (const float*)d_in[12];
    const float* scale = (const float*)d_in[13];
    const float* w_att = (const float*)d_in[14];
    const float* b_att = (const float*)d_in[15];
    const float* bn_g  = (const float*)d_in[16];
    const float* bn_b  = (const float*)d_in[17];
    const float* w_d1  = (const float*)d_in[18];
    const float* b_d1  = (const float*)d_in[19];
    const float* w_d2  = (const float*)d_in[20];
    const float* b_d2  = (const float*)d_in[21];
    const float* w_d3  = (const float*)d_in[22];
    const float* b_d3  = (const float*)d_in[23];

    float* ws    = (float*)d_ws;
    unsigned short* WE1H = (unsigned short*)(ws + OFF_WE1H);
    unsigned short* WE1L = (unsigned short*)(ws + OFF_WE1L);
    unsigned short* WE2H = (unsigned short*)(ws + OFF_WE2H);
    unsigned short* WE2L = (unsigned short*)(ws + OFF_WE2L);
    unsigned short* WE3H = (unsigned short*)(ws + OFF_WE3H);
    unsigned short* WE3L = (unsigned short*)(ws + OFF_WE3L);
    float* TMP   = ws + OFF_C1;     // alias: weff build finishes before conv0 writes C1
    float* C1    = ws + OFF_C1;
    float* C2    = ws + OFF_C2;
    float* XX1   = ws + OFF_XX1;
    float* ALPHA = ws + OFF_ALPHA;
    float* BETA  = ws + OFF_BETA;
    float* GAM   = ws + OFF_GAM;
    float* CTX   = ws + OFF_CTX;
    float* H1P   = ws + OFF_H1P;    // alias ALPHA region (dead at dense phase)
    float* CTX2  = ws + OFF_CTX2;
    float* XX2   = ws + OFF_XX2;
    float* Z     = ws + OFF_Z;
    float* A     = ws + OFF_A;
    float* E     = ws + OFF_E;
    float* BNS   = ws + OFF_BNS;
    float* XX3   = ws + OFF_XX3;
    float* H1    = ws + OFF_H1;
    float* H2    = ws + OFF_H2;
    unsigned short* WH  = (unsigned short*)(ws + OFF_WH);   // alias ALPHA (dead until sac_abg)
    unsigned short* WL  = (unsigned short*)(ws + OFF_WL);
    unsigned short* W1H = (unsigned short*)(ws + OFF_W1H);
    unsigned short* W1L = (unsigned short*)(ws + OFF_W1L);
    unsigned short* W2H = (unsigned short*)(ws + OFF_W2H);
    unsigned short* W2L = (unsigned short*)(ws + OFF_W2L);

    // weight prep (bf16 hi/lo splits)
    sac_wsplit<<<504, 256, 0, stream>>>(w0, WH, WL);
    sac_wsplit64<<<144, 256, 0, stream>>>(w1, W1H, W1L);
    sac_wsplit64<<<144, 256, 0, stream>>>(w2, W2H, W2L);

    // fold bilinear upsample into w_d1, emit bf16 hi/lo weff
    sac_upA<<<20672, 256, 0, stream>>>(w_d1, TMP, 17, 0);
    sac_upB_bf16<<<18496, 256, 0, stream>>>(TMP, WE1H, WE1L, 17);
    sac_upA<<<15808, 256, 0, stream>>>(w_d1, TMP, 13, 64);
    sac_upB_bf16<<<10816, 256, 0, stream>>>(TMP, WE2H, WE2L, 13);
    sac_upA<<<8512, 256, 0, stream>>>(w_d1, TMP, 7, 128);
    sac_upB_bf16<<<3136, 256, 0, stream>>>(TMP, WE3H, WE3L, 7);

    // backbone: 3 dilated convs via split-bf16 MFMA
    //            <IW, OW, DIL, TOTCH, WSTR, NMT, NIRMAX>
    sac_convmfma<19, 17, 1, 200, 224, 5, 7 ><<<2560, 256, 0, stream>>>(x,  WH,  WL,  b0, C1);
    sac_convmfma<17, 13, 2,  64,  64, 3, 10><<<1536, 256, 0, stream>>>(C1, W1H, W1L, b1, C2);
    sac_convmfma<13,  7, 3,  64,  64, 1, 13><<< 512, 256, 0, stream>>>(C2, W2H, W2L, b2, XX1);

    // non-local block
    sac_abg<<<512, 256, 0, stream>>>(XX1, wa, wb, wg, ALPHA, BETA, GAM);
    sac_ctx<<<512, 256, 0, stream>>>(ALPHA, BETA, CTX);
    sac_softmax0<<<2401, 256, 0, stream>>>(CTX);
    sac_ctx2<<<512, 256, 0, stream>>>(GAM, CTX, CTX2);
    sac_xx2<<<512, 256, 0, stream>>>(CTX2, wd, XX1, XX2);

    // soft VQ encoding + gate
    sac_z<<<512, 256, 0, stream>>>(XX2, wenc, Z);
    sac_dist<<<98, 256, 0, stream>>>(Z, cw, scale, A);
    sac_asoft<<<98, 256, 0, stream>>>(A);
    sac_e<<<512, 256, 0, stream>>>(A, Z, cw, E);
    sac_bnstat<<<48, 256, 0, stream>>>(E, BNS);
    sac_gate<<<512, 256, 0, stream>>>(E, BNS, bn_g, bn_b, w_att, b_att, XX2, XX3);

    // dense head (upsample folded into bf16 weff), fine split-K
    sac_d1gemm_mfma<<<896, 256, 0, stream>>>(C1, C2, XX3, WE1H, WE1L, WE2H, WE2L, WE3H, WE3L, H1P);
    sac_h1red<<<512, 256, 0, stream>>>(H1P, b_d1, H1);
    sac_h2<<<256, 256, 0, stream>>>(H1, w_d2, b_d2, H2);
    sac_out<<<32, 256, 0, stream>>>(H2, w_d3, b_d3, (float*)d_out);
}